// Round 10
// baseline (1788.255 us; speedup 1.0000x reference)
//
#include <hip/hip_runtime.h>
#include <hip/hip_bf16.h>
#include <math.h>

// SNN forward: 64 -> 1024 -> 1024 -> 10, T=4000, B=16, LIF beta=exp(-0.025),
// thr=1, hard reset to 0, Dale clamp W>=0.
// R10: layer 0 fused into its scan. input spikes -> 64-bit masks (ballot);
// k_scan_l0 keeps the clamped 64x64 W0 slice in LDS (exact fp32) and does a
// sparse gather per step (avg 3.2 adds, lane-uniform mask). Eliminates the
// L0 GEMM (write-bound, 131 MB fp32 IBUF/chunk), k_cvt and A_in.
// Layer 1: 256^2 8-phase GEMM (T2/T3/T4/T5). Layer 2: 128^2 GEMM, compact C.
// Scans: LDS-staged counted-vmcnt double buffer (R9).

#define T_STEPS 4000
#define NB 16
#define N_IN 64
#define NH 1024
#define N_OUT 10
#define SEGO 40           // scan_out segment rows; vmcnt(40) literal below
#define SEGH 50           // scan_hidden segment rows; vmcnt(50) literal below

typedef __attribute__((ext_vector_type(8))) short bf16x8;
typedef __attribute__((ext_vector_type(4))) float f32x4;
typedef __hip_bfloat16 bf16;
typedef unsigned long long u64;

#define ASG(p) (const __attribute__((address_space(1))) void*)(p)
#define ASL(p) (__attribute__((address_space(3))) void*)(p)

// ---------------- small utility kernels ----------------

__global__ void k_zero(double* p, int n) {
    int i = blockIdx.x * 256 + threadIdx.x;
    if (i < n) p[i] = 0.0;
}

// Build per-(t,b) 64-bit input spike masks. One wave per (t,b).
__global__ void k_mask(const float* __restrict__ in, u64* __restrict__ mask, int total) {
    int w = (blockIdx.x * 256 + threadIdx.x) >> 6;
    int lane = threadIdx.x & 63;
    if (w >= total) return;
    float v = in[(size_t)w * 64 + lane];
    u64 bal = __ballot(v > 0.5f);
    if (lane == 0) mask[w] = bal;
}

// Build BT[n][k2] (row-major [Npad x 2K]) from W [K x N] row-major.
// interleave=1: [hi64|lo64] alternating per source 64-block (for k_gemm).
// interleave=0: plain [hi(0..K) | lo(0..K)] (for k_gemm8; A col = k2 & (K-1)).
__global__ void k_limbs(const float* __restrict__ W, bf16* __restrict__ BT,
                        int K, int N, int Npad, int interleave) {
    int idx = blockIdx.x * 256 + threadIdx.x;
    int total = Npad * 2 * K;
    if (idx >= total) return;
    int n  = idx / (2 * K);
    int k2 = idx - n * (2 * K);
    int k, lo;
    if (interleave) {
        int kt2 = k2 >> 6, kk = k2 & 63;
        k = ((kt2 >> 1) << 6) + kk;
        lo = kt2 & 1;
    } else {
        lo = (k2 >= K);
        k = lo ? (k2 - K) : k2;
    }
    float v = 0.f;
    if (n < N) {
        float w = fmaxf(W[(size_t)k * N + n], 0.f);      // Dale's law clamp
        float hi = __bfloat162float(__float2bfloat16(w));
        v = lo ? (w - hi) : w;
    }
    BT[idx] = __float2bfloat16(v);
}

// ---------------- 128^2 2-phase GEMM (layer 2) ----------------
// BT interleaved: k-iteration kt uses A k-tile (kt>>1).

__global__ __launch_bounds__(256) void k_gemm(
    const bf16* __restrict__ A, const bf16* __restrict__ BT,
    float* __restrict__ C, int KA, int K2, int ldc, int gx) {
    const int nwg = gridDim.x;
    const int wg  = blockIdx.x;
    const int q = nwg >> 3, r = nwg & 7;
    const int xcd = wg & 7, idx0 = wg >> 3;
    const int swz = (xcd < r ? xcd * (q + 1) : r * (q + 1) + (xcd - r) * q) + idx0;
    const int gy = nwg / gx;
    const int n0 = (swz % gy) * 128;      // n-major within XCD chunk
    const int m0 = (swz / gy) * 128;
    __shared__ __align__(16) short Alds[128 * 64];
    __shared__ __align__(16) short Blds[128 * 64];
    const int tid  = threadIdx.x;
    const int lane = tid & 63;
    const int wave = tid >> 6;
    const int wbase = wave * 64;
    const int wm = (wave >> 1) * 64;
    const int wn = (wave & 1) * 64;
    const int r16 = lane & 15;
    const int kg  = lane >> 4;
    f32x4 acc[4][4] = {};
    const int nkt = K2 >> 6;
    for (int kt = 0; kt < nkt; ++kt) {
        const int kB0 = kt << 6;
        const int kA0 = (kt >> 1) << 6;
        __syncthreads();
#pragma unroll
        for (int rr = 0; rr < 4; ++rr) {
            int idx = rr * 256 + wbase + lane;
            int row = idx >> 3;
            int c8  = (idx & 7) << 3;
            if ((kt & 1) == 0)
                __builtin_amdgcn_global_load_lds(
                    ASG(&A[(size_t)(m0 + row) * KA + ((kA0 + c8) & (KA - 1))]),
                    ASL(&Alds[(rr * 256 + wbase) * 8]), 16, 0, 0);
            __builtin_amdgcn_global_load_lds(
                ASG(&BT[(size_t)(n0 + row) * K2 + kB0 + c8]),
                ASL(&Blds[(rr * 256 + wbase) * 8]), 16, 0, 0);
        }
        __syncthreads();
#pragma unroll
        for (int kk = 0; kk < 2; ++kk) {
            bf16x8 af[4], bfr[4];
#pragma unroll
            for (int i = 0; i < 4; ++i) {
                af[i]  = *(const bf16x8*)&Alds[(wm + i * 16 + r16) * 64 + kk * 32 + kg * 8];
                bfr[i] = *(const bf16x8*)&Blds[(wn + i * 16 + r16) * 64 + kk * 32 + kg * 8];
            }
#pragma unroll
            for (int mi = 0; mi < 4; ++mi)
#pragma unroll
                for (int ni = 0; ni < 4; ++ni)
                    acc[mi][ni] = __builtin_amdgcn_mfma_f32_16x16x32_bf16(
                        af[mi], bfr[ni], acc[mi][ni], 0, 0, 0);
        }
    }
#pragma unroll
    for (int mi = 0; mi < 4; ++mi)
#pragma unroll
        for (int ni = 0; ni < 4; ++ni) {
            int col = n0 + wn + ni * 16 + r16;
            if (col < ldc) {
#pragma unroll
                for (int rr = 0; rr < 4; ++rr) {
                    int row = m0 + wm + mi * 16 + kg * 4 + rr;
                    C[(size_t)row * ldc + col] = acc[mi][ni][rr];
                }
            }
        }
}

// ---------------- 256^2 8-phase GEMM (layer 1) ----------------
// Fixed shape: KA=1024, K2=2048, N=1024, ldc=1024. M multiple of 256.
// BT plain [hi|lo]; A col = k & 1023.
// LDS: 2 buf x {A,B} x 2 half-tiles x 16KB = 128 KB. st_16x32 swizzle.
// Stage ordering invariant (R8): a region is staged only in a phase after all
// ds_reads of it have drained past a barrier (A at P3, B at P2).

__global__ __launch_bounds__(512) void k_gemm8(
    const bf16* __restrict__ A, const bf16* __restrict__ BT,
    float* __restrict__ C, int gx) {
    const int KA = 1024, K2 = 2048;
    const int kmask = KA - 1;
    const int nwg = gridDim.x;
    const int wg  = blockIdx.x;
    const int q = nwg >> 3, r = nwg & 7;
    const int xcd = wg & 7, idx0 = wg >> 3;
    const int swz = (xcd < r ? xcd * (q + 1) : r * (q + 1) + (xcd - r) * q) + idx0;
    const int gy = nwg / gx;              // 4
    const int n0 = (swz % gy) * 256;      // n-major within XCD chunk
    const int m0 = (swz / gy) * 256;

    __shared__ __align__(16) char LDS[131072];
    const int tid  = threadIdx.x;
    const int lane = tid & 63;
    const int wave = tid >> 6;
    const int wm = (wave >> 2) * 128;     // 0 / 128
    const int wn = (wave & 3) * 64;       // 0..192
    const int r16l = lane & 15;
    const int kg   = lane >> 4;
    const int hA   = wave >> 2;           // A half this wave reads
    const int hB   = (wave & 3) >> 1;     // B half this wave reads
    const int wn64 = wave & 1;            // 64-col sub-block within B half

    const int po = (r16l * 64 + kg * 16) ^ (((r16l >> 3) & 1) << 5);
    const char* bA[2] = { LDS + hA * 16384 + po,
                          LDS + 65536 + hA * 16384 + po };
    const char* bB[2] = { LDS + 32768 + hB * 16384 + po,
                          LDS + 98304 + hB * 16384 + po };
    const int bOff = wn64 * 8192;

    int s_row[2], s_col[2];
#pragma unroll
    for (int rr = 0; rr < 2; ++rr) {
        int d = (rr * 512 + tid) * 16;            // linear LDS dest byte
        int l = d ^ (((d >> 9) & 1) << 5);        // logical element byte
        int sub = l >> 10;
        int w = l & 1023;
        s_row[rr] = (sub >> 1) * 16 + (w >> 6);
        s_col[rr] = ((sub & 1) * 64 + (w & 63)) >> 1;
    }

#define HBASE(BUF, OP, HALF) ((((BUF) * 2 + (OP)) * 2 + (HALF)) * 16384)
#define STAGE_A(BUF, HALF, K0)                                              \
    {                                                                       \
        _Pragma("unroll")                                                   \
        for (int rr = 0; rr < 2; ++rr)                                      \
            __builtin_amdgcn_global_load_lds(                               \
                ASG(A + (size_t)(m0 + (HALF) * 128 + s_row[rr]) * KA        \
                    + (((K0) + s_col[rr]) & kmask)),                        \
                ASL(LDS + HBASE(BUF, 0, HALF) + (rr * 512 + wave * 64) * 16), \
                16, 0, 0);                                                  \
    }
#define STAGE_B(BUF, HALF, K0)                                              \
    {                                                                       \
        _Pragma("unroll")                                                   \
        for (int rr = 0; rr < 2; ++rr)                                      \
            __builtin_amdgcn_global_load_lds(                               \
                ASG(BT + (size_t)(n0 + (HALF) * 128 + s_row[rr]) * K2       \
                    + (K0) + s_col[rr]),                                    \
                ASL(LDS + HBASE(BUF, 1, HALF) + (rr * 512 + wave * 64) * 16), \
                16, 0, 0);                                                  \
    }

    f32x4 acc[8][4] = {};
    bf16x8 a[4][2], b[4][2];

#define MM(MIB, NIB)                                                        \
    {                                                                       \
        _Pragma("unroll")                                                   \
        for (int i = 0; i < 4; ++i)                                         \
            _Pragma("unroll")                                               \
            for (int j = 0; j < 2; ++j) {                                   \
                acc[(MIB) + i][(NIB) + j] =                                 \
                    __builtin_amdgcn_mfma_f32_16x16x32_bf16(                \
                        a[i][0], b[(NIB) + j][0], acc[(MIB) + i][(NIB) + j], 0, 0, 0); \
                acc[(MIB) + i][(NIB) + j] =                                 \
                    __builtin_amdgcn_mfma_f32_16x16x32_bf16(                \
                        a[i][1], b[(NIB) + j][1], acc[(MIB) + i][(NIB) + j], 0, 0, 0); \
            }                                                               \
    }

#define PH_SYNC()                                                           \
    __builtin_amdgcn_s_barrier();                                           \
    asm volatile("s_waitcnt lgkmcnt(0)" ::: "memory");                      \
    __builtin_amdgcn_sched_barrier(0);

#define KTILE(BUF, SK)                                                      \
    {                                                                       \
        /* P0: ds a[0-3] + b[0-1]; no stage */                              \
        _Pragma("unroll")                                                   \
        for (int i = 0; i < 4; ++i) {                                       \
            a[i][0] = *(const bf16x8*)(bA[BUF] + i * 2048);                 \
            a[i][1] = *(const bf16x8*)(bA[BUF] + i * 2048 + 1024);          \
        }                                                                   \
        _Pragma("unroll")                                                   \
        for (int j = 0; j < 2; ++j) {                                       \
            b[j][0] = *(const bf16x8*)(bB[BUF] + bOff + j * 2048);          \
            b[j][1] = *(const bf16x8*)(bB[BUF] + bOff + j * 2048 + 1024);   \
        }                                                                   \
        PH_SYNC();                                                          \
        __builtin_amdgcn_s_setprio(1);                                      \
        MM(0, 0);                                                           \
        __builtin_amdgcn_s_setprio(0);                                      \
        __builtin_amdgcn_s_barrier();                                       \
        /* P1: ds b[2-3]; no stage */                                       \
        _Pragma("unroll")                                                   \
        for (int j = 0; j < 2; ++j) {                                       \
            b[2 + j][0] = *(const bf16x8*)(bB[BUF] + bOff + (2 + j) * 2048); \
            b[2 + j][1] = *(const bf16x8*)(bB[BUF] + bOff + (2 + j) * 2048 + 1024); \
        }                                                                   \
        PH_SYNC();                                                          \
        __builtin_amdgcn_s_setprio(1);                                      \
        MM(0, 2);                                                           \
        __builtin_amdgcn_s_setprio(0);                                      \
        __builtin_amdgcn_s_barrier();                                       \
        /* P2: ds a[4-7]; stage B-h0+B-h1 (B reads drained at P1) */        \
        _Pragma("unroll")                                                   \
        for (int i = 0; i < 4; ++i) {                                       \
            a[i][0] = *(const bf16x8*)(bA[BUF] + (4 + i) * 2048);           \
            a[i][1] = *(const bf16x8*)(bA[BUF] + (4 + i) * 2048 + 1024);    \
        }                                                                   \
        STAGE_B(BUF, 0, SK);                                                \
        STAGE_B(BUF, 1, SK);                                                \
        PH_SYNC();                                                          \
        __builtin_amdgcn_s_setprio(1);                                      \
        MM(4, 0);                                                           \
        __builtin_amdgcn_s_setprio(0);                                      \
        __builtin_amdgcn_s_barrier();                                       \
        /* P3: stage A-h0+A-h1 (A reads drained at P2); vmcnt(8) */         \
        STAGE_A(BUF, 0, SK);                                                \
        STAGE_A(BUF, 1, SK);                                                \
        PH_SYNC();                                                          \
        __builtin_amdgcn_s_setprio(1);                                      \
        MM(4, 2);                                                           \
        __builtin_amdgcn_s_setprio(0);                                      \
        asm volatile("s_waitcnt vmcnt(8)" ::: "memory");                    \
        __builtin_amdgcn_sched_barrier(0);                                  \
        __builtin_amdgcn_s_barrier();                                       \
    }

    STAGE_A(0, 0, 0);  STAGE_A(0, 1, 0);  STAGE_B(0, 0, 0);  STAGE_B(0, 1, 0);
    STAGE_A(1, 0, 64); STAGE_A(1, 1, 64); STAGE_B(1, 0, 64); STAGE_B(1, 1, 64);
    asm volatile("s_waitcnt vmcnt(8)" ::: "memory");
    __builtin_amdgcn_sched_barrier(0);
    __builtin_amdgcn_s_barrier();

    for (int it = 0; it < 16; ++it) {
        const int k0  = it * 128;
        const int ksA = (k0 + 128) & (K2 - 1);
        const int ksB = (k0 + 192) & (K2 - 1);
        KTILE(0, ksA);
        KTILE(1, ksB);
    }
    asm volatile("s_waitcnt vmcnt(0)" ::: "memory");
    __builtin_amdgcn_sched_barrier(0);

#pragma unroll
    for (int mi = 0; mi < 8; ++mi)
#pragma unroll
        for (int ni = 0; ni < 4; ++ni)
#pragma unroll
            for (int rr = 0; rr < 4; ++rr) {
                int row = m0 + wm + mi * 16 + kg * 4 + rr;
                int col = n0 + wn + ni * 16 + r16l;
                C[(size_t)row * 1024 + col] = acc[mi][ni][rr];
            }
#undef KTILE
#undef PH_SYNC
#undef MM
#undef STAGE_A
#undef STAGE_B
#undef HBASE
}

// ---------------- LIF scan kernels (fp64 membranes) ----------------

// layer 0 fused scan: sparse mask-gather from LDS-resident W0 slice.
// 256 blocks x 64 threads; block = (b, 64-column group q). Mask is uniform
// across the block's lanes (same b) -> no divergence in the while loop.
__global__ __launch_bounds__(64) void k_scan_l0(
    const u64* __restrict__ mask,          // offset to chunk: [Tc*NB]
    const float* __restrict__ W0,          // [64][1024] row-major
    const float* __restrict__ bias,
    double* __restrict__ mstate, bf16* __restrict__ S, int Tc, double beta) {
    __shared__ float Wlds[64 * 64];
    const int lane = threadIdx.x;
    const int gid  = blockIdx.x * 64 + lane;
    const int b = gid >> 10;
    const int qj = blockIdx.x & 15;        // column group within b
    for (int k = 0; k < 64; ++k)
        Wlds[k * 64 + lane] = fmaxf(W0[k * 1024 + qj * 64 + lane], 0.f);
    __syncthreads();
    double m = mstate[gid];
    const float bj = bias[qj * 64 + lane];
    const bf16 one  = __float2bfloat16(1.0f);
    const bf16 zero = __float2bfloat16(0.0f);
    const size_t stride = (size_t)NB * NH;
    // lane l holds the mask for t = tb + l; broadcast via shfl per step
    u64 cur = mask[(size_t)lane * NB + b];
    for (int tb = 0; tb < Tc; tb += 64) {
        u64 nxt = (tb + 64 < Tc) ? mask[(size_t)(tb + 64 + lane) * NB + b] : 0ULL;
        for (int u = 0; u < 64; ++u) {
            u64 msk = __shfl(cur, u);
            float acc = bj;
            while (msk) {
                int k = __builtin_ctzll(msk);
                msk &= msk - 1;
                acc += Wlds[k * 64 + lane];
            }
            m = beta * m + (double)acc;
            bool sp = (m >= 1.0);
            S[(size_t)(tb + u) * stride + gid] = sp ? one : zero;
            m = sp ? 0.0 : m;
        }
        cur = nxt;
    }
    mstate[gid] = m;
}

// hidden layer 1 scan: counted-vmcnt LDS double buffer (R9).
__global__ __launch_bounds__(64) void k_scan_hidden(
    const float* __restrict__ I, const float* __restrict__ bias,
    double* __restrict__ mstate, bf16* __restrict__ S, int Tc, double beta) {
    __shared__ __align__(16) float segA[SEGH * 64];
    __shared__ __align__(16) float segB[SEGH * 64];
    const int lane = threadIdx.x;
    const int gid  = blockIdx.x * 64 + lane;
    const int j = gid & (NH - 1);
    double m = mstate[gid];
    const float bj = bias[j];
    const size_t stride = (size_t)NB * NH;
    const int nseg = Tc / SEGH;                  // even (Tc % 400 == 0)

#define H_PREFETCH(SEGBUF, SIDX)                                            \
    {                                                                       \
        const float* src = I + (size_t)(SIDX) * SEGH * stride + gid;        \
        _Pragma("unroll")                                                   \
        for (int rr = 0; rr < SEGH; ++rr)                                   \
            __builtin_amdgcn_global_load_lds(                               \
                ASG(src + (size_t)rr * stride),                             \
                ASL(&SEGBUF[rr * 64]), 4, 0, 0);                            \
    }

#define H_PROC(SEGBUF, SIDX)                                                \
    {                                                                       \
        const int btt = (SIDX) * SEGH;                                      \
        _Pragma("unroll")                                                   \
        for (int sb = 0; sb < SEGH / 10; ++sb) {                            \
            float v[10];                                                    \
            _Pragma("unroll")                                               \
            for (int u = 0; u < 10; ++u)                                    \
                v[u] = SEGBUF[(sb * 10 + u) * 64 + lane];                   \
            unsigned short o[10];                                           \
            _Pragma("unroll")                                               \
            for (int u = 0; u < 10; ++u) {                                  \
                m = beta * m + (double)(v[u] + bj);                         \
                bool sp = (m >= 1.0);                                       \
                o[u] = sp ? (unsigned short)0x3F80 : (unsigned short)0;     \
                m = sp ? 0.0 : m;                                           \
            }                                                               \
            _Pragma("unroll")                                               \
            for (int u = 0; u < 10; ++u)                                    \
                ((unsigned short*)S)[(size_t)(btt + sb * 10 + u) * stride + gid] = o[u]; \
        }                                                                   \
    }

    H_PREFETCH(segA, 0);
    for (int s = 0; s < nseg; s += 2) {
        H_PREFETCH(segB, s + 1);
        asm volatile("s_waitcnt vmcnt(50)" ::: "memory"); // segA resident
        __builtin_amdgcn_sched_barrier(0);
        H_PROC(segA, s);
        if (s + 2 < nseg) {
            H_PREFETCH(segA, s + 2);
            asm volatile("s_waitcnt vmcnt(50)" ::: "memory"); // segB resident
        } else {
            asm volatile("s_waitcnt vmcnt(0)" ::: "memory");
        }
        __builtin_amdgcn_sched_barrier(0);
        H_PROC(segB, s + 1);
    }
    mstate[gid] = m;
#undef H_PREFETCH
#undef H_PROC
}

__global__ __launch_bounds__(256) void k_scan_out(
    const float* __restrict__ I2, const float* __restrict__ bias,
    double* __restrict__ mstate, float* __restrict__ out,
    int Tc, int t0, double beta) {
    __shared__ __align__(16) float segA[SEGO * 256];
    __shared__ __align__(16) float segB[SEGO * 256];
    const int tid  = threadIdx.x;
    const int lane = tid & 63;
    const int wave = tid >> 6;
    const int k = tid & 15;
    const int b = tid >> 4;
    double m = mstate[tid];
    float bj = (k < N_OUT) ? bias[k] : 0.f;
    const int nseg = Tc / SEGO;                  // even (Tc % 400 == 0)

#define O_PREFETCH(SEGBUF, SIDX)                                            \
    {                                                                       \
        const float* src = I2 + (size_t)(SIDX) * SEGO * 256 + wave * 64 + lane; \
        _Pragma("unroll 8")                                                 \
        for (int rr = 0; rr < SEGO; ++rr)                                   \
            __builtin_amdgcn_global_load_lds(                               \
                ASG(src + (size_t)rr * 256),                                \
                ASL(&SEGBUF[rr * 256 + wave * 64]), 4, 0, 0);               \
    }

#define O_PROC(SEGBUF, SIDX)                                                \
    {                                                                       \
        const int btt = (SIDX) * SEGO;                                      \
        _Pragma("unroll")                                                   \
        for (int sb = 0; sb < SEGO / 8; ++sb) {                             \
            float v[8];                                                     \
            _Pragma("unroll")                                               \
            for (int u = 0; u < 8; ++u)                                     \
                v[u] = SEGBUF[(sb * 8 + u) * 256 + tid];                    \
            float o[8];                                                     \
            _Pragma("unroll")                                               \
            for (int u = 0; u < 8; ++u) {                                   \
                m = beta * m + (double)(v[u] + bj);                         \
                bool sp = (m >= 1.0);                                       \
                o[u] = sp ? 1.f : 0.f;                                      \
                m = sp ? 0.0 : m;                                           \
            }                                                               \
            if (k < N_OUT) {                                                \
                _Pragma("unroll")                                           \
                for (int u = 0; u < 8; ++u)                                 \
                    out[((size_t)(t0 + btt + sb * 8 + u) * NB + b) * N_OUT + k] = o[u]; \
            }                                                               \
        }                                                                   \
    }

    O_PREFETCH(segA, 0);
    for (int s = 0; s < nseg; s += 2) {
        O_PREFETCH(segB, s + 1);
        asm volatile("s_waitcnt vmcnt(40)" ::: "memory"); // segA resident
        __builtin_amdgcn_sched_barrier(0);
        O_PROC(segA, s);
        if (s + 2 < nseg) {
            O_PREFETCH(segA, s + 2);
            asm volatile("s_waitcnt vmcnt(40)" ::: "memory"); // segB resident
        } else {
            asm volatile("s_waitcnt vmcnt(0)" ::: "memory");
        }
        __builtin_amdgcn_sched_barrier(0);
        O_PROC(segB, s + 1);
    }
    mstate[tid] = m;
#undef O_PREFETCH
#undef O_PROC
}

// ---------------- host ----------------

extern "C" void kernel_launch(void* const* d_in, const int* in_sizes, int n_in,
                              void* d_out, int out_size, void* d_ws, size_t ws_size,
                              hipStream_t stream) {
    const float* in_sp = (const float*)d_in[0];
    const float* W0 = (const float*)d_in[1];
    const float* b0 = (const float*)d_in[2];
    const float* W1 = (const float*)d_in[3];
    const float* b1 = (const float*)d_in[4];
    const float* W2 = (const float*)d_in[5];
    const float* b2 = (const float*)d_in[6];
    float* out = (float*)d_out;

    char* p = (char*)d_ws;
    auto carve = [&](size_t bytes) -> void* {
        char* r = p; p += (bytes + 255) & ~(size_t)255; return (void*)r;
    };
    u64*  MASK = (u64*)carve((size_t)T_STEPS * NB * 8);
    bf16* BT1  = (bf16*)carve((size_t)NH * 2 * NH * 2);
    bf16* BT2  = (bf16*)carve((size_t)128 * 2 * NH * 2);
    double* m0s = (double*)carve((size_t)NB * NH * 8);
    double* m1s = (double*)carve((size_t)NB * NH * 8);
    double* m2s = (double*)carve((size_t)NB * 16 * 8);
    size_t fixed = (size_t)(p - (char*)d_ws);

    // Tc | 4000, Tc % 400 == 0 (scan segs even), Mc % 256 == 0
    const int tc_opts[3] = {2000, 800, 400};
    int Tc = 400;
    for (int i = 0; i < 3; ++i) {
        size_t Mc_ = (size_t)tc_opts[i] * NB;
        size_t need = fixed
            + ((Mc_ * NH * 4 + 255) & ~(size_t)255)
            + ((Mc_ * 16 * 4 + 255) & ~(size_t)255)
            + ((Mc_ * NH * 2 + 255) & ~(size_t)255);
        if (need <= ws_size) { Tc = tc_opts[i]; break; }
    }
    size_t Mc = (size_t)Tc * NB;
    float* IBUF  = (float*)carve(Mc * NH * 4);
    float* I2BUF = (float*)carve(Mc * 16 * 4);
    bf16*  S     = (bf16*)carve(Mc * NH * 2);

    const int use8 = (Mc % 256 == 0);     // layer-1 kernel choice
    const double beta = exp(-0.25 / 10.0);

    // m0s/m1s/m2s contiguous: one zero kernel.
    int nM = NB * NH * 2 + NB * 16;
    k_zero<<<(nM + 255) / 256, 256, 0, stream>>>(m0s, nM);

    // input spike masks (one wave per (t,b))
    k_mask<<<(T_STEPS * NB * 64) / 256, 256, 0, stream>>>(in_sp, MASK, T_STEPS * NB);

    k_limbs<<<(NH * 2 * NH + 255) / 256, 256, 0, stream>>>(W1, BT1, NH, NH, NH, use8 ? 0 : 1);
    k_limbs<<<(128 * 2 * NH + 255) / 256, 256, 0, stream>>>(W2, BT2, NH, N_OUT, 128, 1);

    const int C = T_STEPS / Tc;
    const int gx = (int)(Mc / 128);
    const int gx8 = (int)(Mc / 256);
    for (int c = 0; c < C; ++c) {
        int t0 = c * Tc;
        // layer 0: fused sparse scan (exact fp32 weights)
        k_scan_l0<<<256, 64, 0, stream>>>(MASK + (size_t)t0 * NB, W0, b0,
                                          m0s, S, Tc, beta);
        // layer 1 (256^2 8-phase kernel when shape permits)
        if (use8)
            k_gemm8<<<gx8 * 4, 512, 0, stream>>>(S, BT1, IBUF, gx8);
        else
            k_gemm<<<gx * 8, 256, 0, stream>>>(S, BT1, IBUF, NH, 2 * NH, NH, gx);
        k_scan_hidden<<<(NB * NH) / 64, 64, 0, stream>>>(IBUF, b1, m1s, S, Tc, beta);
        // layer 2 (compact 16-col C)
        k_gemm<<<gx, 256, 0, stream>>>(S, BT2, I2BUF, NH, 2 * NH, 16, gx);
        k_scan_out<<<1, 256, 0, stream>>>(I2BUF, b2, m2s, out, Tc, t0, beta);
    }
}

// Round 11
// 988.922 us; speedup vs baseline: 1.8083x; 1.8083x over previous
//
#include <hip/hip_runtime.h>
#include <hip/hip_bf16.h>
#include <math.h>

// SNN forward: 64 -> 1024 -> 1024 -> 10, T=4000, B=16, LIF beta=exp(-0.025),
// thr=1, hard reset to 0, Dale clamp W>=0.
// R11: L0 fused scan redone with per-block MFMA (R10's bit-gather was a
// 650cy/step latency chain). Block = (b, 64-col group): W0 slice lives in
// registers as MFMA B-frags (hi+lo limbs); A-frags built from 64-bit spike
// masks; I0 tile [16t x 64j] goes through padded LDS; scan consumes it.
// Layer 1: 256^2 8-phase GEMM (T2/T3/T4/T5). Layer 2: 128^2 GEMM, compact C.
// Hidden/out scans: LDS-staged counted-vmcnt double buffer (R9).

#define T_STEPS 4000
#define NB 16
#define N_IN 64
#define NH 1024
#define N_OUT 10
#define SEGO 40           // scan_out segment rows; vmcnt(40) literal below
#define SEGH 50           // scan_hidden segment rows; vmcnt(50) literal below

typedef __attribute__((ext_vector_type(8))) short bf16x8;
typedef __attribute__((ext_vector_type(4))) float f32x4;
typedef __hip_bfloat16 bf16;
typedef unsigned long long u64;

#define ASG(p) (const __attribute__((address_space(1))) void*)(p)
#define ASL(p) (__attribute__((address_space(3))) void*)(p)

// ---------------- small utility kernels ----------------

__global__ void k_zero(double* p, int n) {
    int i = blockIdx.x * 256 + threadIdx.x;
    if (i < n) p[i] = 0.0;
}

// Build per-(t,b) 64-bit input spike masks. One wave per (t,b).
__global__ void k_mask(const float* __restrict__ in, u64* __restrict__ mask, int total) {
    int w = (blockIdx.x * 256 + threadIdx.x) >> 6;
    int lane = threadIdx.x & 63;
    if (w >= total) return;
    float v = in[(size_t)w * 64 + lane];
    u64 bal = __ballot(v > 0.5f);
    if (lane == 0) mask[w] = bal;
}

// Build BT[n][k2] (row-major [Npad x 2K]) from W [K x N] row-major.
// interleave=1: [hi64|lo64] alternating per source 64-block (for k_gemm).
// interleave=0: plain [hi(0..K) | lo(0..K)] (for k_gemm8; A col = k2 & (K-1)).
__global__ void k_limbs(const float* __restrict__ W, bf16* __restrict__ BT,
                        int K, int N, int Npad, int interleave) {
    int idx = blockIdx.x * 256 + threadIdx.x;
    int total = Npad * 2 * K;
    if (idx >= total) return;
    int n  = idx / (2 * K);
    int k2 = idx - n * (2 * K);
    int k, lo;
    if (interleave) {
        int kt2 = k2 >> 6, kk = k2 & 63;
        k = ((kt2 >> 1) << 6) + kk;
        lo = kt2 & 1;
    } else {
        lo = (k2 >= K);
        k = lo ? (k2 - K) : k2;
    }
    float v = 0.f;
    if (n < N) {
        float w = fmaxf(W[(size_t)k * N + n], 0.f);      // Dale's law clamp
        float hi = __bfloat162float(__float2bfloat16(w));
        v = lo ? (w - hi) : w;
    }
    BT[idx] = __float2bfloat16(v);
}

// ---------------- 128^2 2-phase GEMM (layer 2 / fallback) ----------------

__global__ __launch_bounds__(256) void k_gemm(
    const bf16* __restrict__ A, const bf16* __restrict__ BT,
    float* __restrict__ C, int KA, int K2, int ldc, int gx) {
    const int nwg = gridDim.x;
    const int wg  = blockIdx.x;
    const int q = nwg >> 3, r = nwg & 7;
    const int xcd = wg & 7, idx0 = wg >> 3;
    const int swz = (xcd < r ? xcd * (q + 1) : r * (q + 1) + (xcd - r) * q) + idx0;
    const int gy = nwg / gx;
    const int n0 = (swz % gy) * 128;
    const int m0 = (swz / gy) * 128;
    __shared__ __align__(16) short Alds[128 * 64];
    __shared__ __align__(16) short Blds[128 * 64];
    const int tid  = threadIdx.x;
    const int lane = tid & 63;
    const int wave = tid >> 6;
    const int wbase = wave * 64;
    const int wm = (wave >> 1) * 64;
    const int wn = (wave & 1) * 64;
    const int r16 = lane & 15;
    const int kg  = lane >> 4;
    f32x4 acc[4][4] = {};
    const int nkt = K2 >> 6;
    for (int kt = 0; kt < nkt; ++kt) {
        const int kB0 = kt << 6;
        const int kA0 = (kt >> 1) << 6;
        __syncthreads();
#pragma unroll
        for (int rr = 0; rr < 4; ++rr) {
            int idx = rr * 256 + wbase + lane;
            int row = idx >> 3;
            int c8  = (idx & 7) << 3;
            if ((kt & 1) == 0)
                __builtin_amdgcn_global_load_lds(
                    ASG(&A[(size_t)(m0 + row) * KA + ((kA0 + c8) & (KA - 1))]),
                    ASL(&Alds[(rr * 256 + wbase) * 8]), 16, 0, 0);
            __builtin_amdgcn_global_load_lds(
                ASG(&BT[(size_t)(n0 + row) * K2 + kB0 + c8]),
                ASL(&Blds[(rr * 256 + wbase) * 8]), 16, 0, 0);
        }
        __syncthreads();
#pragma unroll
        for (int kk = 0; kk < 2; ++kk) {
            bf16x8 af[4], bfr[4];
#pragma unroll
            for (int i = 0; i < 4; ++i) {
                af[i]  = *(const bf16x8*)&Alds[(wm + i * 16 + r16) * 64 + kk * 32 + kg * 8];
                bfr[i] = *(const bf16x8*)&Blds[(wn + i * 16 + r16) * 64 + kk * 32 + kg * 8];
            }
#pragma unroll
            for (int mi = 0; mi < 4; ++mi)
#pragma unroll
                for (int ni = 0; ni < 4; ++ni)
                    acc[mi][ni] = __builtin_amdgcn_mfma_f32_16x16x32_bf16(
                        af[mi], bfr[ni], acc[mi][ni], 0, 0, 0);
        }
    }
#pragma unroll
    for (int mi = 0; mi < 4; ++mi)
#pragma unroll
        for (int ni = 0; ni < 4; ++ni) {
            int col = n0 + wn + ni * 16 + r16;
            if (col < ldc) {
#pragma unroll
                for (int rr = 0; rr < 4; ++rr) {
                    int row = m0 + wm + mi * 16 + kg * 4 + rr;
                    C[(size_t)row * ldc + col] = acc[mi][ni][rr];
                }
            }
        }
}

// ---------------- 256^2 8-phase GEMM (layer 1) ----------------
// Stage ordering invariant (R8): a region is staged only in a phase after all
// ds_reads of it have drained past a barrier (A at P3, B at P2).

__global__ __launch_bounds__(512) void k_gemm8(
    const bf16* __restrict__ A, const bf16* __restrict__ BT,
    float* __restrict__ C, int gx) {
    const int KA = 1024, K2 = 2048;
    const int kmask = KA - 1;
    const int nwg = gridDim.x;
    const int wg  = blockIdx.x;
    const int q = nwg >> 3, r = nwg & 7;
    const int xcd = wg & 7, idx0 = wg >> 3;
    const int swz = (xcd < r ? xcd * (q + 1) : r * (q + 1) + (xcd - r) * q) + idx0;
    const int gy = nwg / gx;              // 4
    const int n0 = (swz % gy) * 256;
    const int m0 = (swz / gy) * 256;

    __shared__ __align__(16) char LDS[131072];
    const int tid  = threadIdx.x;
    const int lane = tid & 63;
    const int wave = tid >> 6;
    const int wm = (wave >> 2) * 128;
    const int wn = (wave & 3) * 64;
    const int r16l = lane & 15;
    const int kg   = lane >> 4;
    const int hA   = wave >> 2;
    const int hB   = (wave & 3) >> 1;
    const int wn64 = wave & 1;

    const int po = (r16l * 64 + kg * 16) ^ (((r16l >> 3) & 1) << 5);
    const char* bA[2] = { LDS + hA * 16384 + po,
                          LDS + 65536 + hA * 16384 + po };
    const char* bB[2] = { LDS + 32768 + hB * 16384 + po,
                          LDS + 98304 + hB * 16384 + po };
    const int bOff = wn64 * 8192;

    int s_row[2], s_col[2];
#pragma unroll
    for (int rr = 0; rr < 2; ++rr) {
        int d = (rr * 512 + tid) * 16;
        int l = d ^ (((d >> 9) & 1) << 5);
        int sub = l >> 10;
        int w = l & 1023;
        s_row[rr] = (sub >> 1) * 16 + (w >> 6);
        s_col[rr] = ((sub & 1) * 64 + (w & 63)) >> 1;
    }

#define HBASE(BUF, OP, HALF) ((((BUF) * 2 + (OP)) * 2 + (HALF)) * 16384)
#define STAGE_A(BUF, HALF, K0)                                              \
    {                                                                       \
        _Pragma("unroll")                                                   \
        for (int rr = 0; rr < 2; ++rr)                                      \
            __builtin_amdgcn_global_load_lds(                               \
                ASG(A + (size_t)(m0 + (HALF) * 128 + s_row[rr]) * KA        \
                    + (((K0) + s_col[rr]) & kmask)),                        \
                ASL(LDS + HBASE(BUF, 0, HALF) + (rr * 512 + wave * 64) * 16), \
                16, 0, 0);                                                  \
    }
#define STAGE_B(BUF, HALF, K0)                                              \
    {                                                                       \
        _Pragma("unroll")                                                   \
        for (int rr = 0; rr < 2; ++rr)                                      \
            __builtin_amdgcn_global_load_lds(                               \
                ASG(BT + (size_t)(n0 + (HALF) * 128 + s_row[rr]) * K2       \
                    + (K0) + s_col[rr]),                                    \
                ASL(LDS + HBASE(BUF, 1, HALF) + (rr * 512 + wave * 64) * 16), \
                16, 0, 0);                                                  \
    }

    f32x4 acc[8][4] = {};
    bf16x8 a[4][2], b[4][2];

#define MM(MIB, NIB)                                                        \
    {                                                                       \
        _Pragma("unroll")                                                   \
        for (int i = 0; i < 4; ++i)                                         \
            _Pragma("unroll")                                               \
            for (int j = 0; j < 2; ++j) {                                   \
                acc[(MIB) + i][(NIB) + j] =                                 \
                    __builtin_amdgcn_mfma_f32_16x16x32_bf16(                \
                        a[i][0], b[(NIB) + j][0], acc[(MIB) + i][(NIB) + j], 0, 0, 0); \
                acc[(MIB) + i][(NIB) + j] =                                 \
                    __builtin_amdgcn_mfma_f32_16x16x32_bf16(                \
                        a[i][1], b[(NIB) + j][1], acc[(MIB) + i][(NIB) + j], 0, 0, 0); \
            }                                                               \
    }

#define PH_SYNC()                                                           \
    __builtin_amdgcn_s_barrier();                                           \
    asm volatile("s_waitcnt lgkmcnt(0)" ::: "memory");                      \
    __builtin_amdgcn_sched_barrier(0);

#define KTILE(BUF, SK)                                                      \
    {                                                                       \
        _Pragma("unroll")                                                   \
        for (int i = 0; i < 4; ++i) {                                       \
            a[i][0] = *(const bf16x8*)(bA[BUF] + i * 2048);                 \
            a[i][1] = *(const bf16x8*)(bA[BUF] + i * 2048 + 1024);          \
        }                                                                   \
        _Pragma("unroll")                                                   \
        for (int j = 0; j < 2; ++j) {                                       \
            b[j][0] = *(const bf16x8*)(bB[BUF] + bOff + j * 2048);          \
            b[j][1] = *(const bf16x8*)(bB[BUF] + bOff + j * 2048 + 1024);   \
        }                                                                   \
        PH_SYNC();                                                          \
        __builtin_amdgcn_s_setprio(1);                                      \
        MM(0, 0);                                                           \
        __builtin_amdgcn_s_setprio(0);                                      \
        __builtin_amdgcn_s_barrier();                                       \
        _Pragma("unroll")                                                   \
        for (int j = 0; j < 2; ++j) {                                       \
            b[2 + j][0] = *(const bf16x8*)(bB[BUF] + bOff + (2 + j) * 2048); \
            b[2 + j][1] = *(const bf16x8*)(bB[BUF] + bOff + (2 + j) * 2048 + 1024); \
        }                                                                   \
        PH_SYNC();                                                          \
        __builtin_amdgcn_s_setprio(1);                                      \
        MM(0, 2);                                                           \
        __builtin_amdgcn_s_setprio(0);                                      \
        __builtin_amdgcn_s_barrier();                                       \
        _Pragma("unroll")                                                   \
        for (int i = 0; i < 4; ++i) {                                       \
            a[i][0] = *(const bf16x8*)(bA[BUF] + (4 + i) * 2048);           \
            a[i][1] = *(const bf16x8*)(bA[BUF] + (4 + i) * 2048 + 1024);    \
        }                                                                   \
        STAGE_B(BUF, 0, SK);                                                \
        STAGE_B(BUF, 1, SK);                                                \
        PH_SYNC();                                                          \
        __builtin_amdgcn_s_setprio(1);                                      \
        MM(4, 0);                                                           \
        __builtin_amdgcn_s_setprio(0);                                      \
        __builtin_amdgcn_s_barrier();                                       \
        STAGE_A(BUF, 0, SK);                                                \
        STAGE_A(BUF, 1, SK);                                                \
        PH_SYNC();                                                          \
        __builtin_amdgcn_s_setprio(1);                                      \
        MM(4, 2);                                                           \
        __builtin_amdgcn_s_setprio(0);                                      \
        asm volatile("s_waitcnt vmcnt(8)" ::: "memory");                    \
        __builtin_amdgcn_sched_barrier(0);                                  \
        __builtin_amdgcn_s_barrier();                                       \
    }

    STAGE_A(0, 0, 0);  STAGE_A(0, 1, 0);  STAGE_B(0, 0, 0);  STAGE_B(0, 1, 0);
    STAGE_A(1, 0, 64); STAGE_A(1, 1, 64); STAGE_B(1, 0, 64); STAGE_B(1, 1, 64);
    asm volatile("s_waitcnt vmcnt(8)" ::: "memory");
    __builtin_amdgcn_sched_barrier(0);
    __builtin_amdgcn_s_barrier();

    for (int it = 0; it < 16; ++it) {
        const int k0  = it * 128;
        const int ksA = (k0 + 128) & (K2 - 1);
        const int ksB = (k0 + 192) & (K2 - 1);
        KTILE(0, ksA);
        KTILE(1, ksB);
    }
    asm volatile("s_waitcnt vmcnt(0)" ::: "memory");
    __builtin_amdgcn_sched_barrier(0);

#pragma unroll
    for (int mi = 0; mi < 8; ++mi)
#pragma unroll
        for (int ni = 0; ni < 4; ++ni)
#pragma unroll
            for (int rr = 0; rr < 4; ++rr) {
                int row = m0 + wm + mi * 16 + kg * 4 + rr;
                int col = n0 + wn + ni * 16 + r16l;
                C[(size_t)row * 1024 + col] = acc[mi][ni][rr];
            }
#undef KTILE
#undef PH_SYNC
#undef MM
#undef STAGE_A
#undef STAGE_B
#undef HBASE
}

// ---------------- LIF scan kernels (fp64 membranes) ----------------

// L0 fused scan via MFMA (R11). 256 blocks x 64 threads; block = (b, jgroup).
// W0 slice in registers as B-frags (hi+lo limbs). Per 16-t tile: A-frag from
// mask bits -> 16 MFMA -> LDS [16][68] (pad: 2-way banks, free) -> scan.
// Iteration order: read v[] of tile tt, issue MFMA of tile tt+1 (matrix pipe
// overlaps the serial fp64 chain), then chain + S stores.
__global__ __launch_bounds__(64) void k_scan_l0(
    const u64* __restrict__ mask,          // [Tc][NB] for this chunk
    const float* __restrict__ W0,          // [64][1024] row-major
    const float* __restrict__ bias,
    double* __restrict__ mstate, bf16* __restrict__ S, int Tc, double beta) {
    __shared__ float Ilds[2][16][68];
    const int lane = threadIdx.x;
    const int gid  = blockIdx.x * 64 + lane;   // = b*1024 + q*64 + lane
    const int b  = blockIdx.x >> 4;
    const int q  = blockIdx.x & 15;
    const int j0 = q * 64;
    const int r16 = lane & 15;
    const int kg  = lane >> 4;
    // B-frags: b?[jt][kk], element e -> W0[kk*32+kg*8+e][j0+jt*16+r16]
    bf16x8 bh[4][2], bl[4][2];
#pragma unroll
    for (int jt = 0; jt < 4; ++jt)
#pragma unroll
        for (int kk = 0; kk < 2; ++kk)
#pragma unroll
            for (int e = 0; e < 8; ++e) {
                int k = kk * 32 + kg * 8 + e;
                float w = fmaxf(W0[(size_t)k * 1024 + j0 + jt * 16 + r16], 0.f);
                bf16 h = __float2bfloat16(w);
                float hf = __bfloat162float(h);
                bf16 l = __float2bfloat16(w - hf);
                bh[jt][kk][e] = *(short*)&h;
                bl[jt][kk][e] = *(short*)&l;
            }
    double m = mstate[gid];
    const float bj = bias[j0 + lane];
    const size_t stride = (size_t)NB * NH;
    const int ntile = Tc / 16;

#define L0_TILE(TT, P)                                                      \
    {                                                                       \
        u64 msk = mask[(size_t)((TT) * 16 + r16) * NB + b];                 \
        f32x4 acc[4] = {};                                                  \
        _Pragma("unroll")                                                   \
        for (int kk = 0; kk < 2; ++kk) {                                    \
            unsigned byte8 = (unsigned)((msk >> (kk * 32 + kg * 8)) & 0xFF); \
            bf16x8 af;                                                      \
            _Pragma("unroll")                                               \
            for (int e = 0; e < 8; ++e)                                     \
                af[e] = ((byte8 >> e) & 1) ? (short)0x3F80 : (short)0;      \
            _Pragma("unroll")                                               \
            for (int jt = 0; jt < 4; ++jt) {                                \
                acc[jt] = __builtin_amdgcn_mfma_f32_16x16x32_bf16(          \
                    af, bh[jt][kk], acc[jt], 0, 0, 0);                      \
                acc[jt] = __builtin_amdgcn_mfma_f32_16x16x32_bf16(          \
                    af, bl[jt][kk], acc[jt], 0, 0, 0);                      \
            }                                                               \
        }                                                                   \
        _Pragma("unroll")                                                   \
        for (int jt = 0; jt < 4; ++jt)                                      \
            _Pragma("unroll")                                               \
            for (int rr = 0; rr < 4; ++rr)                                  \
                Ilds[P][kg * 4 + rr][jt * 16 + r16] = acc[jt][rr];          \
    }

    L0_TILE(0, 0);
    for (int tt = 0; tt < ntile; ++tt) {
        __builtin_amdgcn_s_barrier();            // tile tt resident for all lanes
        float v[16];
#pragma unroll
        for (int u = 0; u < 16; ++u)
            v[u] = Ilds[tt & 1][u][lane];
        if (tt + 1 < ntile) L0_TILE(tt + 1, (tt + 1) & 1);
        unsigned short o[16];
#pragma unroll
        for (int u = 0; u < 16; ++u) {
            m = beta * m + (double)(v[u] + bj);
            bool sp = (m >= 1.0);
            o[u] = sp ? (unsigned short)0x3F80 : (unsigned short)0;
            m = sp ? 0.0 : m;
        }
#pragma unroll
        for (int u = 0; u < 16; ++u)
            ((unsigned short*)S)[(size_t)(tt * 16 + u) * stride + gid] = o[u];
    }
    mstate[gid] = m;
#undef L0_TILE
}

// hidden layer 1 scan: counted-vmcnt LDS double buffer (R9).
__global__ __launch_bounds__(64) void k_scan_hidden(
    const float* __restrict__ I, const float* __restrict__ bias,
    double* __restrict__ mstate, bf16* __restrict__ S, int Tc, double beta) {
    __shared__ __align__(16) float segA[SEGH * 64];
    __shared__ __align__(16) float segB[SEGH * 64];
    const int lane = threadIdx.x;
    const int gid  = blockIdx.x * 64 + lane;
    const int j = gid & (NH - 1);
    double m = mstate[gid];
    const float bj = bias[j];
    const size_t stride = (size_t)NB * NH;
    const int nseg = Tc / SEGH;                  // even (Tc % 400 == 0)

#define H_PREFETCH(SEGBUF, SIDX)                                            \
    {                                                                       \
        const float* src = I + (size_t)(SIDX) * SEGH * stride + gid;        \
        _Pragma("unroll")                                                   \
        for (int rr = 0; rr < SEGH; ++rr)                                   \
            __builtin_amdgcn_global_load_lds(                               \
                ASG(src + (size_t)rr * stride),                             \
                ASL(&SEGBUF[rr * 64]), 4, 0, 0);                            \
    }

#define H_PROC(SEGBUF, SIDX)                                                \
    {                                                                       \
        const int btt = (SIDX) * SEGH;                                      \
        _Pragma("unroll")                                                   \
        for (int sb = 0; sb < SEGH / 10; ++sb) {                            \
            float v[10];                                                    \
            _Pragma("unroll")                                               \
            for (int u = 0; u < 10; ++u)                                    \
                v[u] = SEGBUF[(sb * 10 + u) * 64 + lane];                   \
            unsigned short o[10];                                           \
            _Pragma("unroll")                                               \
            for (int u = 0; u < 10; ++u) {                                  \
                m = beta * m + (double)(v[u] + bj);                         \
                bool sp = (m >= 1.0);                                       \
                o[u] = sp ? (unsigned short)0x3F80 : (unsigned short)0;     \
                m = sp ? 0.0 : m;                                           \
            }                                                               \
            _Pragma("unroll")                                               \
            for (int u = 0; u < 10; ++u)                                    \
                ((unsigned short*)S)[(size_t)(btt + sb * 10 + u) * stride + gid] = o[u]; \
        }                                                                   \
    }

    H_PREFETCH(segA, 0);
    for (int s = 0; s < nseg; s += 2) {
        H_PREFETCH(segB, s + 1);
        asm volatile("s_waitcnt vmcnt(50)" ::: "memory"); // segA resident
        __builtin_amdgcn_sched_barrier(0);
        H_PROC(segA, s);
        if (s + 2 < nseg) {
            H_PREFETCH(segA, s + 2);
            asm volatile("s_waitcnt vmcnt(50)" ::: "memory"); // segB resident
        } else {
            asm volatile("s_waitcnt vmcnt(0)" ::: "memory");
        }
        __builtin_amdgcn_sched_barrier(0);
        H_PROC(segB, s + 1);
    }
    mstate[gid] = m;
#undef H_PREFETCH
#undef H_PROC
}

__global__ __launch_bounds__(256) void k_scan_out(
    const float* __restrict__ I2, const float* __restrict__ bias,
    double* __restrict__ mstate, float* __restrict__ out,
    int Tc, int t0, double beta) {
    __shared__ __align__(16) float segA[SEGO * 256];
    __shared__ __align__(16) float segB[SEGO * 256];
    const int tid  = threadIdx.x;
    const int lane = tid & 63;
    const int wave = tid >> 6;
    const int k = tid & 15;
    const int b = tid >> 4;
    double m = mstate[tid];
    float bj = (k < N_OUT) ? bias[k] : 0.f;
    const int nseg = Tc / SEGO;                  // even (Tc % 400 == 0)

#define O_PREFETCH(SEGBUF, SIDX)                                            \
    {                                                                       \
        const float* src = I2 + (size_t)(SIDX) * SEGO * 256 + wave * 64 + lane; \
        _Pragma("unroll 8")                                                 \
        for (int rr = 0; rr < SEGO; ++rr)                                   \
            __builtin_amdgcn_global_load_lds(                               \
                ASG(src + (size_t)rr * 256),                                \
                ASL(&SEGBUF[rr * 256 + wave * 64]), 4, 0, 0);               \
    }

#define O_PROC(SEGBUF, SIDX)                                                \
    {                                                                       \
        const int btt = (SIDX) * SEGO;                                      \
        _Pragma("unroll")                                                   \
        for (int sb = 0; sb < SEGO / 8; ++sb) {                             \
            float v[8];                                                     \
            _Pragma("unroll")                                               \
            for (int u = 0; u < 8; ++u)                                     \
                v[u] = SEGBUF[(sb * 8 + u) * 256 + tid];                    \
            float o[8];                                                     \
            _Pragma("unroll")                                               \
            for (int u = 0; u < 8; ++u) {                                   \
                m = beta * m + (double)(v[u] + bj);                         \
                bool sp = (m >= 1.0);                                       \
                o[u] = sp ? 1.f : 0.f;                                      \
                m = sp ? 0.0 : m;                                           \
            }                                                               \
            if (k < N_OUT) {                                                \
                _Pragma("unroll")                                           \
                for (int u = 0; u < 8; ++u)                                 \
                    out[((size_t)(t0 + btt + sb * 8 + u) * NB + b) * N_OUT + k] = o[u]; \
            }                                                               \
        }                                                                   \
    }

    O_PREFETCH(segA, 0);
    for (int s = 0; s < nseg; s += 2) {
        O_PREFETCH(segB, s + 1);
        asm volatile("s_waitcnt vmcnt(40)" ::: "memory"); // segA resident
        __builtin_amdgcn_sched_barrier(0);
        O_PROC(segA, s);
        if (s + 2 < nseg) {
            O_PREFETCH(segA, s + 2);
            asm volatile("s_waitcnt vmcnt(40)" ::: "memory"); // segB resident
        } else {
            asm volatile("s_waitcnt vmcnt(0)" ::: "memory");
        }
        __builtin_amdgcn_sched_barrier(0);
        O_PROC(segB, s + 1);
    }
    mstate[tid] = m;
#undef O_PREFETCH
#undef O_PROC
}

// ---------------- host ----------------

extern "C" void kernel_launch(void* const* d_in, const int* in_sizes, int n_in,
                              void* d_out, int out_size, void* d_ws, size_t ws_size,
                              hipStream_t stream) {
    const float* in_sp = (const float*)d_in[0];
    const float* W0 = (const float*)d_in[1];
    const float* b0 = (const float*)d_in[2];
    const float* W1 = (const float*)d_in[3];
    const float* b1 = (const float*)d_in[4];
    const float* W2 = (const float*)d_in[5];
    const float* b2 = (const float*)d_in[6];
    float* out = (float*)d_out;

    char* p = (char*)d_ws;
    auto carve = [&](size_t bytes) -> void* {
        char* r = p; p += (bytes + 255) & ~(size_t)255; return (void*)r;
    };
    u64*  MASK = (u64*)carve((size_t)T_STEPS * NB * 8);
    bf16* BT1  = (bf16*)carve((size_t)NH * 2 * NH * 2);
    bf16* BT2  = (bf16*)carve((size_t)128 * 2 * NH * 2);
    double* m0s = (double*)carve((size_t)NB * NH * 8);
    double* m1s = (double*)carve((size_t)NB * NH * 8);
    double* m2s = (double*)carve((size_t)NB * 16 * 8);
    size_t fixed = (size_t)(p - (char*)d_ws);

    // Tc | 4000, Tc % 400 == 0 (scan segs even; L0 tiles of 16), Mc % 256 == 0
    const int tc_opts[3] = {2000, 800, 400};
    int Tc = 400;
    for (int i = 0; i < 3; ++i) {
        size_t Mc_ = (size_t)tc_opts[i] * NB;
        size_t need = fixed
            + ((Mc_ * NH * 4 + 255) & ~(size_t)255)
            + ((Mc_ * 16 * 4 + 255) & ~(size_t)255)
            + ((Mc_ * NH * 2 + 255) & ~(size_t)255);
        if (need <= ws_size) { Tc = tc_opts[i]; break; }
    }
    size_t Mc = (size_t)Tc * NB;
    float* IBUF  = (float*)carve(Mc * NH * 4);
    float* I2BUF = (float*)carve(Mc * 16 * 4);
    bf16*  S     = (bf16*)carve(Mc * NH * 2);

    const int use8 = (Mc % 256 == 0);
    const double beta = exp(-0.25 / 10.0);

    // m0s/m1s/m2s contiguous: one zero kernel.
    int nM = NB * NH * 2 + NB * 16;
    k_zero<<<(nM + 255) / 256, 256, 0, stream>>>(m0s, nM);

    // input spike masks (one wave per (t,b))
    k_mask<<<(T_STEPS * NB * 64) / 256, 256, 0, stream>>>(in_sp, MASK, T_STEPS * NB);

    k_limbs<<<(NH * 2 * NH + 255) / 256, 256, 0, stream>>>(W1, BT1, NH, NH, NH, use8 ? 0 : 1);
    k_limbs<<<(128 * 2 * NH + 255) / 256, 256, 0, stream>>>(W2, BT2, NH, N_OUT, 128, 1);

    const int C = T_STEPS / Tc;
    const int gx = (int)(Mc / 128);
    const int gx8 = (int)(Mc / 256);
    for (int c = 0; c < C; ++c) {
        int t0 = c * Tc;
        // layer 0: fused MFMA scan (exact fp32 via limbs)
        k_scan_l0<<<256, 64, 0, stream>>>(MASK + (size_t)t0 * NB, W0, b0,
                                          m0s, S, Tc, beta);
        // layer 1 (256^2 8-phase kernel when shape permits)
        if (use8)
            k_gemm8<<<gx8 * 4, 512, 0, stream>>>(S, BT1, IBUF, gx8);
        else
            k_gemm<<<gx * 8, 256, 0, stream>>>(S, BT1, IBUF, NH, 2 * NH, NH, gx);
        k_scan_hidden<<<(NB * NH) / 64, 64, 0, stream>>>(IBUF, b1, m1s, S, Tc, beta);
        // layer 2 (compact 16-col C)
        k_gemm<<<gx, 256, 0, stream>>>(S, BT2, I2BUF, NH, 2 * NH, 16, gx);
        k_scan_out<<<1, 256, 0, stream>>>(I2BUF, b2, m2s, out, Tc, t0, beta);
    }
}

// Round 12
// 962.358 us; speedup vs baseline: 1.8582x; 1.0276x over previous
//
#include <hip/hip_runtime.h>
#include <hip/hip_bf16.h>
#include <math.h>

// SNN forward: 64 -> 1024 -> 1024 -> 10, T=4000, B=16, LIF beta=exp(-0.025),
// thr=1, hard reset to 0, Dale clamp W>=0.
// R12: layer-2 GEMM replaced by k_gemm_thin (N=16 tile, no LDS, A-BW-bound)
// -- the old path computed a full 128x128 tile and stored 16 cols (8x waste).
// L0: fused MFMA scan (R11). L1: 256^2 8-phase GEMM (T2/T3/T4/T5).
// Hidden/out scans: LDS-staged counted-vmcnt double buffer (R9).

#define T_STEPS 4000
#define NB 16
#define N_IN 64
#define NH 1024
#define N_OUT 10
#define SEGO 40           // scan_out segment rows; vmcnt(40) literal below
#define SEGH 50           // scan_hidden segment rows; vmcnt(50) literal below

typedef __attribute__((ext_vector_type(8))) short bf16x8;
typedef __attribute__((ext_vector_type(4))) float f32x4;
typedef __hip_bfloat16 bf16;
typedef unsigned long long u64;

#define ASG(p) (const __attribute__((address_space(1))) void*)(p)
#define ASL(p) (__attribute__((address_space(3))) void*)(p)

// ---------------- small utility kernels ----------------

__global__ void k_zero(double* p, int n) {
    int i = blockIdx.x * 256 + threadIdx.x;
    if (i < n) p[i] = 0.0;
}

// Build per-(t,b) 64-bit input spike masks. One wave per (t,b).
__global__ void k_mask(const float* __restrict__ in, u64* __restrict__ mask, int total) {
    int w = (blockIdx.x * 256 + threadIdx.x) >> 6;
    int lane = threadIdx.x & 63;
    if (w >= total) return;
    float v = in[(size_t)w * 64 + lane];
    u64 bal = __ballot(v > 0.5f);
    if (lane == 0) mask[w] = bal;
}

// Build BT[n][k2] (row-major [Npad x 2K]) from W [K x N] row-major.
// interleave=1: [hi64|lo64] alternating per source 64-block.
// interleave=0: plain [hi(0..K) | lo(0..K)] (A col = k2 & (K-1)).
__global__ void k_limbs(const float* __restrict__ W, bf16* __restrict__ BT,
                        int K, int N, int Npad, int interleave) {
    int idx = blockIdx.x * 256 + threadIdx.x;
    int total = Npad * 2 * K;
    if (idx >= total) return;
    int n  = idx / (2 * K);
    int k2 = idx - n * (2 * K);
    int k, lo;
    if (interleave) {
        int kt2 = k2 >> 6, kk = k2 & 63;
        k = ((kt2 >> 1) << 6) + kk;
        lo = kt2 & 1;
    } else {
        lo = (k2 >= K);
        k = lo ? (k2 - K) : k2;
    }
    float v = 0.f;
    if (n < N) {
        float w = fmaxf(W[(size_t)k * N + n], 0.f);      // Dale's law clamp
        float hi = __bfloat162float(__float2bfloat16(w));
        v = lo ? (w - hi) : w;
    }
    BT[idx] = __float2bfloat16(v);
}

// ---------------- thin GEMM (layer 2): C[M x 16] = A[M x 1024] @ BT^T ------
// BT [128 x 2048] plain [hi|lo]; only rows 0..15 (output cols) are read.
// No LDS, no barriers: per wave 32 M-rows x 16 cols, B frags from L2-hot BT,
// A frags as contiguous 16B loads. A-BW-bound by design.

__global__ __launch_bounds__(256) void k_gemm_thin(
    const bf16* __restrict__ A, const bf16* __restrict__ BT,
    float* __restrict__ C) {
    const int tid  = threadIdx.x;
    const int lane = tid & 63;
    const int wave = tid >> 6;
    const int r16 = lane & 15;
    const int kg  = lane >> 4;
    const int m0 = blockIdx.x * 128 + wave * 32;
    f32x4 acc0 = {}, acc1 = {};
    const bf16* a0 = A + (size_t)(m0 + r16) * 1024 + kg * 8;
    const bf16* a1 = A + (size_t)(m0 + 16 + r16) * 1024 + kg * 8;
    const bf16* bp = BT + (size_t)r16 * 2048 + kg * 8;
#pragma unroll 4
    for (int kt = 0; kt < 64; ++kt) {
        const int kb = kt * 32;
        const int ka = kb & 1023;             // A col wraps over the two limbs
        bf16x8 af0 = *(const bf16x8*)(a0 + ka);
        bf16x8 af1 = *(const bf16x8*)(a1 + ka);
        bf16x8 bfr = *(const bf16x8*)(bp + kb);
        acc0 = __builtin_amdgcn_mfma_f32_16x16x32_bf16(af0, bfr, acc0, 0, 0, 0);
        acc1 = __builtin_amdgcn_mfma_f32_16x16x32_bf16(af1, bfr, acc1, 0, 0, 0);
    }
    // D: row = kg*4 + rr, col = r16 (m89 mapping); ldc = 16
#pragma unroll
    for (int rr = 0; rr < 4; ++rr) {
        C[(size_t)(m0 + kg * 4 + rr) * 16 + r16] = acc0[rr];
        C[(size_t)(m0 + 16 + kg * 4 + rr) * 16 + r16] = acc1[rr];
    }
}

// ---------------- 256^2 8-phase GEMM (layer 1) ----------------
// Stage ordering invariant (R8): a region is staged only in a phase after all
// ds_reads of it have drained past a barrier (A at P3, B at P2).

__global__ __launch_bounds__(512) void k_gemm8(
    const bf16* __restrict__ A, const bf16* __restrict__ BT,
    float* __restrict__ C, int gx) {
    const int KA = 1024, K2 = 2048;
    const int kmask = KA - 1;
    const int nwg = gridDim.x;
    const int wg  = blockIdx.x;
    const int q = nwg >> 3, r = nwg & 7;
    const int xcd = wg & 7, idx0 = wg >> 3;
    const int swz = (xcd < r ? xcd * (q + 1) : r * (q + 1) + (xcd - r) * q) + idx0;
    const int gy = nwg / gx;              // 4
    const int n0 = (swz % gy) * 256;
    const int m0 = (swz / gy) * 256;

    __shared__ __align__(16) char LDS[131072];
    const int tid  = threadIdx.x;
    const int lane = tid & 63;
    const int wave = tid >> 6;
    const int wm = (wave >> 2) * 128;
    const int wn = (wave & 3) * 64;
    const int r16l = lane & 15;
    const int kg   = lane >> 4;
    const int hA   = wave >> 2;
    const int hB   = (wave & 3) >> 1;
    const int wn64 = wave & 1;

    const int po = (r16l * 64 + kg * 16) ^ (((r16l >> 3) & 1) << 5);
    const char* bA[2] = { LDS + hA * 16384 + po,
                          LDS + 65536 + hA * 16384 + po };
    const char* bB[2] = { LDS + 32768 + hB * 16384 + po,
                          LDS + 98304 + hB * 16384 + po };
    const int bOff = wn64 * 8192;

    int s_row[2], s_col[2];
#pragma unroll
    for (int rr = 0; rr < 2; ++rr) {
        int d = (rr * 512 + tid) * 16;
        int l = d ^ (((d >> 9) & 1) << 5);
        int sub = l >> 10;
        int w = l & 1023;
        s_row[rr] = (sub >> 1) * 16 + (w >> 6);
        s_col[rr] = ((sub & 1) * 64 + (w & 63)) >> 1;
    }

#define HBASE(BUF, OP, HALF) ((((BUF) * 2 + (OP)) * 2 + (HALF)) * 16384)
#define STAGE_A(BUF, HALF, K0)                                              \
    {                                                                       \
        _Pragma("unroll")                                                   \
        for (int rr = 0; rr < 2; ++rr)                                      \
            __builtin_amdgcn_global_load_lds(                               \
                ASG(A + (size_t)(m0 + (HALF) * 128 + s_row[rr]) * KA        \
                    + (((K0) + s_col[rr]) & kmask)),                        \
                ASL(LDS + HBASE(BUF, 0, HALF) + (rr * 512 + wave * 64) * 16), \
                16, 0, 0);                                                  \
    }
#define STAGE_B(BUF, HALF, K0)                                              \
    {                                                                       \
        _Pragma("unroll")                                                   \
        for (int rr = 0; rr < 2; ++rr)                                      \
            __builtin_amdgcn_global_load_lds(                               \
                ASG(BT + (size_t)(n0 + (HALF) * 128 + s_row[rr]) * K2       \
                    + (K0) + s_col[rr]),                                    \
                ASL(LDS + HBASE(BUF, 1, HALF) + (rr * 512 + wave * 64) * 16), \
                16, 0, 0);                                                  \
    }

    f32x4 acc[8][4] = {};
    bf16x8 a[4][2], b[4][2];

#define MM(MIB, NIB)                                                        \
    {                                                                       \
        _Pragma("unroll")                                                   \
        for (int i = 0; i < 4; ++i)                                         \
            _Pragma("unroll")                                               \
            for (int j = 0; j < 2; ++j) {                                   \
                acc[(MIB) + i][(NIB) + j] =                                 \
                    __builtin_amdgcn_mfma_f32_16x16x32_bf16(                \
                        a[i][0], b[(NIB) + j][0], acc[(MIB) + i][(NIB) + j], 0, 0, 0); \
                acc[(MIB) + i][(NIB) + j] =                                 \
                    __builtin_amdgcn_mfma_f32_16x16x32_bf16(                \
                        a[i][1], b[(NIB) + j][1], acc[(MIB) + i][(NIB) + j], 0, 0, 0); \
            }                                                               \
    }

#define PH_SYNC()                                                           \
    __builtin_amdgcn_s_barrier();                                           \
    asm volatile("s_waitcnt lgkmcnt(0)" ::: "memory");                      \
    __builtin_amdgcn_sched_barrier(0);

#define KTILE(BUF, SK)                                                      \
    {                                                                       \
        _Pragma("unroll")                                                   \
        for (int i = 0; i < 4; ++i) {                                       \
            a[i][0] = *(const bf16x8*)(bA[BUF] + i * 2048);                 \
            a[i][1] = *(const bf16x8*)(bA[BUF] + i * 2048 + 1024);          \
        }                                                                   \
        _Pragma("unroll")                                                   \
        for (int j = 0; j < 2; ++j) {                                       \
            b[j][0] = *(const bf16x8*)(bB[BUF] + bOff + j * 2048);          \
            b[j][1] = *(const bf16x8*)(bB[BUF] + bOff + j * 2048 + 1024);   \
        }                                                                   \
        PH_SYNC();                                                          \
        __builtin_amdgcn_s_setprio(1);                                      \
        MM(0, 0);                                                           \
        __builtin_amdgcn_s_setprio(0);                                      \
        __builtin_amdgcn_s_barrier();                                       \
        _Pragma("unroll")                                                   \
        for (int j = 0; j < 2; ++j) {                                       \
            b[2 + j][0] = *(const bf16x8*)(bB[BUF] + bOff + (2 + j) * 2048); \
            b[2 + j][1] = *(const bf16x8*)(bB[BUF] + bOff + (2 + j) * 2048 + 1024); \
        }                                                                   \
        PH_SYNC();                                                          \
        __builtin_amdgcn_s_setprio(1);                                      \
        MM(0, 2);                                                           \
        __builtin_amdgcn_s_setprio(0);                                      \
        __builtin_amdgcn_s_barrier();                                       \
        _Pragma("unroll")                                                   \
        for (int i = 0; i < 4; ++i) {                                       \
            a[i][0] = *(const bf16x8*)(bA[BUF] + (4 + i) * 2048);           \
            a[i][1] = *(const bf16x8*)(bA[BUF] + (4 + i) * 2048 + 1024);    \
        }                                                                   \
        STAGE_B(BUF, 0, SK);                                                \
        STAGE_B(BUF, 1, SK);                                                \
        PH_SYNC();                                                          \
        __builtin_amdgcn_s_setprio(1);                                      \
        MM(4, 0);                                                           \
        __builtin_amdgcn_s_setprio(0);                                      \
        __builtin_amdgcn_s_barrier();                                       \
        STAGE_A(BUF, 0, SK);                                                \
        STAGE_A(BUF, 1, SK);                                                \
        PH_SYNC();                                                          \
        __builtin_amdgcn_s_setprio(1);                                      \
        MM(4, 2);                                                           \
        __builtin_amdgcn_s_setprio(0);                                      \
        asm volatile("s_waitcnt vmcnt(8)" ::: "memory");                    \
        __builtin_amdgcn_sched_barrier(0);                                  \
        __builtin_amdgcn_s_barrier();                                       \
    }

    STAGE_A(0, 0, 0);  STAGE_A(0, 1, 0);  STAGE_B(0, 0, 0);  STAGE_B(0, 1, 0);
    STAGE_A(1, 0, 64); STAGE_A(1, 1, 64); STAGE_B(1, 0, 64); STAGE_B(1, 1, 64);
    asm volatile("s_waitcnt vmcnt(8)" ::: "memory");
    __builtin_amdgcn_sched_barrier(0);
    __builtin_amdgcn_s_barrier();

    for (int it = 0; it < 16; ++it) {
        const int k0  = it * 128;
        const int ksA = (k0 + 128) & (K2 - 1);
        const int ksB = (k0 + 192) & (K2 - 1);
        KTILE(0, ksA);
        KTILE(1, ksB);
    }
    asm volatile("s_waitcnt vmcnt(0)" ::: "memory");
    __builtin_amdgcn_sched_barrier(0);

#pragma unroll
    for (int mi = 0; mi < 8; ++mi)
#pragma unroll
        for (int ni = 0; ni < 4; ++ni)
#pragma unroll
            for (int rr = 0; rr < 4; ++rr) {
                int row = m0 + wm + mi * 16 + kg * 4 + rr;
                int col = n0 + wn + ni * 16 + r16l;
                C[(size_t)row * 1024 + col] = acc[mi][ni][rr];
            }
#undef KTILE
#undef PH_SYNC
#undef MM
#undef STAGE_A
#undef STAGE_B
#undef HBASE
}

// ---------------- LIF scan kernels (fp64 membranes) ----------------

// L0 fused scan via MFMA (R11). 256 blocks x 64 threads; block = (b, jgroup).
__global__ __launch_bounds__(64) void k_scan_l0(
    const u64* __restrict__ mask,          // [Tc][NB] for this chunk
    const float* __restrict__ W0,          // [64][1024] row-major
    const float* __restrict__ bias,
    double* __restrict__ mstate, bf16* __restrict__ S, int Tc, double beta) {
    __shared__ float Ilds[2][16][68];
    const int lane = threadIdx.x;
    const int gid  = blockIdx.x * 64 + lane;   // = b*1024 + q*64 + lane
    const int b  = blockIdx.x >> 4;
    const int q  = blockIdx.x & 15;
    const int j0 = q * 64;
    const int r16 = lane & 15;
    const int kg  = lane >> 4;
    bf16x8 bh[4][2], bl[4][2];
#pragma unroll
    for (int jt = 0; jt < 4; ++jt)
#pragma unroll
        for (int kk = 0; kk < 2; ++kk)
#pragma unroll
            for (int e = 0; e < 8; ++e) {
                int k = kk * 32 + kg * 8 + e;
                float w = fmaxf(W0[(size_t)k * 1024 + j0 + jt * 16 + r16], 0.f);
                bf16 h = __float2bfloat16(w);
                float hf = __bfloat162float(h);
                bf16 l = __float2bfloat16(w - hf);
                bh[jt][kk][e] = *(short*)&h;
                bl[jt][kk][e] = *(short*)&l;
            }
    double m = mstate[gid];
    const float bj = bias[j0 + lane];
    const size_t stride = (size_t)NB * NH;
    const int ntile = Tc / 16;

#define L0_TILE(TT, P)                                                      \
    {                                                                       \
        u64 msk = mask[(size_t)((TT) * 16 + r16) * NB + b];                 \
        f32x4 acc[4] = {};                                                  \
        _Pragma("unroll")                                                   \
        for (int kk = 0; kk < 2; ++kk) {                                    \
            unsigned byte8 = (unsigned)((msk >> (kk * 32 + kg * 8)) & 0xFF); \
            bf16x8 af;                                                      \
            _Pragma("unroll")                                               \
            for (int e = 0; e < 8; ++e)                                     \
                af[e] = ((byte8 >> e) & 1) ? (short)0x3F80 : (short)0;      \
            _Pragma("unroll")                                               \
            for (int jt = 0; jt < 4; ++jt) {                                \
                acc[jt] = __builtin_amdgcn_mfma_f32_16x16x32_bf16(          \
                    af, bh[jt][kk], acc[jt], 0, 0, 0);                      \
                acc[jt] = __builtin_amdgcn_mfma_f32_16x16x32_bf16(          \
                    af, bl[jt][kk], acc[jt], 0, 0, 0);                      \
            }                                                               \
        }                                                                   \
        _Pragma("unroll")                                                   \
        for (int jt = 0; jt < 4; ++jt)                                      \
            _Pragma("unroll")                                               \
            for (int rr = 0; rr < 4; ++rr)                                  \
                Ilds[P][kg * 4 + rr][jt * 16 + r16] = acc[jt][rr];          \
    }

    L0_TILE(0, 0);
    for (int tt = 0; tt < ntile; ++tt) {
        __builtin_amdgcn_s_barrier();            // 1-wave block: cheap ordering
        float v[16];
#pragma unroll
        for (int u = 0; u < 16; ++u)
            v[u] = Ilds[tt & 1][u][lane];
        if (tt + 1 < ntile) L0_TILE(tt + 1, (tt + 1) & 1);
        unsigned short o[16];
#pragma unroll
        for (int u = 0; u < 16; ++u) {
            m = beta * m + (double)(v[u] + bj);
            bool sp = (m >= 1.0);
            o[u] = sp ? (unsigned short)0x3F80 : (unsigned short)0;
            m = sp ? 0.0 : m;
        }
#pragma unroll
        for (int u = 0; u < 16; ++u)
            ((unsigned short*)S)[(size_t)(tt * 16 + u) * stride + gid] = o[u];
    }
    mstate[gid] = m;
#undef L0_TILE
}

// hidden layer 1 scan: counted-vmcnt LDS double buffer (R9).
__global__ __launch_bounds__(64) void k_scan_hidden(
    const float* __restrict__ I, const float* __restrict__ bias,
    double* __restrict__ mstate, bf16* __restrict__ S, int Tc, double beta) {
    __shared__ __align__(16) float segA[SEGH * 64];
    __shared__ __align__(16) float segB[SEGH * 64];
    const int lane = threadIdx.x;
    const int gid  = blockIdx.x * 64 + lane;
    const int j = gid & (NH - 1);
    double m = mstate[gid];
    const float bj = bias[j];
    const size_t stride = (size_t)NB * NH;
    const int nseg = Tc / SEGH;                  // even (Tc % 400 == 0)

#define H_PREFETCH(SEGBUF, SIDX)                                            \
    {                                                                       \
        const float* src = I + (size_t)(SIDX) * SEGH * stride + gid;        \
        _Pragma("unroll")                                                   \
        for (int rr = 0; rr < SEGH; ++rr)                                   \
            __builtin_amdgcn_global_load_lds(                               \
                ASG(src + (size_t)rr * stride),                             \
                ASL(&SEGBUF[rr * 64]), 4, 0, 0);                            \
    }

#define H_PROC(SEGBUF, SIDX)                                                \
    {                                                                       \
        const int btt = (SIDX) * SEGH;                                      \
        _Pragma("unroll")                                                   \
        for (int sb = 0; sb < SEGH / 10; ++sb) {                            \
            float v[10];                                                    \
            _Pragma("unroll")                                               \
            for (int u = 0; u < 10; ++u)                                    \
                v[u] = SEGBUF[(sb * 10 + u) * 64 + lane];                   \
            unsigned short o[10];                                           \
            _Pragma("unroll")                                               \
            for (int u = 0; u < 10; ++u) {                                  \
                m = beta * m + (double)(v[u] + bj);                         \
                bool sp = (m >= 1.0);                                       \
                o[u] = sp ? (unsigned short)0x3F80 : (unsigned short)0;     \
                m = sp ? 0.0 : m;                                           \
            }                                                               \
            _Pragma("unroll")                                               \
            for (int u = 0; u < 10; ++u)                                    \
                ((unsigned short*)S)[(size_t)(btt + sb * 10 + u) * stride + gid] = o[u]; \
        }                                                                   \
    }

    H_PREFETCH(segA, 0);
    for (int s = 0; s < nseg; s += 2) {
        H_PREFETCH(segB, s + 1);
        asm volatile("s_waitcnt vmcnt(50)" ::: "memory"); // segA resident
        __builtin_amdgcn_sched_barrier(0);
        H_PROC(segA, s);
        if (s + 2 < nseg) {
            H_PREFETCH(segA, s + 2);
            asm volatile("s_waitcnt vmcnt(50)" ::: "memory"); // segB resident
        } else {
            asm volatile("s_waitcnt vmcnt(0)" ::: "memory");
        }
        __builtin_amdgcn_sched_barrier(0);
        H_PROC(segB, s + 1);
    }
    mstate[gid] = m;
#undef H_PREFETCH
#undef H_PROC
}

__global__ __launch_bounds__(256) void k_scan_out(
    const float* __restrict__ I2, const float* __restrict__ bias,
    double* __restrict__ mstate, float* __restrict__ out,
    int Tc, int t0, double beta) {
    __shared__ __align__(16) float segA[SEGO * 256];
    __shared__ __align__(16) float segB[SEGO * 256];
    const int tid  = threadIdx.x;
    const int lane = tid & 63;
    const int wave = tid >> 6;
    const int k = tid & 15;
    const int b = tid >> 4;
    double m = mstate[tid];
    float bj = (k < N_OUT) ? bias[k] : 0.f;
    const int nseg = Tc / SEGO;                  // even (Tc % 400 == 0)

#define O_PREFETCH(SEGBUF, SIDX)                                            \
    {                                                                       \
        const float* src = I2 + (size_t)(SIDX) * SEGO * 256 + wave * 64 + lane; \
        _Pragma("unroll 8")                                                 \
        for (int rr = 0; rr < SEGO; ++rr)                                   \
            __builtin_amdgcn_global_load_lds(                               \
                ASG(src + (size_t)rr * 256),                                \
                ASL(&SEGBUF[rr * 256 + wave * 64]), 4, 0, 0);               \
    }

#define O_PROC(SEGBUF, SIDX)                                                \
    {                                                                       \
        const int btt = (SIDX) * SEGO;                                      \
        _Pragma("unroll")                                                   \
        for (int sb = 0; sb < SEGO / 8; ++sb) {                             \
            float v[8];                                                     \
            _Pragma("unroll")                                               \
            for (int u = 0; u < 8; ++u)                                     \
                v[u] = SEGBUF[(sb * 8 + u) * 256 + tid];                    \
            float o[8];                                                     \
            _Pragma("unroll")                                               \
            for (int u = 0; u < 8; ++u) {                                   \
                m = beta * m + (double)(v[u] + bj);                         \
                bool sp = (m >= 1.0);                                       \
                o[u] = sp ? 1.f : 0.f;                                      \
                m = sp ? 0.0 : m;                                           \
            }                                                               \
            if (k < N_OUT) {                                                \
                _Pragma("unroll")                                           \
                for (int u = 0; u < 8; ++u)                                 \
                    out[((size_t)(t0 + btt + sb * 8 + u) * NB + b) * N_OUT + k] = o[u]; \
            }                                                               \
        }                                                                   \
    }

    O_PREFETCH(segA, 0);
    for (int s = 0; s < nseg; s += 2) {
        O_PREFETCH(segB, s + 1);
        asm volatile("s_waitcnt vmcnt(40)" ::: "memory"); // segA resident
        __builtin_amdgcn_sched_barrier(0);
        O_PROC(segA, s);
        if (s + 2 < nseg) {
            O_PREFETCH(segA, s + 2);
            asm volatile("s_waitcnt vmcnt(40)" ::: "memory"); // segB resident
        } else {
            asm volatile("s_waitcnt vmcnt(0)" ::: "memory");
        }
        __builtin_amdgcn_sched_barrier(0);
        O_PROC(segB, s + 1);
    }
    mstate[tid] = m;
#undef O_PREFETCH
#undef O_PROC
}

// ---------------- host ----------------

extern "C" void kernel_launch(void* const* d_in, const int* in_sizes, int n_in,
                              void* d_out, int out_size, void* d_ws, size_t ws_size,
                              hipStream_t stream) {
    const float* in_sp = (const float*)d_in[0];
    const float* W0 = (const float*)d_in[1];
    const float* b0 = (const float*)d_in[2];
    const float* W1 = (const float*)d_in[3];
    const float* b1 = (const float*)d_in[4];
    const float* W2 = (const float*)d_in[5];
    const float* b2 = (const float*)d_in[6];
    float* out = (float*)d_out;

    char* p = (char*)d_ws;
    auto carve = [&](size_t bytes) -> void* {
        char* r = p; p += (bytes + 255) & ~(size_t)255; return (void*)r;
    };
    u64*  MASK = (u64*)carve((size_t)T_STEPS * NB * 8);
    bf16* BT1  = (bf16*)carve((size_t)NH * 2 * NH * 2);
    bf16* BT2  = (bf16*)carve((size_t)128 * 2 * NH * 2);
    double* m0s = (double*)carve((size_t)NB * NH * 8);
    double* m1s = (double*)carve((size_t)NB * NH * 8);
    double* m2s = (double*)carve((size_t)NB * 16 * 8);
    size_t fixed = (size_t)(p - (char*)d_ws);

    // Tc | 4000, Tc % 400 == 0 (scan segs even; L0 tiles of 16), Mc % 256 == 0
    const int tc_opts[3] = {2000, 800, 400};
    int Tc = 400;
    for (int i = 0; i < 3; ++i) {
        size_t Mc_ = (size_t)tc_opts[i] * NB;
        size_t need = fixed
            + ((Mc_ * NH * 4 + 255) & ~(size_t)255)
            + ((Mc_ * 16 * 4 + 255) & ~(size_t)255)
            + ((Mc_ * NH * 2 + 255) & ~(size_t)255);
        if (need <= ws_size) { Tc = tc_opts[i]; break; }
    }
    size_t Mc = (size_t)Tc * NB;
    float* IBUF  = (float*)carve(Mc * NH * 4);
    float* I2BUF = (float*)carve(Mc * 16 * 4);
    bf16*  S     = (bf16*)carve(Mc * NH * 2);

    const int use8 = (Mc % 256 == 0);
    const double beta = exp(-0.25 / 10.0);

    // m0s/m1s/m2s contiguous: one zero kernel.
    int nM = NB * NH * 2 + NB * 16;
    k_zero<<<(nM + 255) / 256, 256, 0, stream>>>(m0s, nM);

    // input spike masks (one wave per (t,b))
    k_mask<<<(T_STEPS * NB * 64) / 256, 256, 0, stream>>>(in_sp, MASK, T_STEPS * NB);

    k_limbs<<<(NH * 2 * NH + 255) / 256, 256, 0, stream>>>(W1, BT1, NH, NH, NH, use8 ? 0 : 1);
    k_limbs<<<(128 * 2 * NH + 255) / 256, 256, 0, stream>>>(W2, BT2, NH, N_OUT, 128, 0);

    const int C = T_STEPS / Tc;
    const int gx = (int)(Mc / 128);
    const int gx8 = (int)(Mc / 256);
    for (int c = 0; c < C; ++c) {
        int t0 = c * Tc;
        // layer 0: fused MFMA scan (exact fp32 via limbs)
        k_scan_l0<<<256, 64, 0, stream>>>(MASK + (size_t)t0 * NB, W0, b0,
                                          m0s, S, Tc, beta);
        // layer 1 (256^2 8-phase kernel)
        if (use8)
            k_gemm8<<<gx8 * 4, 512, 0, stream>>>(S, BT1, IBUF, gx8);
        k_scan_hidden<<<(NB * NH) / 64, 64, 0, stream>>>(IBUF, b1, m1s, S, Tc, beta);
        // layer 2: thin GEMM (N=16)
        k_gemm_thin<<<gx, 256, 0, stream>>>(S, BT2, I2BUF);
        k_scan_out<<<1, 256, 0, stream>>>(I2BUF, b2, m2s, out, Tc, t0, beta);
    }
}

// Round 13
// 920.638 us; speedup vs baseline: 1.9424x; 1.0453x over previous
//
#include <hip/hip_runtime.h>
#include <hip/hip_bf16.h>
#include <math.h>

// SNN forward: 64 -> 1024 -> 1024 -> 10, T=4000, B=16, LIF beta=exp(-0.025),
// thr=1, hard reset to 0, Dale clamp W>=0.
// R13: scan_l0 mask load software-pipelined one tile ahead (R12 postmortem:
// the in-macro mask load exposed ~400cy L2 latency per 16-step tile on a
// 1-wave/CU serial chain). k_limbs_t: LDS-transpose limb builder for BT1
// (old version did stride-4KB scattered reads). Unused 128^2 GEMM removed.
// L0: fused MFMA scan. L1: 256^2 8-phase GEMM (T2/T3/T4/T5).
// L2: thin N=16 GEMM. Scans: LDS-staged counted-vmcnt double buffer.

#define T_STEPS 4000
#define NB 16
#define N_IN 64
#define NH 1024
#define N_OUT 10
#define SEGO 40           // scan_out segment rows; vmcnt(40) literal below
#define SEGH 50           // scan_hidden segment rows; vmcnt(50) literal below

typedef __attribute__((ext_vector_type(8))) short bf16x8;
typedef __attribute__((ext_vector_type(4))) float f32x4;
typedef __hip_bfloat16 bf16;
typedef unsigned long long u64;

#define ASG(p) (const __attribute__((address_space(1))) void*)(p)
#define ASL(p) (__attribute__((address_space(3))) void*)(p)

// ---------------- small utility kernels ----------------

__global__ void k_zero(double* p, int n) {
    int i = blockIdx.x * 256 + threadIdx.x;
    if (i < n) p[i] = 0.0;
}

// Build per-(t,b) 64-bit input spike masks. One wave per (t,b).
__global__ void k_mask(const float* __restrict__ in, u64* __restrict__ mask, int total) {
    int w = (blockIdx.x * 256 + threadIdx.x) >> 6;
    int lane = threadIdx.x & 63;
    if (w >= total) return;
    float v = in[(size_t)w * 64 + lane];
    u64 bal = __ballot(v > 0.5f);
    if (lane == 0) mask[w] = bal;
}

// Transposing limb builder for BT1: W [1024 x 1024] -> BT [1024][2048],
// plain [hi | lo]. Coalesced reads (64 consecutive n per wave), LDS
// transpose ([64][65] pad -> conflict-free), coalesced 128B writes.
__global__ __launch_bounds__(256) void k_limbs_t(
    const float* __restrict__ W, bf16* __restrict__ BT) {
    __shared__ float Wlds[64][65];
    const int tid  = threadIdx.x;
    const int lane = tid & 63;
    const int wr   = tid >> 6;            // 0..3
    const int k0 = (blockIdx.x & 15) * 64;
    const int n0 = (blockIdx.x >> 4) * 64;
#pragma unroll
    for (int rr = 0; rr < 16; ++rr) {
        int kl = wr * 16 + rr;
        Wlds[kl][lane] = W[(size_t)(k0 + kl) * 1024 + n0 + lane];
    }
    __syncthreads();
#pragma unroll
    for (int rr = 0; rr < 16; ++rr) {
        int nl = wr * 16 + rr;
        float w = fmaxf(Wlds[lane][nl], 0.f);      // Dale's law clamp
        bf16 h = __float2bfloat16(w);
        float hf = __bfloat162float(h);
        bf16 l = __float2bfloat16(w - hf);
        size_t base = (size_t)(n0 + nl) * 2048 + k0 + lane;
        BT[base] = h;
        BT[base + 1024] = l;
    }
}

// Small limb builder (BT2): W [K x N] -> BT [Npad x 2K] plain [hi|lo].
__global__ void k_limbs(const float* __restrict__ W, bf16* __restrict__ BT,
                        int K, int N, int Npad) {
    int idx = blockIdx.x * 256 + threadIdx.x;
    int total = Npad * 2 * K;
    if (idx >= total) return;
    int n  = idx / (2 * K);
    int k2 = idx - n * (2 * K);
    int lo = (k2 >= K);
    int k = lo ? (k2 - K) : k2;
    float v = 0.f;
    if (n < N) {
        float w = fmaxf(W[(size_t)k * N + n], 0.f);
        float hi = __bfloat162float(__float2bfloat16(w));
        v = lo ? (w - hi) : w;
    }
    BT[idx] = __float2bfloat16(v);
}

// ---------------- thin GEMM (layer 2): C[M x 16] = A[M x 1024] @ BT^T ------
// BT [128 x 2048] plain [hi|lo]; only rows 0..15 (output cols) are read.
// No LDS, no barriers; A-BW-bound by design.

__global__ __launch_bounds__(256) void k_gemm_thin(
    const bf16* __restrict__ A, const bf16* __restrict__ BT,
    float* __restrict__ C) {
    const int tid  = threadIdx.x;
    const int lane = tid & 63;
    const int wave = tid >> 6;
    const int r16 = lane & 15;
    const int kg  = lane >> 4;
    const int m0 = blockIdx.x * 128 + wave * 32;
    f32x4 acc0 = {}, acc1 = {};
    const bf16* a0 = A + (size_t)(m0 + r16) * 1024 + kg * 8;
    const bf16* a1 = A + (size_t)(m0 + 16 + r16) * 1024 + kg * 8;
    const bf16* bp = BT + (size_t)r16 * 2048 + kg * 8;
#pragma unroll 4
    for (int kt = 0; kt < 64; ++kt) {
        const int kb = kt * 32;
        const int ka = kb & 1023;             // A col wraps over the two limbs
        bf16x8 af0 = *(const bf16x8*)(a0 + ka);
        bf16x8 af1 = *(const bf16x8*)(a1 + ka);
        bf16x8 bfr = *(const bf16x8*)(bp + kb);
        acc0 = __builtin_amdgcn_mfma_f32_16x16x32_bf16(af0, bfr, acc0, 0, 0, 0);
        acc1 = __builtin_amdgcn_mfma_f32_16x16x32_bf16(af1, bfr, acc1, 0, 0, 0);
    }
#pragma unroll
    for (int rr = 0; rr < 4; ++rr) {
        C[(size_t)(m0 + kg * 4 + rr) * 16 + r16] = acc0[rr];
        C[(size_t)(m0 + 16 + kg * 4 + rr) * 16 + r16] = acc1[rr];
    }
}

// ---------------- 256^2 8-phase GEMM (layer 1) ----------------
// Stage ordering invariant (R8): a region is staged only in a phase after all
// ds_reads of it have drained past a barrier (A at P3, B at P2).

__global__ __launch_bounds__(512) void k_gemm8(
    const bf16* __restrict__ A, const bf16* __restrict__ BT,
    float* __restrict__ C, int gx) {
    const int KA = 1024, K2 = 2048;
    const int kmask = KA - 1;
    const int nwg = gridDim.x;
    const int wg  = blockIdx.x;
    const int q = nwg >> 3, r = nwg & 7;
    const int xcd = wg & 7, idx0 = wg >> 3;
    const int swz = (xcd < r ? xcd * (q + 1) : r * (q + 1) + (xcd - r) * q) + idx0;
    const int gy = nwg / gx;              // 4
    const int n0 = (swz % gy) * 256;
    const int m0 = (swz / gy) * 256;

    __shared__ __align__(16) char LDS[131072];
    const int tid  = threadIdx.x;
    const int lane = tid & 63;
    const int wave = tid >> 6;
    const int wm = (wave >> 2) * 128;
    const int wn = (wave & 3) * 64;
    const int r16l = lane & 15;
    const int kg   = lane >> 4;
    const int hA   = wave >> 2;
    const int hB   = (wave & 3) >> 1;
    const int wn64 = wave & 1;

    const int po = (r16l * 64 + kg * 16) ^ (((r16l >> 3) & 1) << 5);
    const char* bA[2] = { LDS + hA * 16384 + po,
                          LDS + 65536 + hA * 16384 + po };
    const char* bB[2] = { LDS + 32768 + hB * 16384 + po,
                          LDS + 98304 + hB * 16384 + po };
    const int bOff = wn64 * 8192;

    int s_row[2], s_col[2];
#pragma unroll
    for (int rr = 0; rr < 2; ++rr) {
        int d = (rr * 512 + tid) * 16;
        int l = d ^ (((d >> 9) & 1) << 5);
        int sub = l >> 10;
        int w = l & 1023;
        s_row[rr] = (sub >> 1) * 16 + (w >> 6);
        s_col[rr] = ((sub & 1) * 64 + (w & 63)) >> 1;
    }

#define HBASE(BUF, OP, HALF) ((((BUF) * 2 + (OP)) * 2 + (HALF)) * 16384)
#define STAGE_A(BUF, HALF, K0)                                              \
    {                                                                       \
        _Pragma("unroll")                                                   \
        for (int rr = 0; rr < 2; ++rr)                                      \
            __builtin_amdgcn_global_load_lds(                               \
                ASG(A + (size_t)(m0 + (HALF) * 128 + s_row[rr]) * KA        \
                    + (((K0) + s_col[rr]) & kmask)),                        \
                ASL(LDS + HBASE(BUF, 0, HALF) + (rr * 512 + wave * 64) * 16), \
                16, 0, 0);                                                  \
    }
#define STAGE_B(BUF, HALF, K0)                                              \
    {                                                                       \
        _Pragma("unroll")                                                   \
        for (int rr = 0; rr < 2; ++rr)                                      \
            __builtin_amdgcn_global_load_lds(                               \
                ASG(BT + (size_t)(n0 + (HALF) * 128 + s_row[rr]) * K2       \
                    + (K0) + s_col[rr]),                                    \
                ASL(LDS + HBASE(BUF, 1, HALF) + (rr * 512 + wave * 64) * 16), \
                16, 0, 0);                                                  \
    }

    f32x4 acc[8][4] = {};
    bf16x8 a[4][2], b[4][2];

#define MM(MIB, NIB)                                                        \
    {                                                                       \
        _Pragma("unroll")                                                   \
        for (int i = 0; i < 4; ++i)                                         \
            _Pragma("unroll")                                               \
            for (int j = 0; j < 2; ++j) {                                   \
                acc[(MIB) + i][(NIB) + j] =                                 \
                    __builtin_amdgcn_mfma_f32_16x16x32_bf16(                \
                        a[i][0], b[(NIB) + j][0], acc[(MIB) + i][(NIB) + j], 0, 0, 0); \
                acc[(MIB) + i][(NIB) + j] =                                 \
                    __builtin_amdgcn_mfma_f32_16x16x32_bf16(                \
                        a[i][1], b[(NIB) + j][1], acc[(MIB) + i][(NIB) + j], 0, 0, 0); \
            }                                                               \
    }

#define PH_SYNC()                                                           \
    __builtin_amdgcn_s_barrier();                                           \
    asm volatile("s_waitcnt lgkmcnt(0)" ::: "memory");                      \
    __builtin_amdgcn_sched_barrier(0);

#define KTILE(BUF, SK)                                                      \
    {                                                                       \
        _Pragma("unroll")                                                   \
        for (int i = 0; i < 4; ++i) {                                       \
            a[i][0] = *(const bf16x8*)(bA[BUF] + i * 2048);                 \
            a[i][1] = *(const bf16x8*)(bA[BUF] + i * 2048 + 1024);          \
        }                                                                   \
        _Pragma("unroll")                                                   \
        for (int j = 0; j < 2; ++j) {                                       \
            b[j][0] = *(const bf16x8*)(bB[BUF] + bOff + j * 2048);          \
            b[j][1] = *(const bf16x8*)(bB[BUF] + bOff + j * 2048 + 1024);   \
        }                                                                   \
        PH_SYNC();                                                          \
        __builtin_amdgcn_s_setprio(1);                                      \
        MM(0, 0);                                                           \
        __builtin_amdgcn_s_setprio(0);                                      \
        __builtin_amdgcn_s_barrier();                                       \
        _Pragma("unroll")                                                   \
        for (int j = 0; j < 2; ++j) {                                       \
            b[2 + j][0] = *(const bf16x8*)(bB[BUF] + bOff + (2 + j) * 2048); \
            b[2 + j][1] = *(const bf16x8*)(bB[BUF] + bOff + (2 + j) * 2048 + 1024); \
        }                                                                   \
        PH_SYNC();                                                          \
        __builtin_amdgcn_s_setprio(1);                                      \
        MM(0, 2);                                                           \
        __builtin_amdgcn_s_setprio(0);                                      \
        __builtin_amdgcn_s_barrier();                                       \
        _Pragma("unroll")                                                   \
        for (int i = 0; i < 4; ++i) {                                       \
            a[i][0] = *(const bf16x8*)(bA[BUF] + (4 + i) * 2048);           \
            a[i][1] = *(const bf16x8*)(bA[BUF] + (4 + i) * 2048 + 1024);    \
        }                                                                   \
        STAGE_B(BUF, 0, SK);                                                \
        STAGE_B(BUF, 1, SK);                                                \
        PH_SYNC();                                                          \
        __builtin_amdgcn_s_setprio(1);                                      \
        MM(4, 0);                                                           \
        __builtin_amdgcn_s_setprio(0);                                      \
        __builtin_amdgcn_s_barrier();                                       \
        STAGE_A(BUF, 0, SK);                                                \
        STAGE_A(BUF, 1, SK);                                                \
        PH_SYNC();                                                          \
        __builtin_amdgcn_s_setprio(1);                                      \
        MM(4, 2);                                                           \
        __builtin_amdgcn_s_setprio(0);                                      \
        asm volatile("s_waitcnt vmcnt(8)" ::: "memory");                    \
        __builtin_amdgcn_sched_barrier(0);                                  \
        __builtin_amdgcn_s_barrier();                                       \
    }

    STAGE_A(0, 0, 0);  STAGE_A(0, 1, 0);  STAGE_B(0, 0, 0);  STAGE_B(0, 1, 0);
    STAGE_A(1, 0, 64); STAGE_A(1, 1, 64); STAGE_B(1, 0, 64); STAGE_B(1, 1, 64);
    asm volatile("s_waitcnt vmcnt(8)" ::: "memory");
    __builtin_amdgcn_sched_barrier(0);
    __builtin_amdgcn_s_barrier();

    for (int it = 0; it < 16; ++it) {
        const int k0  = it * 128;
        const int ksA = (k0 + 128) & (K2 - 1);
        const int ksB = (k0 + 192) & (K2 - 1);
        KTILE(0, ksA);
        KTILE(1, ksB);
    }
    asm volatile("s_waitcnt vmcnt(0)" ::: "memory");
    __builtin_amdgcn_sched_barrier(0);

#pragma unroll
    for (int mi = 0; mi < 8; ++mi)
#pragma unroll
        for (int ni = 0; ni < 4; ++ni)
#pragma unroll
            for (int rr = 0; rr < 4; ++rr) {
                int row = m0 + wm + mi * 16 + kg * 4 + rr;
                int col = n0 + wn + ni * 16 + r16l;
                C[(size_t)row * 1024 + col] = acc[mi][ni][rr];
            }
#undef KTILE
#undef PH_SYNC
#undef MM
#undef STAGE_A
#undef STAGE_B
#undef HBASE
}

// ---------------- LIF scan kernels (fp64 membranes) ----------------

// L0 fused scan via MFMA + mask software-pipeline (R13). 256 blocks x 64
// threads; block = (b, jgroup). W0 slice in registers as B-frags (hi+lo).
// The mask for tile tt+1 is loaded a full iteration early (issue at tt's
// v[]-read, consume at tt+1's compute) so its L2 latency hides under the
// fp64 chain instead of serializing every tile.
__global__ __launch_bounds__(64) void k_scan_l0(
    const u64* __restrict__ mask,          // [Tc][NB] for this chunk
    const float* __restrict__ W0,          // [64][1024] row-major
    const float* __restrict__ bias,
    double* __restrict__ mstate, bf16* __restrict__ S, int Tc, double beta) {
    __shared__ float Ilds[2][16][68];
    const int lane = threadIdx.x;
    const int gid  = blockIdx.x * 64 + lane;   // = b*1024 + q*64 + lane
    const int b  = blockIdx.x >> 4;
    const int q  = blockIdx.x & 15;
    const int j0 = q * 64;
    const int r16 = lane & 15;
    const int kg  = lane >> 4;
    bf16x8 bh[4][2], bl[4][2];
#pragma unroll
    for (int jt = 0; jt < 4; ++jt)
#pragma unroll
        for (int kk = 0; kk < 2; ++kk)
#pragma unroll
            for (int e = 0; e < 8; ++e) {
                int k = kk * 32 + kg * 8 + e;
                float w = fmaxf(W0[(size_t)k * 1024 + j0 + jt * 16 + r16], 0.f);
                bf16 h = __float2bfloat16(w);
                float hf = __bfloat162float(h);
                bf16 l = __float2bfloat16(w - hf);
                bh[jt][kk][e] = *(short*)&h;
                bl[jt][kk][e] = *(short*)&l;
            }
    double m = mstate[gid];
    const float bj = bias[j0 + lane];
    const size_t stride = (size_t)NB * NH;
    const int ntile = Tc / 16;
    const int tmax = ntile - 1;

#define LOADM(TT) mask[(size_t)(((TT) <= tmax ? (TT) : tmax) * 16 + r16) * NB + b]

#define L0_COMPUTE(MSK, P)                                                  \
    {                                                                       \
        f32x4 acc[4] = {};                                                  \
        _Pragma("unroll")                                                   \
        for (int kk = 0; kk < 2; ++kk) {                                    \
            unsigned byte8 = (unsigned)(((MSK) >> (kk * 32 + kg * 8)) & 0xFF); \
            bf16x8 af;                                                      \
            _Pragma("unroll")                                               \
            for (int e = 0; e < 8; ++e)                                     \
                af[e] = ((byte8 >> e) & 1) ? (short)0x3F80 : (short)0;      \
            _Pragma("unroll")                                               \
            for (int jt = 0; jt < 4; ++jt) {                                \
                acc[jt] = __builtin_amdgcn_mfma_f32_16x16x32_bf16(          \
                    af, bh[jt][kk], acc[jt], 0, 0, 0);                      \
                acc[jt] = __builtin_amdgcn_mfma_f32_16x16x32_bf16(          \
                    af, bl[jt][kk], acc[jt], 0, 0, 0);                      \
            }                                                               \
        }                                                                   \
        _Pragma("unroll")                                                   \
        for (int jt = 0; jt < 4; ++jt)                                      \
            _Pragma("unroll")                                               \
            for (int rr = 0; rr < 4; ++rr)                                  \
                Ilds[P][kg * 4 + rr][jt * 16 + r16] = acc[jt][rr];          \
    }

    u64 mc = LOADM(0);
    L0_COMPUTE(mc, 0);
    u64 mn = LOADM(1);                           // in flight for tile 1
    for (int tt = 0; tt < ntile; ++tt) {
        __builtin_amdgcn_s_barrier();            // tile tt resident
        float v[16];
#pragma unroll
        for (int u = 0; u < 16; ++u)
            v[u] = Ilds[tt & 1][u][lane];
        u64 m2 = LOADM(tt + 2);                  // issue early (used next iter)
        if (tt + 1 < ntile) L0_COMPUTE(mn, (tt + 1) & 1);
        unsigned short o[16];
#pragma unroll
        for (int u = 0; u < 16; ++u) {
            m = beta * m + (double)(v[u] + bj);
            bool sp = (m >= 1.0);
            o[u] = sp ? (unsigned short)0x3F80 : (unsigned short)0;
            m = sp ? 0.0 : m;
        }
#pragma unroll
        for (int u = 0; u < 16; ++u)
            ((unsigned short*)S)[(size_t)(tt * 16 + u) * stride + gid] = o[u];
        mn = m2;
    }
    mstate[gid] = m;
#undef L0_COMPUTE
#undef LOADM
}

// hidden layer 1 scan: counted-vmcnt LDS double buffer (R9).
__global__ __launch_bounds__(64) void k_scan_hidden(
    const float* __restrict__ I, const float* __restrict__ bias,
    double* __restrict__ mstate, bf16* __restrict__ S, int Tc, double beta) {
    __shared__ __align__(16) float segA[SEGH * 64];
    __shared__ __align__(16) float segB[SEGH * 64];
    const int lane = threadIdx.x;
    const int gid  = blockIdx.x * 64 + lane;
    const int j = gid & (NH - 1);
    double m = mstate[gid];
    const float bj = bias[j];
    const size_t stride = (size_t)NB * NH;
    const int nseg = Tc / SEGH;                  // even (Tc % 400 == 0)

#define H_PREFETCH(SEGBUF, SIDX)                                            \
    {                                                                       \
        const float* src = I + (size_t)(SIDX) * SEGH * stride + gid;        \
        _Pragma("unroll")                                                   \
        for (int rr = 0; rr < SEGH; ++rr)                                   \
            __builtin_amdgcn_global_load_lds(                               \
                ASG(src + (size_t)rr * stride),                             \
                ASL(&SEGBUF[rr * 64]), 4, 0, 0);                            \
    }

#define H_PROC(SEGBUF, SIDX)                                                \
    {                                                                       \
        const int btt = (SIDX) * SEGH;                                      \
        _Pragma("unroll")                                                   \
        for (int sb = 0; sb < SEGH / 10; ++sb) {                            \
            float v[10];                                                    \
            _Pragma("unroll")                                               \
            for (int u = 0; u < 10; ++u)                                    \
                v[u] = SEGBUF[(sb * 10 + u) * 64 + lane];                   \
            unsigned short o[10];                                           \
            _Pragma("unroll")                                               \
            for (int u = 0; u < 10; ++u) {                                  \
                m = beta * m + (double)(v[u] + bj);                         \
                bool sp = (m >= 1.0);                                       \
                o[u] = sp ? (unsigned short)0x3F80 : (unsigned short)0;     \
                m = sp ? 0.0 : m;                                           \
            }                                                               \
            _Pragma("unroll")                                               \
            for (int u = 0; u < 10; ++u)                                    \
                ((unsigned short*)S)[(size_t)(btt + sb * 10 + u) * stride + gid] = o[u]; \
        }                                                                   \
    }

    H_PREFETCH(segA, 0);
    for (int s = 0; s < nseg; s += 2) {
        H_PREFETCH(segB, s + 1);
        asm volatile("s_waitcnt vmcnt(50)" ::: "memory"); // segA resident
        __builtin_amdgcn_sched_barrier(0);
        H_PROC(segA, s);
        if (s + 2 < nseg) {
            H_PREFETCH(segA, s + 2);
            asm volatile("s_waitcnt vmcnt(50)" ::: "memory"); // segB resident
        } else {
            asm volatile("s_waitcnt vmcnt(0)" ::: "memory");
        }
        __builtin_amdgcn_sched_barrier(0);
        H_PROC(segB, s + 1);
    }
    mstate[gid] = m;
#undef H_PREFETCH
#undef H_PROC
}

__global__ __launch_bounds__(256) void k_scan_out(
    const float* __restrict__ I2, const float* __restrict__ bias,
    double* __restrict__ mstate, float* __restrict__ out,
    int Tc, int t0, double beta) {
    __shared__ __align__(16) float segA[SEGO * 256];
    __shared__ __align__(16) float segB[SEGO * 256];
    const int tid  = threadIdx.x;
    const int lane = tid & 63;
    const int wave = tid >> 6;
    const int k = tid & 15;
    const int b = tid >> 4;
    double m = mstate[tid];
    float bj = (k < N_OUT) ? bias[k] : 0.f;
    const int nseg = Tc / SEGO;                  // even (Tc % 400 == 0)

#define O_PREFETCH(SEGBUF, SIDX)                                            \
    {                                                                       \
        const float* src = I2 + (size_t)(SIDX) * SEGO * 256 + wave * 64 + lane; \
        _Pragma("unroll 8")                                                 \
        for (int rr = 0; rr < SEGO; ++rr)                                   \
            __builtin_amdgcn_global_load_lds(                               \
                ASG(src + (size_t)rr * 256),                                \
                ASL(&SEGBUF[rr * 256 + wave * 64]), 4, 0, 0);               \
    }

#define O_PROC(SEGBUF, SIDX)                                                \
    {                                                                       \
        const int btt = (SIDX) * SEGO;                                      \
        _Pragma("unroll")                                                   \
        for (int sb = 0; sb < SEGO / 8; ++sb) {                             \
            float v[8];                                                     \
            _Pragma("unroll")                                               \
            for (int u = 0; u < 8; ++u)                                     \
                v[u] = SEGBUF[(sb * 8 + u) * 256 + tid];                    \
            float o[8];                                                     \
            _Pragma("unroll")                                               \
            for (int u = 0; u < 8; ++u) {                                   \
                m = beta * m + (double)(v[u] + bj);                         \
                bool sp = (m >= 1.0);                                       \
                o[u] = sp ? 1.f : 0.f;                                      \
                m = sp ? 0.0 : m;                                           \
            }                                                               \
            if (k < N_OUT) {                                                \
                _Pragma("unroll")                                           \
                for (int u = 0; u < 8; ++u)                                 \
                    out[((size_t)(t0 + btt + sb * 8 + u) * NB + b) * N_OUT + k] = o[u]; \
            }                                                               \
        }                                                                   \
    }

    O_PREFETCH(segA, 0);
    for (int s = 0; s < nseg; s += 2) {
        O_PREFETCH(segB, s + 1);
        asm volatile("s_waitcnt vmcnt(40)" ::: "memory"); // segA resident
        __builtin_amdgcn_sched_barrier(0);
        O_PROC(segA, s);
        if (s + 2 < nseg) {
            O_PREFETCH(segA, s + 2);
            asm volatile("s_waitcnt vmcnt(40)" ::: "memory"); // segB resident
        } else {
            asm volatile("s_waitcnt vmcnt(0)" ::: "memory");
        }
        __builtin_amdgcn_sched_barrier(0);
        O_PROC(segB, s + 1);
    }
    mstate[tid] = m;
#undef O_PREFETCH
#undef O_PROC
}

// ---------------- host ----------------

extern "C" void kernel_launch(void* const* d_in, const int* in_sizes, int n_in,
                              void* d_out, int out_size, void* d_ws, size_t ws_size,
                              hipStream_t stream) {
    const float* in_sp = (const float*)d_in[0];
    const float* W0 = (const float*)d_in[1];
    const float* b0 = (const float*)d_in[2];
    const float* W1 = (const float*)d_in[3];
    const float* b1 = (const float*)d_in[4];
    const float* W2 = (const float*)d_in[5];
    const float* b2 = (const float*)d_in[6];
    float* out = (float*)d_out;

    char* p = (char*)d_ws;
    auto carve = [&](size_t bytes) -> void* {
        char* r = p; p += (bytes + 255) & ~(size_t)255; return (void*)r;
    };
    u64*  MASK = (u64*)carve((size_t)T_STEPS * NB * 8);
    bf16* BT1  = (bf16*)carve((size_t)NH * 2 * NH * 2);
    bf16* BT2  = (bf16*)carve((size_t)128 * 2 * NH * 2);
    double* m0s = (double*)carve((size_t)NB * NH * 8);
    double* m1s = (double*)carve((size_t)NB * NH * 8);
    double* m2s = (double*)carve((size_t)NB * 16 * 8);
    size_t fixed = (size_t)(p - (char*)d_ws);

    // Tc | 4000, Tc % 400 == 0 (scan segs even; L0 tiles of 16; Mc % 256 == 0)
    const int tc_opts[3] = {2000, 800, 400};
    int Tc = 400;
    for (int i = 0; i < 3; ++i) {
        size_t Mc_ = (size_t)tc_opts[i] * NB;
        size_t need = fixed
            + ((Mc_ * NH * 4 + 255) & ~(size_t)255)
            + ((Mc_ * 16 * 4 + 255) & ~(size_t)255)
            + ((Mc_ * NH * 2 + 255) & ~(size_t)255);
        if (need <= ws_size) { Tc = tc_opts[i]; break; }
    }
    size_t Mc = (size_t)Tc * NB;
    float* IBUF  = (float*)carve(Mc * NH * 4);
    float* I2BUF = (float*)carve(Mc * 16 * 4);
    bf16*  S     = (bf16*)carve(Mc * NH * 2);

    const double beta = exp(-0.25 / 10.0);

    // m0s/m1s/m2s contiguous: one zero kernel.
    int nM = NB * NH * 2 + NB * 16;
    k_zero<<<(nM + 255) / 256, 256, 0, stream>>>(m0s, nM);

    // input spike masks (one wave per (t,b))
    k_mask<<<(T_STEPS * NB * 64) / 256, 256, 0, stream>>>(in_sp, MASK, T_STEPS * NB);

    k_limbs_t<<<256, 256, 0, stream>>>(W1, BT1);
    k_limbs<<<(128 * 2 * NH + 255) / 256, 256, 0, stream>>>(W2, BT2, NH, N_OUT, 128);

    const int C = T_STEPS / Tc;
    const int gx = (int)(Mc / 128);
    const int gx8 = (int)(Mc / 256);   // Mc % 256 == 0 for all tc_opts
    for (int c = 0; c < C; ++c) {
        int t0 = c * Tc;
        // layer 0: fused MFMA scan (exact fp32 via limbs)
        k_scan_l0<<<256, 64, 0, stream>>>(MASK + (size_t)t0 * NB, W0, b0,
                                          m0s, S, Tc, beta);
        // layer 1: 256^2 8-phase GEMM
        k_gemm8<<<gx8 * 4, 512, 0, stream>>>(S, BT1, IBUF, gx8);
        k_scan_hidden<<<(NB * NH) / 64, 64, 0, stream>>>(IBUF, b1, m1s, S, Tc, beta);
        // layer 2: thin GEMM (N=16)
        k_gemm_thin<<<gx, 256, 0, stream>>>(S, BT2, I2BUF);
        k_scan_out<<<1, 256, 0, stream>>>(I2BUF, b2, m2s, out, Tc, t0, beta);
    }
}

// Round 14
// 879.578 us; speedup vs baseline: 2.0331x; 1.0467x over previous
//
#include <hip/hip_runtime.h>
#include <hip/hip_bf16.h>
#include <math.h>

// SNN forward: 64 -> 1024 -> 1024 -> 10, T=4000, B=16, LIF beta=exp(-0.025),
// thr=1, hard reset to 0, Dale clamp W>=0.
// R14: (1) k_gemm_thin v2 -- A read once (hi+lo B per A-frag), 64 rows/block
// (grid 500, ~2 blocks/CU), unroll 8: fixes latency starvation (R13 analysis:
// ~12 loads in flight -> 0.9 TB/s -> ~120us hidden under gemm8's cutoff).
// (2) fp32 membrane chains in all scans (fmaf): fp64 dep-latency halved;
// error class unchanged (limb-GEMM I-error ~1e-5 dominates either way).
// L0: fused MFMA scan + mask pipeline. L1: 256^2 8-phase GEMM (T2/T3/T4/T5).
// Scans: LDS-staged counted-vmcnt double buffer.

#define T_STEPS 4000
#define NB 16
#define N_IN 64
#define NH 1024
#define N_OUT 10
#define SEGO 40           // scan_out segment rows; vmcnt(40) literal below
#define SEGH 50           // scan_hidden segment rows; vmcnt(50) literal below

typedef __attribute__((ext_vector_type(8))) short bf16x8;
typedef __attribute__((ext_vector_type(4))) float f32x4;
typedef __hip_bfloat16 bf16;
typedef unsigned long long u64;

#define ASG(p) (const __attribute__((address_space(1))) void*)(p)
#define ASL(p) (__attribute__((address_space(3))) void*)(p)

// ---------------- small utility kernels ----------------

__global__ void k_zero(float* p, int n) {
    int i = blockIdx.x * 256 + threadIdx.x;
    if (i < n) p[i] = 0.f;
}

// Build per-(t,b) 64-bit input spike masks. One wave per (t,b).
__global__ void k_mask(const float* __restrict__ in, u64* __restrict__ mask, int total) {
    int w = (blockIdx.x * 256 + threadIdx.x) >> 6;
    int lane = threadIdx.x & 63;
    if (w >= total) return;
    float v = in[(size_t)w * 64 + lane];
    u64 bal = __ballot(v > 0.5f);
    if (lane == 0) mask[w] = bal;
}

// Transposing limb builder for BT1: W [1024 x 1024] -> BT [1024][2048],
// plain [hi | lo]. Coalesced reads, LDS transpose ([64][65] pad), coalesced
// writes.
__global__ __launch_bounds__(256) void k_limbs_t(
    const float* __restrict__ W, bf16* __restrict__ BT) {
    __shared__ float Wlds[64][65];
    const int tid  = threadIdx.x;
    const int lane = tid & 63;
    const int wr   = tid >> 6;            // 0..3
    const int k0 = (blockIdx.x & 15) * 64;
    const int n0 = (blockIdx.x >> 4) * 64;
#pragma unroll
    for (int rr = 0; rr < 16; ++rr) {
        int kl = wr * 16 + rr;
        Wlds[kl][lane] = W[(size_t)(k0 + kl) * 1024 + n0 + lane];
    }
    __syncthreads();
#pragma unroll
    for (int rr = 0; rr < 16; ++rr) {
        int nl = wr * 16 + rr;
        float w = fmaxf(Wlds[lane][nl], 0.f);      // Dale's law clamp
        bf16 h = __float2bfloat16(w);
        float hf = __bfloat162float(h);
        bf16 l = __float2bfloat16(w - hf);
        size_t base = (size_t)(n0 + nl) * 2048 + k0 + lane;
        BT[base] = h;
        BT[base + 1024] = l;
    }
}

// Small limb builder (BT2): W [K x N] -> BT [Npad x 2K] plain [hi|lo].
__global__ void k_limbs(const float* __restrict__ W, bf16* __restrict__ BT,
                        int K, int N, int Npad) {
    int idx = blockIdx.x * 256 + threadIdx.x;
    int total = Npad * 2 * K;
    if (idx >= total) return;
    int n  = idx / (2 * K);
    int k2 = idx - n * (2 * K);
    int lo = (k2 >= K);
    int k = lo ? (k2 - K) : k2;
    float v = 0.f;
    if (n < N) {
        float w = fmaxf(W[(size_t)k * N + n], 0.f);
        float hi = __bfloat162float(__float2bfloat16(w));
        v = lo ? (w - hi) : w;
    }
    BT[idx] = __float2bfloat16(v);
}

// ---------------- thin GEMM v2 (layer 2): C[M x 16] = A[M x 1024] @ BT^T ---
// A read ONCE per row (hi and lo B both consumed per A-frag). 64 rows/block
// (4 waves x 16 rows), grid = M/64 (~2 blocks/CU), unroll 8 for load ILP.

__global__ __launch_bounds__(256) void k_gemm_thin(
    const bf16* __restrict__ A, const bf16* __restrict__ BT,
    float* __restrict__ C) {
    const int tid  = threadIdx.x;
    const int lane = tid & 63;
    const int wave = tid >> 6;
    const int r16 = lane & 15;
    const int kg  = lane >> 4;
    const int m0 = blockIdx.x * 64 + wave * 16;
    f32x4 acc = {};
    const bf16* ap = A + (size_t)(m0 + r16) * 1024 + kg * 8;
    const bf16* bh = BT + (size_t)r16 * 2048 + kg * 8;   // hi limb cols
    const bf16* bl = bh + 1024;                          // lo limb cols
#pragma unroll 8
    for (int kt = 0; kt < 32; ++kt) {
        const int ka = kt * 32;
        bf16x8 af  = *(const bf16x8*)(ap + ka);
        bf16x8 bfh = *(const bf16x8*)(bh + ka);
        bf16x8 bfl = *(const bf16x8*)(bl + ka);
        acc = __builtin_amdgcn_mfma_f32_16x16x32_bf16(af, bfh, acc, 0, 0, 0);
        acc = __builtin_amdgcn_mfma_f32_16x16x32_bf16(af, bfl, acc, 0, 0, 0);
    }
#pragma unroll
    for (int rr = 0; rr < 4; ++rr)
        C[(size_t)(m0 + kg * 4 + rr) * 16 + r16] = acc[rr];
}

// ---------------- 256^2 8-phase GEMM (layer 1) ----------------
// Stage ordering invariant (R8): a region is staged only in a phase after all
// ds_reads of it have drained past a barrier (A at P3, B at P2).

__global__ __launch_bounds__(512) void k_gemm8(
    const bf16* __restrict__ A, const bf16* __restrict__ BT,
    float* __restrict__ C, int gx) {
    const int KA = 1024, K2 = 2048;
    const int kmask = KA - 1;
    const int nwg = gridDim.x;
    const int wg  = blockIdx.x;
    const int q = nwg >> 3, r = nwg & 7;
    const int xcd = wg & 7, idx0 = wg >> 3;
    const int swz = (xcd < r ? xcd * (q + 1) : r * (q + 1) + (xcd - r) * q) + idx0;
    const int gy = nwg / gx;              // 4
    const int n0 = (swz % gy) * 256;
    const int m0 = (swz / gy) * 256;

    __shared__ __align__(16) char LDS[131072];
    const int tid  = threadIdx.x;
    const int lane = tid & 63;
    const int wave = tid >> 6;
    const int wm = (wave >> 2) * 128;
    const int wn = (wave & 3) * 64;
    const int r16l = lane & 15;
    const int kg   = lane >> 4;
    const int hA   = wave >> 2;
    const int hB   = (wave & 3) >> 1;
    const int wn64 = wave & 1;

    const int po = (r16l * 64 + kg * 16) ^ (((r16l >> 3) & 1) << 5);
    const char* bA[2] = { LDS + hA * 16384 + po,
                          LDS + 65536 + hA * 16384 + po };
    const char* bB[2] = { LDS + 32768 + hB * 16384 + po,
                          LDS + 98304 + hB * 16384 + po };
    const int bOff = wn64 * 8192;

    int s_row[2], s_col[2];
#pragma unroll
    for (int rr = 0; rr < 2; ++rr) {
        int d = (rr * 512 + tid) * 16;
        int l = d ^ (((d >> 9) & 1) << 5);
        int sub = l >> 10;
        int w = l & 1023;
        s_row[rr] = (sub >> 1) * 16 + (w >> 6);
        s_col[rr] = ((sub & 1) * 64 + (w & 63)) >> 1;
    }

#define HBASE(BUF, OP, HALF) ((((BUF) * 2 + (OP)) * 2 + (HALF)) * 16384)
#define STAGE_A(BUF, HALF, K0)                                              \
    {                                                                       \
        _Pragma("unroll")                                                   \
        for (int rr = 0; rr < 2; ++rr)                                      \
            __builtin_amdgcn_global_load_lds(                               \
                ASG(A + (size_t)(m0 + (HALF) * 128 + s_row[rr]) * KA        \
                    + (((K0) + s_col[rr]) & kmask)),                        \
                ASL(LDS + HBASE(BUF, 0, HALF) + (rr * 512 + wave * 64) * 16), \
                16, 0, 0);                                                  \
    }
#define STAGE_B(BUF, HALF, K0)                                              \
    {                                                                       \
        _Pragma("unroll")                                                   \
        for (int rr = 0; rr < 2; ++rr)                                      \
            __builtin_amdgcn_global_load_lds(                               \
                ASG(BT + (size_t)(n0 + (HALF) * 128 + s_row[rr]) * K2       \
                    + (K0) + s_col[rr]),                                    \
                ASL(LDS + HBASE(BUF, 1, HALF) + (rr * 512 + wave * 64) * 16), \
                16, 0, 0);                                                  \
    }

    f32x4 acc[8][4] = {};
    bf16x8 a[4][2], b[4][2];

#define MM(MIB, NIB)                                                        \
    {                                                                       \
        _Pragma("unroll")                                                   \
        for (int i = 0; i < 4; ++i)                                         \
            _Pragma("unroll")                                               \
            for (int j = 0; j < 2; ++j) {                                   \
                acc[(MIB) + i][(NIB) + j] =                                 \
                    __builtin_amdgcn_mfma_f32_16x16x32_bf16(                \
                        a[i][0], b[(NIB) + j][0], acc[(MIB) + i][(NIB) + j], 0, 0, 0); \
                acc[(MIB) + i][(NIB) + j] =                                 \
                    __builtin_amdgcn_mfma_f32_16x16x32_bf16(                \
                        a[i][1], b[(NIB) + j][1], acc[(MIB) + i][(NIB) + j], 0, 0, 0); \
            }                                                               \
    }

#define PH_SYNC()                                                           \
    __builtin_amdgcn_s_barrier();                                           \
    asm volatile("s_waitcnt lgkmcnt(0)" ::: "memory");                      \
    __builtin_amdgcn_sched_barrier(0);

#define KTILE(BUF, SK)                                                      \
    {                                                                       \
        _Pragma("unroll")                                                   \
        for (int i = 0; i < 4; ++i) {                                       \
            a[i][0] = *(const bf16x8*)(bA[BUF] + i * 2048);                 \
            a[i][1] = *(const bf16x8*)(bA[BUF] + i * 2048 + 1024);          \
        }                                                                   \
        _Pragma("unroll")                                                   \
        for (int j = 0; j < 2; ++j) {                                       \
            b[j][0] = *(const bf16x8*)(bB[BUF] + bOff + j * 2048);          \
            b[j][1] = *(const bf16x8*)(bB[BUF] + bOff + j * 2048 + 1024);   \
        }                                                                   \
        PH_SYNC();                                                          \
        __builtin_amdgcn_s_setprio(1);                                      \
        MM(0, 0);                                                           \
        __builtin_amdgcn_s_setprio(0);                                      \
        __builtin_amdgcn_s_barrier();                                       \
        _Pragma("unroll")                                                   \
        for (int j = 0; j < 2; ++j) {                                       \
            b[2 + j][0] = *(const bf16x8*)(bB[BUF] + bOff + (2 + j) * 2048); \
            b[2 + j][1] = *(const bf16x8*)(bB[BUF] + bOff + (2 + j) * 2048 + 1024); \
        }                                                                   \
        PH_SYNC();                                                          \
        __builtin_amdgcn_s_setprio(1);                                      \
        MM(0, 2);                                                           \
        __builtin_amdgcn_s_setprio(0);                                      \
        __builtin_amdgcn_s_barrier();                                       \
        _Pragma("unroll")                                                   \
        for (int i = 0; i < 4; ++i) {                                       \
            a[i][0] = *(const bf16x8*)(bA[BUF] + (4 + i) * 2048);           \
            a[i][1] = *(const bf16x8*)(bA[BUF] + (4 + i) * 2048 + 1024);    \
        }                                                                   \
        STAGE_B(BUF, 0, SK);                                                \
        STAGE_B(BUF, 1, SK);                                                \
        PH_SYNC();                                                          \
        __builtin_amdgcn_s_setprio(1);                                      \
        MM(4, 0);                                                           \
        __builtin_amdgcn_s_setprio(0);                                      \
        __builtin_amdgcn_s_barrier();                                       \
        STAGE_A(BUF, 0, SK);                                                \
        STAGE_A(BUF, 1, SK);                                                \
        PH_SYNC();                                                          \
        __builtin_amdgcn_s_setprio(1);                                      \
        MM(4, 2);                                                           \
        __builtin_amdgcn_s_setprio(0);                                      \
        asm volatile("s_waitcnt vmcnt(8)" ::: "memory");                    \
        __builtin_amdgcn_sched_barrier(0);                                  \
        __builtin_amdgcn_s_barrier();                                       \
    }

    STAGE_A(0, 0, 0);  STAGE_A(0, 1, 0);  STAGE_B(0, 0, 0);  STAGE_B(0, 1, 0);
    STAGE_A(1, 0, 64); STAGE_A(1, 1, 64); STAGE_B(1, 0, 64); STAGE_B(1, 1, 64);
    asm volatile("s_waitcnt vmcnt(8)" ::: "memory");
    __builtin_amdgcn_sched_barrier(0);
    __builtin_amdgcn_s_barrier();

    for (int it = 0; it < 16; ++it) {
        const int k0  = it * 128;
        const int ksA = (k0 + 128) & (K2 - 1);
        const int ksB = (k0 + 192) & (K2 - 1);
        KTILE(0, ksA);
        KTILE(1, ksB);
    }
    asm volatile("s_waitcnt vmcnt(0)" ::: "memory");
    __builtin_amdgcn_sched_barrier(0);

#pragma unroll
    for (int mi = 0; mi < 8; ++mi)
#pragma unroll
        for (int ni = 0; ni < 4; ++ni)
#pragma unroll
            for (int rr = 0; rr < 4; ++rr) {
                int row = m0 + wm + mi * 16 + kg * 4 + rr;
                int col = n0 + wn + ni * 16 + r16l;
                C[(size_t)row * 1024 + col] = acc[mi][ni][rr];
            }
#undef KTILE
#undef PH_SYNC
#undef MM
#undef STAGE_A
#undef STAGE_B
#undef HBASE
}

// ---------------- LIF scan kernels (fp32 membranes, R14) ----------------

// L0 fused scan via MFMA + mask software-pipeline. 256 blocks x 64 threads.
__global__ __launch_bounds__(64) void k_scan_l0(
    const u64* __restrict__ mask,          // [Tc][NB] for this chunk
    const float* __restrict__ W0,          // [64][1024] row-major
    const float* __restrict__ bias,
    float* __restrict__ mstate, bf16* __restrict__ S, int Tc, float beta) {
    __shared__ float Ilds[2][16][68];
    const int lane = threadIdx.x;
    const int gid  = blockIdx.x * 64 + lane;   // = b*1024 + q*64 + lane
    const int b  = blockIdx.x >> 4;
    const int q  = blockIdx.x & 15;
    const int j0 = q * 64;
    const int r16 = lane & 15;
    const int kg  = lane >> 4;
    bf16x8 bh[4][2], bl[4][2];
#pragma unroll
    for (int jt = 0; jt < 4; ++jt)
#pragma unroll
        for (int kk = 0; kk < 2; ++kk)
#pragma unroll
            for (int e = 0; e < 8; ++e) {
                int k = kk * 32 + kg * 8 + e;
                float w = fmaxf(W0[(size_t)k * 1024 + j0 + jt * 16 + r16], 0.f);
                bf16 h = __float2bfloat16(w);
                float hf = __bfloat162float(h);
                bf16 l = __float2bfloat16(w - hf);
                bh[jt][kk][e] = *(short*)&h;
                bl[jt][kk][e] = *(short*)&l;
            }
    float m = mstate[gid];
    const float bj = bias[j0 + lane];
    const size_t stride = (size_t)NB * NH;
    const int ntile = Tc / 16;
    const int tmax = ntile - 1;

#define LOADM(TT) mask[(size_t)(((TT) <= tmax ? (TT) : tmax) * 16 + r16) * NB + b]

#define L0_COMPUTE(MSK, P)                                                  \
    {                                                                       \
        f32x4 acc[4] = {};                                                  \
        _Pragma("unroll")                                                   \
        for (int kk = 0; kk < 2; ++kk) {                                    \
            unsigned byte8 = (unsigned)(((MSK) >> (kk * 32 + kg * 8)) & 0xFF); \
            bf16x8 af;                                                      \
            _Pragma("unroll")                                               \
            for (int e = 0; e < 8; ++e)                                     \
                af[e] = ((byte8 >> e) & 1) ? (short)0x3F80 : (short)0;      \
            _Pragma("unroll")                                               \
            for (int jt = 0; jt < 4; ++jt) {                                \
                acc[jt] = __builtin_amdgcn_mfma_f32_16x16x32_bf16(          \
                    af, bh[jt][kk], acc[jt], 0, 0, 0);                      \
                acc[jt] = __builtin_amdgcn_mfma_f32_16x16x32_bf16(          \
                    af, bl[jt][kk], acc[jt], 0, 0, 0);                      \
            }                                                               \
        }                                                                   \
        _Pragma("unroll")                                                   \
        for (int jt = 0; jt < 4; ++jt)                                      \
            _Pragma("unroll")                                               \
            for (int rr = 0; rr < 4; ++rr)                                  \
                Ilds[P][kg * 4 + rr][jt * 16 + r16] = acc[jt][rr];          \
    }

    u64 mc = LOADM(0);
    L0_COMPUTE(mc, 0);
    u64 mn = LOADM(1);
    for (int tt = 0; tt < ntile; ++tt) {
        __builtin_amdgcn_s_barrier();            // tile tt resident
        float v[16];
#pragma unroll
        for (int u = 0; u < 16; ++u)
            v[u] = Ilds[tt & 1][u][lane];
        u64 m2 = LOADM(tt + 2);
        if (tt + 1 < ntile) L0_COMPUTE(mn, (tt + 1) & 1);
        unsigned short o[16];
#pragma unroll
        for (int u = 0; u < 16; ++u) {
            m = fmaf(beta, m, v[u] + bj);
            bool sp = (m >= 1.0f);
            o[u] = sp ? (unsigned short)0x3F80 : (unsigned short)0;
            m = sp ? 0.f : m;
        }
#pragma unroll
        for (int u = 0; u < 16; ++u)
            ((unsigned short*)S)[(size_t)(tt * 16 + u) * stride + gid] = o[u];
        mn = m2;
    }
    mstate[gid] = m;
#undef L0_COMPUTE
#undef LOADM
}

// hidden layer 1 scan: counted-vmcnt LDS double buffer.
__global__ __launch_bounds__(64) void k_scan_hidden(
    const float* __restrict__ I, const float* __restrict__ bias,
    float* __restrict__ mstate, bf16* __restrict__ S, int Tc, float beta) {
    __shared__ __align__(16) float segA[SEGH * 64];
    __shared__ __align__(16) float segB[SEGH * 64];
    const int lane = threadIdx.x;
    const int gid  = blockIdx.x * 64 + lane;
    const int j = gid & (NH - 1);
    float m = mstate[gid];
    const float bj = bias[j];
    const size_t stride = (size_t)NB * NH;
    const int nseg = Tc / SEGH;                  // even (Tc % 400 == 0)

#define H_PREFETCH(SEGBUF, SIDX)                                            \
    {                                                                       \
        const float* src = I + (size_t)(SIDX) * SEGH * stride + gid;        \
        _Pragma("unroll")                                                   \
        for (int rr = 0; rr < SEGH; ++rr)                                   \
            __builtin_amdgcn_global_load_lds(                               \
                ASG(src + (size_t)rr * stride),                             \
                ASL(&SEGBUF[rr * 64]), 4, 0, 0);                            \
    }

#define H_PROC(SEGBUF, SIDX)                                                \
    {                                                                       \
        const int btt = (SIDX) * SEGH;                                      \
        _Pragma("unroll")                                                   \
        for (int sb = 0; sb < SEGH / 10; ++sb) {                            \
            float v[10];                                                    \
            _Pragma("unroll")                                               \
            for (int u = 0; u < 10; ++u)                                    \
                v[u] = SEGBUF[(sb * 10 + u) * 64 + lane];                   \
            unsigned short o[10];                                           \
            _Pragma("unroll")                                               \
            for (int u = 0; u < 10; ++u) {                                  \
                m = fmaf(beta, m, v[u] + bj);                               \
                bool sp = (m >= 1.0f);                                      \
                o[u] = sp ? (unsigned short)0x3F80 : (unsigned short)0;     \
                m = sp ? 0.f : m;                                           \
            }                                                               \
            _Pragma("unroll")                                               \
            for (int u = 0; u < 10; ++u)                                    \
                ((unsigned short*)S)[(size_t)(btt + sb * 10 + u) * stride + gid] = o[u]; \
        }                                                                   \
    }

    H_PREFETCH(segA, 0);
    for (int s = 0; s < nseg; s += 2) {
        H_PREFETCH(segB, s + 1);
        asm volatile("s_waitcnt vmcnt(50)" ::: "memory"); // segA resident
        __builtin_amdgcn_sched_barrier(0);
        H_PROC(segA, s);
        if (s + 2 < nseg) {
            H_PREFETCH(segA, s + 2);
            asm volatile("s_waitcnt vmcnt(50)" ::: "memory"); // segB resident
        } else {
            asm volatile("s_waitcnt vmcnt(0)" ::: "memory");
        }
        __builtin_amdgcn_sched_barrier(0);
        H_PROC(segB, s + 1);
    }
    mstate[gid] = m;
#undef H_PREFETCH
#undef H_PROC
}

__global__ __launch_bounds__(256) void k_scan_out(
    const float* __restrict__ I2, const float* __restrict__ bias,
    float* __restrict__ mstate, float* __restrict__ out,
    int Tc, int t0, float beta) {
    __shared__ __align__(16) float segA[SEGO * 256];
    __shared__ __align__(16) float segB[SEGO * 256];
    const int tid  = threadIdx.x;
    const int lane = tid & 63;
    const int wave = tid >> 6;
    const int k = tid & 15;
    const int b = tid >> 4;
    float m = mstate[tid];
    float bj = (k < N_OUT) ? bias[k] : 0.f;
    const int nseg = Tc / SEGO;                  // even (Tc % 400 == 0)

#define O_PREFETCH(SEGBUF, SIDX)                                            \
    {                                                                       \
        const float* src = I2 + (size_t)(SIDX) * SEGO * 256 + wave * 64 + lane; \
        _Pragma("unroll 8")                                                 \
        for (int rr = 0; rr < SEGO; ++rr)                                   \
            __builtin_amdgcn_global_load_lds(                               \
                ASG(src + (size_t)rr * 256),                                \
                ASL(&SEGBUF[rr * 256 + wave * 64]), 4, 0, 0);               \
    }

#define O_PROC(SEGBUF, SIDX)                                                \
    {                                                                       \
        const int btt = (SIDX) * SEGO;                                      \
        _Pragma("unroll")                                                   \
        for (int sb = 0; sb < SEGO / 8; ++sb) {                             \
            float v[8];                                                     \
            _Pragma("unroll")                                               \
            for (int u = 0; u < 8; ++u)                                     \
                v[u] = SEGBUF[(sb * 8 + u) * 256 + tid];                    \
            float o[8];                                                     \
            _Pragma("unroll")                                               \
            for (int u = 0; u < 8; ++u) {                                   \
                m = fmaf(beta, m, v[u] + bj);                               \
                bool sp = (m >= 1.0f);                                      \
                o[u] = sp ? 1.f : 0.f;                                      \
                m = sp ? 0.f : m;                                           \
            }                                                               \
            if (k < N_OUT) {                                                \
                _Pragma("unroll")                                           \
                for (int u = 0; u < 8; ++u)                                 \
                    out[((size_t)(t0 + btt + sb * 8 + u) * NB + b) * N_OUT + k] = o[u]; \
            }                                                               \
        }                                                                   \
    }

    O_PREFETCH(segA, 0);
    for (int s = 0; s < nseg; s += 2) {
        O_PREFETCH(segB, s + 1);
        asm volatile("s_waitcnt vmcnt(40)" ::: "memory"); // segA resident
        __builtin_amdgcn_sched_barrier(0);
        O_PROC(segA, s);
        if (s + 2 < nseg) {
            O_PREFETCH(segA, s + 2);
            asm volatile("s_waitcnt vmcnt(40)" ::: "memory"); // segB resident
        } else {
            asm volatile("s_waitcnt vmcnt(0)" ::: "memory");
        }
        __builtin_amdgcn_sched_barrier(0);
        O_PROC(segB, s + 1);
    }
    mstate[tid] = m;
#undef O_PREFETCH
#undef O_PROC
}

// ---------------- host ----------------

extern "C" void kernel_launch(void* const* d_in, const int* in_sizes, int n_in,
                              void* d_out, int out_size, void* d_ws, size_t ws_size,
                              hipStream_t stream) {
    const float* in_sp = (const float*)d_in[0];
    const float* W0 = (const float*)d_in[1];
    const float* b0 = (const float*)d_in[2];
    const float* W1 = (const float*)d_in[3];
    const float* b1 = (const float*)d_in[4];
    const float* W2 = (const float*)d_in[5];
    const float* b2 = (const float*)d_in[6];
    float* out = (float*)d_out;

    char* p = (char*)d_ws;
    auto carve = [&](size_t bytes) -> void* {
        char* r = p; p += (bytes + 255) & ~(size_t)255; return (void*)r;
    };
    u64*  MASK = (u64*)carve((size_t)T_STEPS * NB * 8);
    bf16* BT1  = (bf16*)carve((size_t)NH * 2 * NH * 2);
    bf16* BT2  = (bf16*)carve((size_t)128 * 2 * NH * 2);
    float* m0s = (float*)carve((size_t)NB * NH * 4);
    float* m1s = (float*)carve((size_t)NB * NH * 4);
    float* m2s = (float*)carve((size_t)NB * 16 * 4);
    size_t fixed = (size_t)(p - (char*)d_ws);

    // Tc | 4000, Tc % 400 == 0 (scan segs even; L0 tiles of 16; Mc % 256 == 0)
    const int tc_opts[3] = {2000, 800, 400};
    int Tc = 400;
    for (int i = 0; i < 3; ++i) {
        size_t Mc_ = (size_t)tc_opts[i] * NB;
        size_t need = fixed
            + ((Mc_ * NH * 4 + 255) & ~(size_t)255)
            + ((Mc_ * 16 * 4 + 255) & ~(size_t)255)
            + ((Mc_ * NH * 2 + 255) & ~(size_t)255);
        if (need <= ws_size) { Tc = tc_opts[i]; break; }
    }
    size_t Mc = (size_t)Tc * NB;
    float* IBUF  = (float*)carve(Mc * NH * 4);
    float* I2BUF = (float*)carve(Mc * 16 * 4);
    bf16*  S     = (bf16*)carve(Mc * NH * 2);

    const float beta = (float)exp(-0.25 / 10.0);

    // m0s/m1s/m2s contiguous: one zero kernel.
    int nM = NB * NH * 2 + NB * 16;
    k_zero<<<(nM + 255) / 256, 256, 0, stream>>>(m0s, nM);

    // input spike masks (one wave per (t,b))
    k_mask<<<(T_STEPS * NB * 64) / 256, 256, 0, stream>>>(in_sp, MASK, T_STEPS * NB);

    k_limbs_t<<<256, 256, 0, stream>>>(W1, BT1);
    k_limbs<<<(128 * 2 * NH + 255) / 256, 256, 0, stream>>>(W2, BT2, NH, N_OUT, 128);

    const int C = T_STEPS / Tc;
    const int gx8 = (int)(Mc / 256);
    const int gthin = (int)(Mc / 64);
    for (int c = 0; c < C; ++c) {
        int t0 = c * Tc;
        // layer 0: fused MFMA scan (exact fp32 via limbs)
        k_scan_l0<<<256, 64, 0, stream>>>(MASK + (size_t)t0 * NB, W0, b0,
                                          m0s, S, Tc, beta);
        // layer 1: 256^2 8-phase GEMM
        k_gemm8<<<gx8 * 4, 512, 0, stream>>>(S, BT1, IBUF, gx8);
        k_scan_hidden<<<(NB * NH) / 64, 64, 0, stream>>>(IBUF, b1, m1s, S, Tc, beta);
        // layer 2: thin GEMM v2 (N=16, A read once)
        k_gemm_thin<<<gthin, 256, 0, stream>>>(S, BT2, I2BUF);
        k_scan_out<<<1, 256, 0, stream>>>(I2BUF, b2, m2s, out, Tc, t0, beta);
    }
}

// Round 15
// 842.782 us; speedup vs baseline: 2.1218x; 1.0437x over previous
//
#include <hip/hip_runtime.h>
#include <hip/hip_bf16.h>
#include <math.h>

// SNN forward: 64 -> 1024 -> 1024 -> 10, T=4000, B=16, LIF beta=exp(-0.025),
// thr=1, hard reset to 0, Dale clamp W>=0.
// R15: 16B/lane global_load_lds staging in scan_hidden and scan_out
// (was 4B/lane, 50 instrs/segment -> 10 instrs; m97 lesson: width 4->16 is
// the staging lever). Lane-row repack keeps the LDS image exactly linear.
// L0: fused MFMA scan + mask pipeline. L1: 256^2 8-phase GEMM (T2/T3/T4/T5).
// L2: thin N=16 GEMM (A read once). Scans: fp32 chains, counted vmcnt.

#define T_STEPS 4000
#define NB 16
#define N_IN 64
#define NH 1024
#define N_OUT 10
#define SEGO 40           // scan_out segment rows; 10 glds/wave -> vmcnt(10)
#define SEGH 40           // scan_hidden segment rows; 10 glds -> vmcnt(10)

typedef __attribute__((ext_vector_type(8))) short bf16x8;
typedef __attribute__((ext_vector_type(4))) float f32x4;
typedef __hip_bfloat16 bf16;
typedef unsigned long long u64;

#define ASG(p) (const __attribute__((address_space(1))) void*)(p)
#define ASL(p) (__attribute__((address_space(3))) void*)(p)

// ---------------- small utility kernels ----------------

__global__ void k_zero(float* p, int n) {
    int i = blockIdx.x * 256 + threadIdx.x;
    if (i < n) p[i] = 0.f;
}

// Build per-(t,b) 64-bit input spike masks. One wave per (t,b).
__global__ void k_mask(const float* __restrict__ in, u64* __restrict__ mask, int total) {
    int w = (blockIdx.x * 256 + threadIdx.x) >> 6;
    int lane = threadIdx.x & 63;
    if (w >= total) return;
    float v = in[(size_t)w * 64 + lane];
    u64 bal = __ballot(v > 0.5f);
    if (lane == 0) mask[w] = bal;
}

// Transposing limb builder for BT1: W [1024 x 1024] -> BT [1024][2048],
// plain [hi | lo]. Coalesced reads, LDS transpose ([64][65] pad), coalesced
// writes.
__global__ __launch_bounds__(256) void k_limbs_t(
    const float* __restrict__ W, bf16* __restrict__ BT) {
    __shared__ float Wlds[64][65];
    const int tid  = threadIdx.x;
    const int lane = tid & 63;
    const int wr   = tid >> 6;            // 0..3
    const int k0 = (blockIdx.x & 15) * 64;
    const int n0 = (blockIdx.x >> 4) * 64;
#pragma unroll
    for (int rr = 0; rr < 16; ++rr) {
        int kl = wr * 16 + rr;
        Wlds[kl][lane] = W[(size_t)(k0 + kl) * 1024 + n0 + lane];
    }
    __syncthreads();
#pragma unroll
    for (int rr = 0; rr < 16; ++rr) {
        int nl = wr * 16 + rr;
        float w = fmaxf(Wlds[lane][nl], 0.f);      // Dale's law clamp
        bf16 h = __float2bfloat16(w);
        float hf = __bfloat162float(h);
        bf16 l = __float2bfloat16(w - hf);
        size_t base = (size_t)(n0 + nl) * 2048 + k0 + lane;
        BT[base] = h;
        BT[base + 1024] = l;
    }
}

// Small limb builder (BT2): W [K x N] -> BT [Npad x 2K] plain [hi|lo].
__global__ void k_limbs(const float* __restrict__ W, bf16* __restrict__ BT,
                        int K, int N, int Npad) {
    int idx = blockIdx.x * 256 + threadIdx.x;
    int total = Npad * 2 * K;
    if (idx >= total) return;
    int n  = idx / (2 * K);
    int k2 = idx - n * (2 * K);
    int lo = (k2 >= K);
    int k = lo ? (k2 - K) : k2;
    float v = 0.f;
    if (n < N) {
        float w = fmaxf(W[(size_t)k * N + n], 0.f);
        float hi = __bfloat162float(__float2bfloat16(w));
        v = lo ? (w - hi) : w;
    }
    BT[idx] = __float2bfloat16(v);
}

// ---------------- thin GEMM v2 (layer 2): C[M x 16] = A[M x 1024] @ BT^T ---
// A read ONCE per row (hi and lo B both consumed per A-frag). 64 rows/block.

__global__ __launch_bounds__(256) void k_gemm_thin(
    const bf16* __restrict__ A, const bf16* __restrict__ BT,
    float* __restrict__ C) {
    const int tid  = threadIdx.x;
    const int lane = tid & 63;
    const int wave = tid >> 6;
    const int r16 = lane & 15;
    const int kg  = lane >> 4;
    const int m0 = blockIdx.x * 64 + wave * 16;
    f32x4 acc = {};
    const bf16* ap = A + (size_t)(m0 + r16) * 1024 + kg * 8;
    const bf16* bh = BT + (size_t)r16 * 2048 + kg * 8;   // hi limb cols
    const bf16* bl = bh + 1024;                          // lo limb cols
#pragma unroll 8
    for (int kt = 0; kt < 32; ++kt) {
        const int ka = kt * 32;
        bf16x8 af  = *(const bf16x8*)(ap + ka);
        bf16x8 bfh = *(const bf16x8*)(bh + ka);
        bf16x8 bfl = *(const bf16x8*)(bl + ka);
        acc = __builtin_amdgcn_mfma_f32_16x16x32_bf16(af, bfh, acc, 0, 0, 0);
        acc = __builtin_amdgcn_mfma_f32_16x16x32_bf16(af, bfl, acc, 0, 0, 0);
    }
#pragma unroll
    for (int rr = 0; rr < 4; ++rr)
        C[(size_t)(m0 + kg * 4 + rr) * 16 + r16] = acc[rr];
}

// ---------------- 256^2 8-phase GEMM (layer 1) ----------------
// Stage ordering invariant (R8): a region is staged only in a phase after all
// ds_reads of it have drained past a barrier (A at P3, B at P2).

__global__ __launch_bounds__(512) void k_gemm8(
    const bf16* __restrict__ A, const bf16* __restrict__ BT,
    float* __restrict__ C, int gx) {
    const int KA = 1024, K2 = 2048;
    const int kmask = KA - 1;
    const int nwg = gridDim.x;
    const int wg  = blockIdx.x;
    const int q = nwg >> 3, r = nwg & 7;
    const int xcd = wg & 7, idx0 = wg >> 3;
    const int swz = (xcd < r ? xcd * (q + 1) : r * (q + 1) + (xcd - r) * q) + idx0;
    const int gy = nwg / gx;              // 4
    const int n0 = (swz % gy) * 256;
    const int m0 = (swz / gy) * 256;

    __shared__ __align__(16) char LDS[131072];
    const int tid  = threadIdx.x;
    const int lane = tid & 63;
    const int wave = tid >> 6;
    const int wm = (wave >> 2) * 128;
    const int wn = (wave & 3) * 64;
    const int r16l = lane & 15;
    const int kg   = lane >> 4;
    const int hA   = wave >> 2;
    const int hB   = (wave & 3) >> 1;
    const int wn64 = wave & 1;

    const int po = (r16l * 64 + kg * 16) ^ (((r16l >> 3) & 1) << 5);
    const char* bA[2] = { LDS + hA * 16384 + po,
                          LDS + 65536 + hA * 16384 + po };
    const char* bB[2] = { LDS + 32768 + hB * 16384 + po,
                          LDS + 98304 + hB * 16384 + po };
    const int bOff = wn64 * 8192;

    int s_row[2], s_col[2];
#pragma unroll
    for (int rr = 0; rr < 2; ++rr) {
        int d = (rr * 512 + tid) * 16;
        int l = d ^ (((d >> 9) & 1) << 5);
        int sub = l >> 10;
        int w = l & 1023;
        s_row[rr] = (sub >> 1) * 16 + (w >> 6);
        s_col[rr] = ((sub & 1) * 64 + (w & 63)) >> 1;
    }

#define HBASE(BUF, OP, HALF) ((((BUF) * 2 + (OP)) * 2 + (HALF)) * 16384)
#define STAGE_A(BUF, HALF, K0)                                              \
    {                                                                       \
        _Pragma("unroll")                                                   \
        for (int rr = 0; rr < 2; ++rr)                                      \
            __builtin_amdgcn_global_load_lds(                               \
                ASG(A + (size_t)(m0 + (HALF) * 128 + s_row[rr]) * KA        \
                    + (((K0) + s_col[rr]) & kmask)),                        \
                ASL(LDS + HBASE(BUF, 0, HALF) + (rr * 512 + wave * 64) * 16), \
                16, 0, 0);                                                  \
    }
#define STAGE_B(BUF, HALF, K0)                                              \
    {                                                                       \
        _Pragma("unroll")                                                   \
        for (int rr = 0; rr < 2; ++rr)                                      \
            __builtin_amdgcn_global_load_lds(                               \
                ASG(BT + (size_t)(n0 + (HALF) * 128 + s_row[rr]) * K2       \
                    + (K0) + s_col[rr]),                                    \
                ASL(LDS + HBASE(BUF, 1, HALF) + (rr * 512 + wave * 64) * 16), \
                16, 0, 0);                                                  \
    }

    f32x4 acc[8][4] = {};
    bf16x8 a[4][2], b[4][2];

#define MM(MIB, NIB)                                                        \
    {                                                                       \
        _Pragma("unroll")                                                   \
        for (int i = 0; i < 4; ++i)                                         \
            _Pragma("unroll")                                               \
            for (int j = 0; j < 2; ++j) {                                   \
                acc[(MIB) + i][(NIB) + j] =                                 \
                    __builtin_amdgcn_mfma_f32_16x16x32_bf16(                \
                        a[i][0], b[(NIB) + j][0], acc[(MIB) + i][(NIB) + j], 0, 0, 0); \
                acc[(MIB) + i][(NIB) + j] =                                 \
                    __builtin_amdgcn_mfma_f32_16x16x32_bf16(                \
                        a[i][1], b[(NIB) + j][1], acc[(MIB) + i][(NIB) + j], 0, 0, 0); \
            }                                                               \
    }

#define PH_SYNC()                                                           \
    __builtin_amdgcn_s_barrier();                                           \
    asm volatile("s_waitcnt lgkmcnt(0)" ::: "memory");                      \
    __builtin_amdgcn_sched_barrier(0);

#define KTILE(BUF, SK)                                                      \
    {                                                                       \
        _Pragma("unroll")                                                   \
        for (int i = 0; i < 4; ++i) {                                       \
            a[i][0] = *(const bf16x8*)(bA[BUF] + i * 2048);                 \
            a[i][1] = *(const bf16x8*)(bA[BUF] + i * 2048 + 1024);          \
        }                                                                   \
        _Pragma("unroll")                                                   \
        for (int j = 0; j < 2; ++j) {                                       \
            b[j][0] = *(const bf16x8*)(bB[BUF] + bOff + j * 2048);          \
            b[j][1] = *(const bf16x8*)(bB[BUF] + bOff + j * 2048 + 1024);   \
        }                                                                   \
        PH_SYNC();                                                          \
        __builtin_amdgcn_s_setprio(1);                                      \
        MM(0, 0);                                                           \
        __builtin_amdgcn_s_setprio(0);                                      \
        __builtin_amdgcn_s_barrier();                                       \
        _Pragma("unroll")                                                   \
        for (int j = 0; j < 2; ++j) {                                       \
            b[2 + j][0] = *(const bf16x8*)(bB[BUF] + bOff + (2 + j) * 2048); \
            b[2 + j][1] = *(const bf16x8*)(bB[BUF] + bOff + (2 + j) * 2048 + 1024); \
        }                                                                   \
        PH_SYNC();                                                          \
        __builtin_amdgcn_s_setprio(1);                                      \
        MM(0, 2);                                                           \
        __builtin_amdgcn_s_setprio(0);                                      \
        __builtin_amdgcn_s_barrier();                                       \
        _Pragma("unroll")                                                   \
        for (int i = 0; i < 4; ++i) {                                       \
            a[i][0] = *(const bf16x8*)(bA[BUF] + (4 + i) * 2048);           \
            a[i][1] = *(const bf16x8*)(bA[BUF] + (4 + i) * 2048 + 1024);    \
        }                                                                   \
        STAGE_B(BUF, 0, SK);                                                \
        STAGE_B(BUF, 1, SK);                                                \
        PH_SYNC();                                                          \
        __builtin_amdgcn_s_setprio(1);                                      \
        MM(4, 0);                                                           \
        __builtin_amdgcn_s_setprio(0);                                      \
        __builtin_amdgcn_s_barrier();                                       \
        STAGE_A(BUF, 0, SK);                                                \
        STAGE_A(BUF, 1, SK);                                                \
        PH_SYNC();                                                          \
        __builtin_amdgcn_s_setprio(1);                                      \
        MM(4, 2);                                                           \
        __builtin_amdgcn_s_setprio(0);                                      \
        asm volatile("s_waitcnt vmcnt(8)" ::: "memory");                    \
        __builtin_amdgcn_sched_barrier(0);                                  \
        __builtin_amdgcn_s_barrier();                                       \
    }

    STAGE_A(0, 0, 0);  STAGE_A(0, 1, 0);  STAGE_B(0, 0, 0);  STAGE_B(0, 1, 0);
    STAGE_A(1, 0, 64); STAGE_A(1, 1, 64); STAGE_B(1, 0, 64); STAGE_B(1, 1, 64);
    asm volatile("s_waitcnt vmcnt(8)" ::: "memory");
    __builtin_amdgcn_sched_barrier(0);
    __builtin_amdgcn_s_barrier();

    for (int it = 0; it < 16; ++it) {
        const int k0  = it * 128;
        const int ksA = (k0 + 128) & (K2 - 1);
        const int ksB = (k0 + 192) & (K2 - 1);
        KTILE(0, ksA);
        KTILE(1, ksB);
    }
    asm volatile("s_waitcnt vmcnt(0)" ::: "memory");
    __builtin_amdgcn_sched_barrier(0);

#pragma unroll
    for (int mi = 0; mi < 8; ++mi)
#pragma unroll
        for (int ni = 0; ni < 4; ++ni)
#pragma unroll
            for (int rr = 0; rr < 4; ++rr) {
                int row = m0 + wm + mi * 16 + kg * 4 + rr;
                int col = n0 + wn + ni * 16 + r16l;
                C[(size_t)row * 1024 + col] = acc[mi][ni][rr];
            }
#undef KTILE
#undef PH_SYNC
#undef MM
#undef STAGE_A
#undef STAGE_B
#undef HBASE
}

// ---------------- LIF scan kernels (fp32 membranes) ----------------

// L0 fused scan via MFMA + mask software-pipeline. 256 blocks x 64 threads.
__global__ __launch_bounds__(64) void k_scan_l0(
    const u64* __restrict__ mask,          // [Tc][NB] for this chunk
    const float* __restrict__ W0,          // [64][1024] row-major
    const float* __restrict__ bias,
    float* __restrict__ mstate, bf16* __restrict__ S, int Tc, float beta) {
    __shared__ float Ilds[2][16][68];
    const int lane = threadIdx.x;
    const int gid  = blockIdx.x * 64 + lane;   // = b*1024 + q*64 + lane
    const int b  = blockIdx.x >> 4;
    const int q  = blockIdx.x & 15;
    const int j0 = q * 64;
    const int r16 = lane & 15;
    const int kg  = lane >> 4;
    bf16x8 bh[4][2], bl[4][2];
#pragma unroll
    for (int jt = 0; jt < 4; ++jt)
#pragma unroll
        for (int kk = 0; kk < 2; ++kk)
#pragma unroll
            for (int e = 0; e < 8; ++e) {
                int k = kk * 32 + kg * 8 + e;
                float w = fmaxf(W0[(size_t)k * 1024 + j0 + jt * 16 + r16], 0.f);
                bf16 h = __float2bfloat16(w);
                float hf = __bfloat162float(h);
                bf16 l = __float2bfloat16(w - hf);
                bh[jt][kk][e] = *(short*)&h;
                bl[jt][kk][e] = *(short*)&l;
            }
    float m = mstate[gid];
    const float bj = bias[j0 + lane];
    const size_t stride = (size_t)NB * NH;
    const int ntile = Tc / 16;
    const int tmax = ntile - 1;

#define LOADM(TT) mask[(size_t)(((TT) <= tmax ? (TT) : tmax) * 16 + r16) * NB + b]

#define L0_COMPUTE(MSK, P)                                                  \
    {                                                                       \
        f32x4 acc[4] = {};                                                  \
        _Pragma("unroll")                                                   \
        for (int kk = 0; kk < 2; ++kk) {                                    \
            unsigned byte8 = (unsigned)(((MSK) >> (kk * 32 + kg * 8)) & 0xFF); \
            bf16x8 af;                                                      \
            _Pragma("unroll")                                               \
            for (int e = 0; e < 8; ++e)                                     \
                af[e] = ((byte8 >> e) & 1) ? (short)0x3F80 : (short)0;      \
            _Pragma("unroll")                                               \
            for (int jt = 0; jt < 4; ++jt) {                                \
                acc[jt] = __builtin_amdgcn_mfma_f32_16x16x32_bf16(          \
                    af, bh[jt][kk], acc[jt], 0, 0, 0);                      \
                acc[jt] = __builtin_amdgcn_mfma_f32_16x16x32_bf16(          \
                    af, bl[jt][kk], acc[jt], 0, 0, 0);                      \
            }                                                               \
        }                                                                   \
        _Pragma("unroll")                                                   \
        for (int jt = 0; jt < 4; ++jt)                                      \
            _Pragma("unroll")                                               \
            for (int rr = 0; rr < 4; ++rr)                                  \
                Ilds[P][kg * 4 + rr][jt * 16 + r16] = acc[jt][rr];          \
    }

    u64 mc = LOADM(0);
    L0_COMPUTE(mc, 0);
    u64 mn = LOADM(1);
    for (int tt = 0; tt < ntile; ++tt) {
        __builtin_amdgcn_s_barrier();            // tile tt resident
        float v[16];
#pragma unroll
        for (int u = 0; u < 16; ++u)
            v[u] = Ilds[tt & 1][u][lane];
        u64 m2 = LOADM(tt + 2);
        if (tt + 1 < ntile) L0_COMPUTE(mn, (tt + 1) & 1);
        unsigned short o[16];
#pragma unroll
        for (int u = 0; u < 16; ++u) {
            m = fmaf(beta, m, v[u] + bj);
            bool sp = (m >= 1.0f);
            o[u] = sp ? (unsigned short)0x3F80 : (unsigned short)0;
            m = sp ? 0.f : m;
        }
#pragma unroll
        for (int u = 0; u < 16; ++u)
            ((unsigned short*)S)[(size_t)(tt * 16 + u) * stride + gid] = o[u];
        mn = m2;
    }
    mstate[gid] = m;
#undef L0_COMPUTE
#undef LOADM
}

// hidden layer 1 scan: counted-vmcnt LDS double buffer, 16B/lane staging.
// Per glds instr: lane l stages row 4g+(l>>4), cols (l&15)*4..+3 of the
// block's 64-col slice -> LDS image is exactly row-major [SEGH][64].
__global__ __launch_bounds__(64) void k_scan_hidden(
    const float* __restrict__ I, const float* __restrict__ bias,
    float* __restrict__ mstate, bf16* __restrict__ S, int Tc, float beta) {
    __shared__ __align__(16) float segA[SEGH * 64];
    __shared__ __align__(16) float segB[SEGH * 64];
    const int lane = threadIdx.x;
    const int gid  = blockIdx.x * 64 + lane;
    const int j = gid & (NH - 1);
    float m = mstate[gid];
    const float bj = bias[j];
    const size_t stride = (size_t)NB * NH;
    const int nseg = Tc / SEGH;                  // even (Tc % 400 == 0)
    const int lrow = lane >> 4;                  // staging sub-row 0..3
    const int lcol = (lane & 15) << 2;           // staging col 0..60

#define H_PREFETCH(SEGBUF, SIDX)                                            \
    {                                                                       \
        const float* src = I + (size_t)(SIDX) * SEGH * stride               \
                             + (size_t)lrow * stride + blockIdx.x * 64 + lcol; \
        _Pragma("unroll")                                                   \
        for (int g = 0; g < SEGH / 4; ++g)                                  \
            __builtin_amdgcn_global_load_lds(                               \
                ASG(src + (size_t)(g * 4) * stride),                        \
                ASL(&SEGBUF[g * 256]), 16, 0, 0);                           \
    }

#define H_PROC(SEGBUF, SIDX)                                                \
    {                                                                       \
        const int btt = (SIDX) * SEGH;                                      \
        _Pragma("unroll")                                                   \
        for (int sb = 0; sb < SEGH / 8; ++sb) {                             \
            float v[8];                                                     \
            _Pragma("unroll")                                               \
            for (int u = 0; u < 8; ++u)                                     \
                v[u] = SEGBUF[(sb * 8 + u) * 64 + lane];                    \
            unsigned short o[8];                                            \
            _Pragma("unroll")                                               \
            for (int u = 0; u < 8; ++u) {                                   \
                m = fmaf(beta, m, v[u] + bj);                               \
                bool sp = (m >= 1.0f);                                      \
                o[u] = sp ? (unsigned short)0x3F80 : (unsigned short)0;     \
                m = sp ? 0.f : m;                                           \
            }                                                               \
            _Pragma("unroll")                                               \
            for (int u = 0; u < 8; ++u)                                     \
                ((unsigned short*)S)[(size_t)(btt + sb * 8 + u) * stride + gid] = o[u]; \
        }                                                                   \
    }

    H_PREFETCH(segA, 0);
    for (int s = 0; s < nseg; s += 2) {
        H_PREFETCH(segB, s + 1);
        asm volatile("s_waitcnt vmcnt(10)" ::: "memory"); // segA resident
        __builtin_amdgcn_sched_barrier(0);
        H_PROC(segA, s);
        if (s + 2 < nseg) {
            H_PREFETCH(segA, s + 2);
            asm volatile("s_waitcnt vmcnt(10)" ::: "memory"); // segB resident
        } else {
            asm volatile("s_waitcnt vmcnt(0)" ::: "memory");
        }
        __builtin_amdgcn_sched_barrier(0);
        H_PROC(segB, s + 1);
    }
    mstate[gid] = m;
#undef H_PREFETCH
#undef H_PROC
}

// output layer scan: wave w stages full rows {w+4g} with 16B/lane (one row
// = 64 lanes x 16B = 256 floats). LDS row-major [SEGO][256].
__global__ __launch_bounds__(256) void k_scan_out(
    const float* __restrict__ I2, const float* __restrict__ bias,
    float* __restrict__ mstate, float* __restrict__ out,
    int Tc, int t0, float beta) {
    __shared__ __align__(16) float segA[SEGO * 256];
    __shared__ __align__(16) float segB[SEGO * 256];
    const int tid  = threadIdx.x;
    const int lane = tid & 63;
    const int wave = tid >> 6;
    const int k = tid & 15;
    const int b = tid >> 4;
    float m = mstate[tid];
    float bj = (k < N_OUT) ? bias[k] : 0.f;
    const int nseg = Tc / SEGO;                  // even (Tc % 400 == 0)

#define O_PREFETCH(SEGBUF, SIDX)                                            \
    {                                                                       \
        const float* src = I2 + (size_t)(SIDX) * SEGO * 256                 \
                              + (size_t)wave * 256 + lane * 4;              \
        _Pragma("unroll")                                                   \
        for (int g = 0; g < SEGO / 4; ++g)                                  \
            __builtin_amdgcn_global_load_lds(                               \
                ASG(src + (size_t)(g * 4) * 256),                           \
                ASL(&SEGBUF[(g * 4 + wave) * 256]), 16, 0, 0);              \
    }

#define O_PROC(SEGBUF, SIDX)                                                \
    {                                                                       \
        const int btt = (SIDX) * SEGO;                                      \
        _Pragma("unroll")                                                   \
        for (int sb = 0; sb < SEGO / 8; ++sb) {                             \
            float v[8];                                                     \
            _Pragma("unroll")                                               \
            for (int u = 0; u < 8; ++u)                                     \
                v[u] = SEGBUF[(sb * 8 + u) * 256 + tid];                    \
            float o[8];                                                     \
            _Pragma("unroll")                                               \
            for (int u = 0; u < 8; ++u) {                                   \
                m = fmaf(beta, m, v[u] + bj);                               \
                bool sp = (m >= 1.0f);                                      \
                o[u] = sp ? 1.f : 0.f;                                      \
                m = sp ? 0.f : m;                                           \
            }                                                               \
            if (k < N_OUT) {                                                \
                _Pragma("unroll")                                           \
                for (int u = 0; u < 8; ++u)                                 \
                    out[((size_t)(t0 + btt + sb * 8 + u) * NB + b) * N_OUT + k] = o[u]; \
            }                                                               \
        }                                                                   \
    }

    O_PREFETCH(segA, 0);
    for (int s = 0; s < nseg; s += 2) {
        O_PREFETCH(segB, s + 1);
        asm volatile("s_waitcnt vmcnt(10)" ::: "memory"); // segA resident
        __builtin_amdgcn_sched_barrier(0);
        __builtin_amdgcn_s_barrier();                     // all waves' rows in
        O_PROC(segA, s);
        if (s + 2 < nseg) {
            O_PREFETCH(segA, s + 2);
            asm volatile("s_waitcnt vmcnt(10)" ::: "memory"); // segB resident
        } else {
            asm volatile("s_waitcnt vmcnt(0)" ::: "memory");
        }
        __builtin_amdgcn_sched_barrier(0);
        __builtin_amdgcn_s_barrier();
        O_PROC(segB, s + 1);
    }
    mstate[tid] = m;
#undef O_PREFETCH
#undef O_PROC
}

// ---------------- host ----------------

extern "C" void kernel_launch(void* const* d_in, const int* in_sizes, int n_in,
                              void* d_out, int out_size, void* d_ws, size_t ws_size,
                              hipStream_t stream) {
    const float* in_sp = (const float*)d_in[0];
    const float* W0 = (const float*)d_in[1];
    const float* b0 = (const float*)d_in[2];
    const float* W1 = (const float*)d_in[3];
    const float* b1 = (const float*)d_in[4];
    const float* W2 = (const float*)d_in[5];
    const float* b2 = (const float*)d_in[6];
    float* out = (float*)d_out;

    char* p = (char*)d_ws;
    auto carve = [&](size_t bytes) -> void* {
        char* r = p; p += (bytes + 255) & ~(size_t)255; return (void*)r;
    };
    u64*  MASK = (u64*)carve((size_t)T_STEPS * NB * 8);
    bf16* BT1  = (bf16*)carve((size_t)NH * 2 * NH * 2);
    bf16* BT2  = (bf16*)carve((size_t)128 * 2 * NH * 2);
    float* m0s = (float*)carve((size_t)NB * NH * 4);
    float* m1s = (float*)carve((size_t)NB * NH * 4);
    float* m2s = (float*)carve((size_t)NB * 16 * 4);
    size_t fixed = (size_t)(p - (char*)d_ws);

    // Tc | 4000, Tc % 400 == 0 (scan segs even; L0 tiles of 16; Mc % 256 == 0)
    const int tc_opts[3] = {2000, 800, 400};
    int Tc = 400;
    for (int i = 0; i < 3; ++i) {
        size_t Mc_ = (size_t)tc_opts[i] * NB;
        size_t need = fixed
            + ((Mc_ * NH * 4 + 255) & ~(size_t)255)
            + ((Mc_ * 16 * 4 + 255) & ~(size_t)255)
            + ((Mc_ * NH * 2 + 255) & ~(size_t)255);
        if (need <= ws_size) { Tc = tc_opts[i]; break; }
    }
    size_t Mc = (size_t)Tc * NB;
    float* IBUF  = (float*)carve(Mc * NH * 4);
    float* I2BUF = (float*)carve(Mc * 16 * 4);
    bf16*  S     = (bf16*)carve(Mc * NH * 2);

    const float beta = (float)exp(-0.25 / 10.0);

    // m0s/m1s/m2s contiguous: one zero kernel.
    int nM = NB * NH * 2 + NB * 16;
    k_zero<<<(nM + 255) / 256, 256, 0, stream>>>(m0s, nM);

    // input spike masks (one wave per (t,b))
    k_mask<<<(T_STEPS * NB * 64) / 256, 256, 0, stream>>>(in_sp, MASK, T_STEPS * NB);

    k_limbs_t<<<256, 256, 0, stream>>>(W1, BT1);
    k_limbs<<<(128 * 2 * NH + 255) / 256, 256, 0, stream>>>(W2, BT2, NH, N_OUT, 128);

    const int C = T_STEPS / Tc;
    const int gx8 = (int)(Mc / 256);
    const int gthin = (int)(Mc / 64);
    for (int c = 0; c < C; ++c) {
        int t0 = c * Tc;
        // layer 0: fused MFMA scan (exact fp32 via limbs)
        k_scan_l0<<<256, 64, 0, stream>>>(MASK + (size_t)t0 * NB, W0, b0,
                                          m0s, S, Tc, beta);
        // layer 1: 256^2 8-phase GEMM
        k_gemm8<<<gx8 * 4, 512, 0, stream>>>(S, BT1, IBUF, gx8);
        k_scan_hidden<<<(NB * NH) / 64, 64, 0, stream>>>(IBUF, b1, m1s, S, Tc, beta);
        // layer 2: thin GEMM v2 (N=16, A read once)
        k_gemm_thin<<<gthin, 256, 0, stream>>>(S, BT2, I2BUF);
        k_scan_out<<<1, 256, 0, stream>>>(I2BUF, b2, m2s, out, Tc, t0, beta);
    }
}

// Round 16
// 840.965 us; speedup vs baseline: 2.1264x; 1.0022x over previous
//
#include <hip/hip_runtime.h>
#include <hip/hip_bf16.h>
#include <math.h>

// SNN forward: 64 -> 1024 -> 1024 -> 10, T=4000, B=16, LIF beta=exp(-0.025),
// thr=1, hard reset to 0, Dale clamp W>=0.
// R16: scan_out hoisted out of the chunk loop -- runs ONCE over full T at the
// end (I2 is a full-T 4MB buffer). Removes a 1-block whole-GPU-idle launch
// per chunk. Everything else frozen at R15.
// L0: fused MFMA scan + mask pipeline. L1: 256^2 8-phase GEMM (T2/T3/T4/T5).
// L2: thin N=16 GEMM (A read once). Scans: fp32 chains, counted vmcnt,
// 16B/lane global_load_lds staging.

#define T_STEPS 4000
#define NB 16
#define N_IN 64
#define NH 1024
#define N_OUT 10
#define SEGO 40           // scan_out segment rows; 10 glds/wave -> vmcnt(10)
#define SEGH 40           // scan_hidden segment rows; 10 glds -> vmcnt(10)

typedef __attribute__((ext_vector_type(8))) short bf16x8;
typedef __attribute__((ext_vector_type(4))) float f32x4;
typedef __hip_bfloat16 bf16;
typedef unsigned long long u64;

#define ASG(p) (const __attribute__((address_space(1))) void*)(p)
#define ASL(p) (__attribute__((address_space(3))) void*)(p)

// ---------------- small utility kernels ----------------

__global__ void k_zero(float* p, int n) {
    int i = blockIdx.x * 256 + threadIdx.x;
    if (i < n) p[i] = 0.f;
}

// Build per-(t,b) 64-bit input spike masks. One wave per (t,b).
__global__ void k_mask(const float* __restrict__ in, u64* __restrict__ mask, int total) {
    int w = (blockIdx.x * 256 + threadIdx.x) >> 6;
    int lane = threadIdx.x & 63;
    if (w >= total) return;
    float v = in[(size_t)w * 64 + lane];
    u64 bal = __ballot(v > 0.5f);
    if (lane == 0) mask[w] = bal;
}

// Transposing limb builder for BT1: W [1024 x 1024] -> BT [1024][2048],
// plain [hi | lo]. Coalesced reads, LDS transpose ([64][65] pad), coalesced
// writes.
__global__ __launch_bounds__(256) void k_limbs_t(
    const float* __restrict__ W, bf16* __restrict__ BT) {
    __shared__ float Wlds[64][65];
    const int tid  = threadIdx.x;
    const int lane = tid & 63;
    const int wr   = tid >> 6;            // 0..3
    const int k0 = (blockIdx.x & 15) * 64;
    const int n0 = (blockIdx.x >> 4) * 64;
#pragma unroll
    for (int rr = 0; rr < 16; ++rr) {
        int kl = wr * 16 + rr;
        Wlds[kl][lane] = W[(size_t)(k0 + kl) * 1024 + n0 + lane];
    }
    __syncthreads();
#pragma unroll
    for (int rr = 0; rr < 16; ++rr) {
        int nl = wr * 16 + rr;
        float w = fmaxf(Wlds[lane][nl], 0.f);      // Dale's law clamp
        bf16 h = __float2bfloat16(w);
        float hf = __bfloat162float(h);
        bf16 l = __float2bfloat16(w - hf);
        size_t base = (size_t)(n0 + nl) * 2048 + k0 + lane;
        BT[base] = h;
        BT[base + 1024] = l;
    }
}

// Small limb builder (BT2): W [K x N] -> BT [Npad x 2K] plain [hi|lo].
__global__ void k_limbs(const float* __restrict__ W, bf16* __restrict__ BT,
                        int K, int N, int Npad) {
    int idx = blockIdx.x * 256 + threadIdx.x;
    int total = Npad * 2 * K;
    if (idx >= total) return;
    int n  = idx / (2 * K);
    int k2 = idx - n * (2 * K);
    int lo = (k2 >= K);
    int k = lo ? (k2 - K) : k2;
    float v = 0.f;
    if (n < N) {
        float w = fmaxf(W[(size_t)k * N + n], 0.f);
        float hi = __bfloat162float(__float2bfloat16(w));
        v = lo ? (w - hi) : w;
    }
    BT[idx] = __float2bfloat16(v);
}

// ---------------- thin GEMM v2 (layer 2): C[M x 16] = A[M x 1024] @ BT^T ---
// A read ONCE per row (hi and lo B both consumed per A-frag). 64 rows/block.

__global__ __launch_bounds__(256) void k_gemm_thin(
    const bf16* __restrict__ A, const bf16* __restrict__ BT,
    float* __restrict__ C) {
    const int tid  = threadIdx.x;
    const int lane = tid & 63;
    const int wave = tid >> 6;
    const int r16 = lane & 15;
    const int kg  = lane >> 4;
    const int m0 = blockIdx.x * 64 + wave * 16;
    f32x4 acc = {};
    const bf16* ap = A + (size_t)(m0 + r16) * 1024 + kg * 8;
    const bf16* bh = BT + (size_t)r16 * 2048 + kg * 8;   // hi limb cols
    const bf16* bl = bh + 1024;                          // lo limb cols
#pragma unroll 8
    for (int kt = 0; kt < 32; ++kt) {
        const int ka = kt * 32;
        bf16x8 af  = *(const bf16x8*)(ap + ka);
        bf16x8 bfh = *(const bf16x8*)(bh + ka);
        bf16x8 bfl = *(const bf16x8*)(bl + ka);
        acc = __builtin_amdgcn_mfma_f32_16x16x32_bf16(af, bfh, acc, 0, 0, 0);
        acc = __builtin_amdgcn_mfma_f32_16x16x32_bf16(af, bfl, acc, 0, 0, 0);
    }
#pragma unroll
    for (int rr = 0; rr < 4; ++rr)
        C[(size_t)(m0 + kg * 4 + rr) * 16 + r16] = acc[rr];
}

// ---------------- 256^2 8-phase GEMM (layer 1) ----------------
// Stage ordering invariant (R8): a region is staged only in a phase after all
// ds_reads of it have drained past a barrier (A at P3, B at P2).

__global__ __launch_bounds__(512) void k_gemm8(
    const bf16* __restrict__ A, const bf16* __restrict__ BT,
    float* __restrict__ C, int gx) {
    const int KA = 1024, K2 = 2048;
    const int kmask = KA - 1;
    const int nwg = gridDim.x;
    const int wg  = blockIdx.x;
    const int q = nwg >> 3, r = nwg & 7;
    const int xcd = wg & 7, idx0 = wg >> 3;
    const int swz = (xcd < r ? xcd * (q + 1) : r * (q + 1) + (xcd - r) * q) + idx0;
    const int gy = nwg / gx;              // 4
    const int n0 = (swz % gy) * 256;
    const int m0 = (swz / gy) * 256;

    __shared__ __align__(16) char LDS[131072];
    const int tid  = threadIdx.x;
    const int lane = tid & 63;
    const int wave = tid >> 6;
    const int wm = (wave >> 2) * 128;
    const int wn = (wave & 3) * 64;
    const int r16l = lane & 15;
    const int kg   = lane >> 4;
    const int hA   = wave >> 2;
    const int hB   = (wave & 3) >> 1;
    const int wn64 = wave & 1;

    const int po = (r16l * 64 + kg * 16) ^ (((r16l >> 3) & 1) << 5);
    const char* bA[2] = { LDS + hA * 16384 + po,
                          LDS + 65536 + hA * 16384 + po };
    const char* bB[2] = { LDS + 32768 + hB * 16384 + po,
                          LDS + 98304 + hB * 16384 + po };
    const int bOff = wn64 * 8192;

    int s_row[2], s_col[2];
#pragma unroll
    for (int rr = 0; rr < 2; ++rr) {
        int d = (rr * 512 + tid) * 16;
        int l = d ^ (((d >> 9) & 1) << 5);
        int sub = l >> 10;
        int w = l & 1023;
        s_row[rr] = (sub >> 1) * 16 + (w >> 6);
        s_col[rr] = ((sub & 1) * 64 + (w & 63)) >> 1;
    }

#define HBASE(BUF, OP, HALF) ((((BUF) * 2 + (OP)) * 2 + (HALF)) * 16384)
#define STAGE_A(BUF, HALF, K0)                                              \
    {                                                                       \
        _Pragma("unroll")                                                   \
        for (int rr = 0; rr < 2; ++rr)                                      \
            __builtin_amdgcn_global_load_lds(                               \
                ASG(A + (size_t)(m0 + (HALF) * 128 + s_row[rr]) * KA        \
                    + (((K0) + s_col[rr]) & kmask)),                        \
                ASL(LDS + HBASE(BUF, 0, HALF) + (rr * 512 + wave * 64) * 16), \
                16, 0, 0);                                                  \
    }
#define STAGE_B(BUF, HALF, K0)                                              \
    {                                                                       \
        _Pragma("unroll")                                                   \
        for (int rr = 0; rr < 2; ++rr)                                      \
            __builtin_amdgcn_global_load_lds(                               \
                ASG(BT + (size_t)(n0 + (HALF) * 128 + s_row[rr]) * K2       \
                    + (K0) + s_col[rr]),                                    \
                ASL(LDS + HBASE(BUF, 1, HALF) + (rr * 512 + wave * 64) * 16), \
                16, 0, 0);                                                  \
    }

    f32x4 acc[8][4] = {};
    bf16x8 a[4][2], b[4][2];

#define MM(MIB, NIB)                                                        \
    {                                                                       \
        _Pragma("unroll")                                                   \
        for (int i = 0; i < 4; ++i)                                         \
            _Pragma("unroll")                                               \
            for (int j = 0; j < 2; ++j) {                                   \
                acc[(MIB) + i][(NIB) + j] =                                 \
                    __builtin_amdgcn_mfma_f32_16x16x32_bf16(                \
                        a[i][0], b[(NIB) + j][0], acc[(MIB) + i][(NIB) + j], 0, 0, 0); \
                acc[(MIB) + i][(NIB) + j] =                                 \
                    __builtin_amdgcn_mfma_f32_16x16x32_bf16(                \
                        a[i][1], b[(NIB) + j][1], acc[(MIB) + i][(NIB) + j], 0, 0, 0); \
            }                                                               \
    }

#define PH_SYNC()                                                           \
    __builtin_amdgcn_s_barrier();                                           \
    asm volatile("s_waitcnt lgkmcnt(0)" ::: "memory");                      \
    __builtin_amdgcn_sched_barrier(0);

#define KTILE(BUF, SK)                                                      \
    {                                                                       \
        _Pragma("unroll")                                                   \
        for (int i = 0; i < 4; ++i) {                                       \
            a[i][0] = *(const bf16x8*)(bA[BUF] + i * 2048);                 \
            a[i][1] = *(const bf16x8*)(bA[BUF] + i * 2048 + 1024);          \
        }                                                                   \
        _Pragma("unroll")                                                   \
        for (int j = 0; j < 2; ++j) {                                       \
            b[j][0] = *(const bf16x8*)(bB[BUF] + bOff + j * 2048);          \
            b[j][1] = *(const bf16x8*)(bB[BUF] + bOff + j * 2048 + 1024);   \
        }                                                                   \
        PH_SYNC();                                                          \
        __builtin_amdgcn_s_setprio(1);                                      \
        MM(0, 0);                                                           \
        __builtin_amdgcn_s_setprio(0);                                      \
        __builtin_amdgcn_s_barrier();                                       \
        _Pragma("unroll")                                                   \
        for (int j = 0; j < 2; ++j) {                                       \
            b[2 + j][0] = *(const bf16x8*)(bB[BUF] + bOff + (2 + j) * 2048); \
            b[2 + j][1] = *(const bf16x8*)(bB[BUF] + bOff + (2 + j) * 2048 + 1024); \
        }                                                                   \
        PH_SYNC();                                                          \
        __builtin_amdgcn_s_setprio(1);                                      \
        MM(0, 2);                                                           \
        __builtin_amdgcn_s_setprio(0);                                      \
        __builtin_amdgcn_s_barrier();                                       \
        _Pragma("unroll")                                                   \
        for (int i = 0; i < 4; ++i) {                                       \
            a[i][0] = *(const bf16x8*)(bA[BUF] + (4 + i) * 2048);           \
            a[i][1] = *(const bf16x8*)(bA[BUF] + (4 + i) * 2048 + 1024);    \
        }                                                                   \
        STAGE_B(BUF, 0, SK);                                                \
        STAGE_B(BUF, 1, SK);                                                \
        PH_SYNC();                                                          \
        __builtin_amdgcn_s_setprio(1);                                      \
        MM(4, 0);                                                           \
        __builtin_amdgcn_s_setprio(0);                                      \
        __builtin_amdgcn_s_barrier();                                       \
        STAGE_A(BUF, 0, SK);                                                \
        STAGE_A(BUF, 1, SK);                                                \
        PH_SYNC();                                                          \
        __builtin_amdgcn_s_setprio(1);                                      \
        MM(4, 2);                                                           \
        __builtin_amdgcn_s_setprio(0);                                      \
        asm volatile("s_waitcnt vmcnt(8)" ::: "memory");                    \
        __builtin_amdgcn_sched_barrier(0);                                  \
        __builtin_amdgcn_s_barrier();                                       \
    }

    STAGE_A(0, 0, 0);  STAGE_A(0, 1, 0);  STAGE_B(0, 0, 0);  STAGE_B(0, 1, 0);
    STAGE_A(1, 0, 64); STAGE_A(1, 1, 64); STAGE_B(1, 0, 64); STAGE_B(1, 1, 64);
    asm volatile("s_waitcnt vmcnt(8)" ::: "memory");
    __builtin_amdgcn_sched_barrier(0);
    __builtin_amdgcn_s_barrier();

    for (int it = 0; it < 16; ++it) {
        const int k0  = it * 128;
        const int ksA = (k0 + 128) & (K2 - 1);
        const int ksB = (k0 + 192) & (K2 - 1);
        KTILE(0, ksA);
        KTILE(1, ksB);
    }
    asm volatile("s_waitcnt vmcnt(0)" ::: "memory");
    __builtin_amdgcn_sched_barrier(0);

#pragma unroll
    for (int mi = 0; mi < 8; ++mi)
#pragma unroll
        for (int ni = 0; ni < 4; ++ni)
#pragma unroll
            for (int rr = 0; rr < 4; ++rr) {
                int row = m0 + wm + mi * 16 + kg * 4 + rr;
                int col = n0 + wn + ni * 16 + r16l;
                C[(size_t)row * 1024 + col] = acc[mi][ni][rr];
            }
#undef KTILE
#undef PH_SYNC
#undef MM
#undef STAGE_A
#undef STAGE_B
#undef HBASE
}

// ---------------- LIF scan kernels (fp32 membranes) ----------------

// L0 fused scan via MFMA + mask software-pipeline. 256 blocks x 64 threads.
__global__ __launch_bounds__(64) void k_scan_l0(
    const u64* __restrict__ mask,          // [Tc][NB] for this chunk
    const float* __restrict__ W0,          // [64][1024] row-major
    const float* __restrict__ bias,
    float* __restrict__ mstate, bf16* __restrict__ S, int Tc, float beta) {
    __shared__ float Ilds[2][16][68];
    const int lane = threadIdx.x;
    const int gid  = blockIdx.x * 64 + lane;   // = b*1024 + q*64 + lane
    const int b  = blockIdx.x >> 4;
    const int q  = blockIdx.x & 15;
    const int j0 = q * 64;
    const int r16 = lane & 15;
    const int kg  = lane >> 4;
    bf16x8 bh[4][2], bl[4][2];
#pragma unroll
    for (int jt = 0; jt < 4; ++jt)
#pragma unroll
        for (int kk = 0; kk < 2; ++kk)
#pragma unroll
            for (int e = 0; e < 8; ++e) {
                int k = kk * 32 + kg * 8 + e;
                float w = fmaxf(W0[(size_t)k * 1024 + j0 + jt * 16 + r16], 0.f);
                bf16 h = __float2bfloat16(w);
                float hf = __bfloat162float(h);
                bf16 l = __float2bfloat16(w - hf);
                bh[jt][kk][e] = *(short*)&h;
                bl[jt][kk][e] = *(short*)&l;
            }
    float m = mstate[gid];
    const float bj = bias[j0 + lane];
    const size_t stride = (size_t)NB * NH;
    const int ntile = Tc / 16;
    const int tmax = ntile - 1;

#define LOADM(TT) mask[(size_t)(((TT) <= tmax ? (TT) : tmax) * 16 + r16) * NB + b]

#define L0_COMPUTE(MSK, P)                                                  \
    {                                                                       \
        f32x4 acc[4] = {};                                                  \
        _Pragma("unroll")                                                   \
        for (int kk = 0; kk < 2; ++kk) {                                    \
            unsigned byte8 = (unsigned)(((MSK) >> (kk * 32 + kg * 8)) & 0xFF); \
            bf16x8 af;                                                      \
            _Pragma("unroll")                                               \
            for (int e = 0; e < 8; ++e)                                     \
                af[e] = ((byte8 >> e) & 1) ? (short)0x3F80 : (short)0;      \
            _Pragma("unroll")                                               \
            for (int jt = 0; jt < 4; ++jt) {                                \
                acc[jt] = __builtin_amdgcn_mfma_f32_16x16x32_bf16(          \
                    af, bh[jt][kk], acc[jt], 0, 0, 0);                      \
                acc[jt] = __builtin_amdgcn_mfma_f32_16x16x32_bf16(          \
                    af, bl[jt][kk], acc[jt], 0, 0, 0);                      \
            }                                                               \
        }                                                                   \
        _Pragma("unroll")                                                   \
        for (int jt = 0; jt < 4; ++jt)                                      \
            _Pragma("unroll")                                               \
            for (int rr = 0; rr < 4; ++rr)                                  \
                Ilds[P][kg * 4 + rr][jt * 16 + r16] = acc[jt][rr];          \
    }

    u64 mc = LOADM(0);
    L0_COMPUTE(mc, 0);
    u64 mn = LOADM(1);
    for (int tt = 0; tt < ntile; ++tt) {
        __builtin_amdgcn_s_barrier();            // tile tt resident
        float v[16];
#pragma unroll
        for (int u = 0; u < 16; ++u)
            v[u] = Ilds[tt & 1][u][lane];
        u64 m2 = LOADM(tt + 2);
        if (tt + 1 < ntile) L0_COMPUTE(mn, (tt + 1) & 1);
        unsigned short o[16];
#pragma unroll
        for (int u = 0; u < 16; ++u) {
            m = fmaf(beta, m, v[u] + bj);
            bool sp = (m >= 1.0f);
            o[u] = sp ? (unsigned short)0x3F80 : (unsigned short)0;
            m = sp ? 0.f : m;
        }
#pragma unroll
        for (int u = 0; u < 16; ++u)
            ((unsigned short*)S)[(size_t)(tt * 16 + u) * stride + gid] = o[u];
        mn = m2;
    }
    mstate[gid] = m;
#undef L0_COMPUTE
#undef LOADM
}

// hidden layer 1 scan: counted-vmcnt LDS double buffer, 16B/lane staging.
__global__ __launch_bounds__(64) void k_scan_hidden(
    const float* __restrict__ I, const float* __restrict__ bias,
    float* __restrict__ mstate, bf16* __restrict__ S, int Tc, float beta) {
    __shared__ __align__(16) float segA[SEGH * 64];
    __shared__ __align__(16) float segB[SEGH * 64];
    const int lane = threadIdx.x;
    const int gid  = blockIdx.x * 64 + lane;
    const int j = gid & (NH - 1);
    float m = mstate[gid];
    const float bj = bias[j];
    const size_t stride = (size_t)NB * NH;
    const int nseg = Tc / SEGH;                  // even (Tc % 400 == 0)
    const int lrow = lane >> 4;                  // staging sub-row 0..3
    const int lcol = (lane & 15) << 2;           // staging col 0..60

#define H_PREFETCH(SEGBUF, SIDX)                                            \
    {                                                                       \
        const float* src = I + (size_t)(SIDX) * SEGH * stride               \
                             + (size_t)lrow * stride + blockIdx.x * 64 + lcol; \
        _Pragma("unroll")                                                   \
        for (int g = 0; g < SEGH / 4; ++g)                                  \
            __builtin_amdgcn_global_load_lds(                               \
                ASG(src + (size_t)(g * 4) * stride),                        \
                ASL(&SEGBUF[g * 256]), 16, 0, 0);                           \
    }

#define H_PROC(SEGBUF, SIDX)                                                \
    {                                                                       \
        const int btt = (SIDX) * SEGH;                                      \
        _Pragma("unroll")                                                   \
        for (int sb = 0; sb < SEGH / 8; ++sb) {                             \
            float v[8];                                                     \
            _Pragma("unroll")                                               \
            for (int u = 0; u < 8; ++u)                                     \
                v[u] = SEGBUF[(sb * 8 + u) * 64 + lane];                    \
            unsigned short o[8];                                            \
            _Pragma("unroll")                                               \
            for (int u = 0; u < 8; ++u) {                                   \
                m = fmaf(beta, m, v[u] + bj);                               \
                bool sp = (m >= 1.0f);                                      \
                o[u] = sp ? (unsigned short)0x3F80 : (unsigned short)0;     \
                m = sp ? 0.f : m;                                           \
            }                                                               \
            _Pragma("unroll")                                               \
            for (int u = 0; u < 8; ++u)                                     \
                ((unsigned short*)S)[(size_t)(btt + sb * 8 + u) * stride + gid] = o[u]; \
        }                                                                   \
    }

    H_PREFETCH(segA, 0);
    for (int s = 0; s < nseg; s += 2) {
        H_PREFETCH(segB, s + 1);
        asm volatile("s_waitcnt vmcnt(10)" ::: "memory"); // segA resident
        __builtin_amdgcn_sched_barrier(0);
        H_PROC(segA, s);
        if (s + 2 < nseg) {
            H_PREFETCH(segA, s + 2);
            asm volatile("s_waitcnt vmcnt(10)" ::: "memory"); // segB resident
        } else {
            asm volatile("s_waitcnt vmcnt(0)" ::: "memory");
        }
        __builtin_amdgcn_sched_barrier(0);
        H_PROC(segB, s + 1);
    }
    mstate[gid] = m;
#undef H_PREFETCH
#undef H_PROC
}

// output layer scan (runs ONCE over full T): wave w stages full rows {w+4g}
// with 16B/lane. LDS row-major [SEGO][256].
__global__ __launch_bounds__(256) void k_scan_out(
    const float* __restrict__ I2, const float* __restrict__ bias,
    float* __restrict__ mstate, float* __restrict__ out,
    int Tc, int t0, float beta) {
    __shared__ __align__(16) float segA[SEGO * 256];
    __shared__ __align__(16) float segB[SEGO * 256];
    const int tid  = threadIdx.x;
    const int lane = tid & 63;
    const int wave = tid >> 6;
    const int k = tid & 15;
    const int b = tid >> 4;
    float m = mstate[tid];
    float bj = (k < N_OUT) ? bias[k] : 0.f;
    const int nseg = Tc / SEGO;                  // even

#define O_PREFETCH(SEGBUF, SIDX)                                            \
    {                                                                       \
        const float* src = I2 + (size_t)(SIDX) * SEGO * 256                 \
                              + (size_t)wave * 256 + lane * 4;              \
        _Pragma("unroll")                                                   \
        for (int g = 0; g < SEGO / 4; ++g)                                  \
            __builtin_amdgcn_global_load_lds(                               \
                ASG(src + (size_t)(g * 4) * 256),                           \
                ASL(&SEGBUF[(g * 4 + wave) * 256]), 16, 0, 0);              \
    }

#define O_PROC(SEGBUF, SIDX)                                                \
    {                                                                       \
        const int btt = (SIDX) * SEGO;                                      \
        _Pragma("unroll")                                                   \
        for (int sb = 0; sb < SEGO / 8; ++sb) {                             \
            float v[8];                                                     \
            _Pragma("unroll")                                               \
            for (int u = 0; u < 8; ++u)                                     \
                v[u] = SEGBUF[(sb * 8 + u) * 256 + tid];                    \
            float o[8];                                                     \
            _Pragma("unroll")                                               \
            for (int u = 0; u < 8; ++u) {                                   \
                m = fmaf(beta, m, v[u] + bj);                               \
                bool sp = (m >= 1.0f);                                      \
                o[u] = sp ? 1.f : 0.f;                                      \
                m = sp ? 0.f : m;                                           \
            }                                                               \
            if (k < N_OUT) {                                                \
                _Pragma("unroll")                                           \
                for (int u = 0; u < 8; ++u)                                 \
                    out[((size_t)(t0 + btt + sb * 8 + u) * NB + b) * N_OUT + k] = o[u]; \
            }                                                               \
        }                                                                   \
    }

    O_PREFETCH(segA, 0);
    for (int s = 0; s < nseg; s += 2) {
        O_PREFETCH(segB, s + 1);
        asm volatile("s_waitcnt vmcnt(10)" ::: "memory"); // segA resident
        __builtin_amdgcn_sched_barrier(0);
        __builtin_amdgcn_s_barrier();                     // all waves' rows in
        O_PROC(segA, s);
        if (s + 2 < nseg) {
            O_PREFETCH(segA, s + 2);
            asm volatile("s_waitcnt vmcnt(10)" ::: "memory"); // segB resident
        } else {
            asm volatile("s_waitcnt vmcnt(0)" ::: "memory");
        }
        __builtin_amdgcn_sched_barrier(0);
        __builtin_amdgcn_s_barrier();
        O_PROC(segB, s + 1);
    }
    mstate[tid] = m;
#undef O_PREFETCH
#undef O_PROC
}

// ---------------- host ----------------

extern "C" void kernel_launch(void* const* d_in, const int* in_sizes, int n_in,
                              void* d_out, int out_size, void* d_ws, size_t ws_size,
                              hipStream_t stream) {
    const float* in_sp = (const float*)d_in[0];
    const float* W0 = (const float*)d_in[1];
    const float* b0 = (const float*)d_in[2];
    const float* W1 = (const float*)d_in[3];
    const float* b1 = (const float*)d_in[4];
    const float* W2 = (const float*)d_in[5];
    const float* b2 = (const float*)d_in[6];
    float* out = (float*)d_out;

    char* p = (char*)d_ws;
    auto carve = [&](size_t bytes) -> void* {
        char* r = p; p += (bytes + 255) & ~(size_t)255; return (void*)r;
    };
    u64*  MASK  = (u64*)carve((size_t)T_STEPS * NB * 8);
    bf16* BT1   = (bf16*)carve((size_t)NH * 2 * NH * 2);
    bf16* BT2   = (bf16*)carve((size_t)128 * 2 * NH * 2);
    float* m0s  = (float*)carve((size_t)NB * NH * 4);
    float* m1s  = (float*)carve((size_t)NB * NH * 4);
    float* m2s  = (float*)carve((size_t)NB * 16 * 4);
    float* I2BUF = (float*)carve((size_t)T_STEPS * NB * 16 * 4);  // full T
    size_t fixed = (size_t)(p - (char*)d_ws);

    // Tc | 4000, Tc % 400 == 0 (scan segs even; L0 tiles of 16; Mc % 256 == 0)
    const int tc_opts[3] = {2000, 800, 400};
    int Tc = 400;
    for (int i = 0; i < 3; ++i) {
        size_t Mc_ = (size_t)tc_opts[i] * NB;
        size_t need = fixed
            + ((Mc_ * NH * 4 + 255) & ~(size_t)255)
            + ((Mc_ * NH * 2 + 255) & ~(size_t)255);
        if (need <= ws_size) { Tc = tc_opts[i]; break; }
    }
    size_t Mc = (size_t)Tc * NB;
    float* IBUF = (float*)carve(Mc * NH * 4);
    bf16*  S    = (bf16*)carve(Mc * NH * 2);

    const float beta = (float)exp(-0.25 / 10.0);

    // m0s/m1s/m2s contiguous: one zero kernel.
    int nM = NB * NH * 2 + NB * 16;
    k_zero<<<(nM + 255) / 256, 256, 0, stream>>>(m0s, nM);

    // input spike masks (one wave per (t,b))
    k_mask<<<(T_STEPS * NB * 64) / 256, 256, 0, stream>>>(in_sp, MASK, T_STEPS * NB);

    k_limbs_t<<<256, 256, 0, stream>>>(W1, BT1);
    k_limbs<<<(128 * 2 * NH + 255) / 256, 256, 0, stream>>>(W2, BT2, NH, N_OUT, 128);

    const int C = T_STEPS / Tc;
    const int gx8 = (int)(Mc / 256);
    const int gthin = (int)(Mc / 64);
    for (int c = 0; c < C; ++c) {
        int t0 = c * Tc;
        // layer 0: fused MFMA scan (exact fp32 via limbs)
        k_scan_l0<<<256, 64, 0, stream>>>(MASK + (size_t)t0 * NB, W0, b0,
                                          m0s, S, Tc, beta);
        // layer 1: 256^2 8-phase GEMM
        k_gemm8<<<gx8 * 4, 512, 0, stream>>>(S, BT1, IBUF, gx8);
        k_scan_hidden<<<(NB * NH) / 64, 64, 0, stream>>>(IBUF, b1, m1s, S, Tc, beta);
        // layer 2: thin GEMM v2 into the full-T I2 buffer
        k_gemm_thin<<<gthin, 256, 0, stream>>>(S, BT2,
                                               I2BUF + (size_t)t0 * NB * 16);
    }
    // output scan once over full T
    k_scan_out<<<1, 256, 0, stream>>>(I2BUF, b2, m2s, out, T_STEPS, 0, beta);
}

// Round 17
// 816.160 us; speedup vs baseline: 2.1911x; 1.0304x over previous
//
#include <hip/hip_runtime.h>
#include <hip/hip_bf16.h>
#include <math.h>

// SNN forward: 64 -> 1024 -> 1024 -> 10, T=4000, B=16, LIF beta=exp(-0.025),
// thr=1, hard reset to 0, Dale clamp W>=0.
// R17: fixed the scan vmcnt-counts-stores bug (R16 counters: scan_out 202us,
// 0% VALU -- every vmcnt(10) drained the 40 older stores of the previous
// PROC). New wait scheme per segment: PROC(40 stores) -> prefetch(10 loads)
// -> vmcnt(50) [steady: 40 stores + 10 loads newer than the needed segment's
// loads]; peel first wait vmcnt(10); tail wait vmcnt(40).
// L0: fused MFMA scan + mask pipeline. L1: 256^2 8-phase GEMM (T2/T3/T4/T5).
// L2: thin N=16 GEMM. scan_out once over full T.

#define T_STEPS 4000
#define NB 16
#define N_IN 64
#define NH 1024
#define N_OUT 10
#define SEGO 40           // scan_out segment rows; 10 glds/wave/segment
#define SEGH 40           // scan_hidden segment rows; 10 glds/segment

typedef __attribute__((ext_vector_type(8))) short bf16x8;
typedef __attribute__((ext_vector_type(4))) float f32x4;
typedef __hip_bfloat16 bf16;
typedef unsigned long long u64;

#define ASG(p) (const __attribute__((address_space(1))) void*)(p)
#define ASL(p) (__attribute__((address_space(3))) void*)(p)

// ---------------- small utility kernels ----------------

__global__ void k_zero(float* p, int n) {
    int i = blockIdx.x * 256 + threadIdx.x;
    if (i < n) p[i] = 0.f;
}

// Build per-(t,b) 64-bit input spike masks. One wave per (t,b).
__global__ void k_mask(const float* __restrict__ in, u64* __restrict__ mask, int total) {
    int w = (blockIdx.x * 256 + threadIdx.x) >> 6;
    int lane = threadIdx.x & 63;
    if (w >= total) return;
    float v = in[(size_t)w * 64 + lane];
    u64 bal = __ballot(v > 0.5f);
    if (lane == 0) mask[w] = bal;
}

// Transposing limb builder for BT1: W [1024 x 1024] -> BT [1024][2048],
// plain [hi | lo]. Coalesced reads, LDS transpose ([64][65] pad), coalesced
// writes.
__global__ __launch_bounds__(256) void k_limbs_t(
    const float* __restrict__ W, bf16* __restrict__ BT) {
    __shared__ float Wlds[64][65];
    const int tid  = threadIdx.x;
    const int lane = tid & 63;
    const int wr   = tid >> 6;            // 0..3
    const int k0 = (blockIdx.x & 15) * 64;
    const int n0 = (blockIdx.x >> 4) * 64;
#pragma unroll
    for (int rr = 0; rr < 16; ++rr) {
        int kl = wr * 16 + rr;
        Wlds[kl][lane] = W[(size_t)(k0 + kl) * 1024 + n0 + lane];
    }
    __syncthreads();
#pragma unroll
    for (int rr = 0; rr < 16; ++rr) {
        int nl = wr * 16 + rr;
        float w = fmaxf(Wlds[lane][nl], 0.f);      // Dale's law clamp
        bf16 h = __float2bfloat16(w);
        float hf = __bfloat162float(h);
        bf16 l = __float2bfloat16(w - hf);
        size_t base = (size_t)(n0 + nl) * 2048 + k0 + lane;
        BT[base] = h;
        BT[base + 1024] = l;
    }
}

// Small limb builder (BT2): W [K x N] -> BT [Npad x 2K] plain [hi|lo].
__global__ void k_limbs(const float* __restrict__ W, bf16* __restrict__ BT,
                        int K, int N, int Npad) {
    int idx = blockIdx.x * 256 + threadIdx.x;
    int total = Npad * 2 * K;
    if (idx >= total) return;
    int n  = idx / (2 * K);
    int k2 = idx - n * (2 * K);
    int lo = (k2 >= K);
    int k = lo ? (k2 - K) : k2;
    float v = 0.f;
    if (n < N) {
        float w = fmaxf(W[(size_t)k * N + n], 0.f);
        float hi = __bfloat162float(__float2bfloat16(w));
        v = lo ? (w - hi) : w;
    }
    BT[idx] = __float2bfloat16(v);
}

// ---------------- thin GEMM v2 (layer 2): C[M x 16] = A[M x 1024] @ BT^T ---
// A read ONCE per row (hi and lo B both consumed per A-frag). 64 rows/block.

__global__ __launch_bounds__(256) void k_gemm_thin(
    const bf16* __restrict__ A, const bf16* __restrict__ BT,
    float* __restrict__ C) {
    const int tid  = threadIdx.x;
    const int lane = tid & 63;
    const int wave = tid >> 6;
    const int r16 = lane & 15;
    const int kg  = lane >> 4;
    const int m0 = blockIdx.x * 64 + wave * 16;
    f32x4 acc = {};
    const bf16* ap = A + (size_t)(m0 + r16) * 1024 + kg * 8;
    const bf16* bh = BT + (size_t)r16 * 2048 + kg * 8;   // hi limb cols
    const bf16* bl = bh + 1024;                          // lo limb cols
#pragma unroll 8
    for (int kt = 0; kt < 32; ++kt) {
        const int ka = kt * 32;
        bf16x8 af  = *(const bf16x8*)(ap + ka);
        bf16x8 bfh = *(const bf16x8*)(bh + ka);
        bf16x8 bfl = *(const bf16x8*)(bl + ka);
        acc = __builtin_amdgcn_mfma_f32_16x16x32_bf16(af, bfh, acc, 0, 0, 0);
        acc = __builtin_amdgcn_mfma_f32_16x16x32_bf16(af, bfl, acc, 0, 0, 0);
    }
#pragma unroll
    for (int rr = 0; rr < 4; ++rr)
        C[(size_t)(m0 + kg * 4 + rr) * 16 + r16] = acc[rr];
}

// ---------------- 256^2 8-phase GEMM (layer 1) ----------------
// Stage ordering invariant (R8): a region is staged only in a phase after all
// ds_reads of it have drained past a barrier (A at P3, B at P2).

__global__ __launch_bounds__(512) void k_gemm8(
    const bf16* __restrict__ A, const bf16* __restrict__ BT,
    float* __restrict__ C, int gx) {
    const int KA = 1024, K2 = 2048;
    const int kmask = KA - 1;
    const int nwg = gridDim.x;
    const int wg  = blockIdx.x;
    const int q = nwg >> 3, r = nwg & 7;
    const int xcd = wg & 7, idx0 = wg >> 3;
    const int swz = (xcd < r ? xcd * (q + 1) : r * (q + 1) + (xcd - r) * q) + idx0;
    const int gy = nwg / gx;              // 4
    const int n0 = (swz % gy) * 256;
    const int m0 = (swz / gy) * 256;

    __shared__ __align__(16) char LDS[131072];
    const int tid  = threadIdx.x;
    const int lane = tid & 63;
    const int wave = tid >> 6;
    const int wm = (wave >> 2) * 128;
    const int wn = (wave & 3) * 64;
    const int r16l = lane & 15;
    const int kg   = lane >> 4;
    const int hA   = wave >> 2;
    const int hB   = (wave & 3) >> 1;
    const int wn64 = wave & 1;

    const int po = (r16l * 64 + kg * 16) ^ (((r16l >> 3) & 1) << 5);
    const char* bA[2] = { LDS + hA * 16384 + po,
                          LDS + 65536 + hA * 16384 + po };
    const char* bB[2] = { LDS + 32768 + hB * 16384 + po,
                          LDS + 98304 + hB * 16384 + po };
    const int bOff = wn64 * 8192;

    int s_row[2], s_col[2];
#pragma unroll
    for (int rr = 0; rr < 2; ++rr) {
        int d = (rr * 512 + tid) * 16;
        int l = d ^ (((d >> 9) & 1) << 5);
        int sub = l >> 10;
        int w = l & 1023;
        s_row[rr] = (sub >> 1) * 16 + (w >> 6);
        s_col[rr] = ((sub & 1) * 64 + (w & 63)) >> 1;
    }

#define HBASE(BUF, OP, HALF) ((((BUF) * 2 + (OP)) * 2 + (HALF)) * 16384)
#define STAGE_A(BUF, HALF, K0)                                              \
    {                                                                       \
        _Pragma("unroll")                                                   \
        for (int rr = 0; rr < 2; ++rr)                                      \
            __builtin_amdgcn_global_load_lds(                               \
                ASG(A + (size_t)(m0 + (HALF) * 128 + s_row[rr]) * KA        \
                    + (((K0) + s_col[rr]) & kmask)),                        \
                ASL(LDS + HBASE(BUF, 0, HALF) + (rr * 512 + wave * 64) * 16), \
                16, 0, 0);                                                  \
    }
#define STAGE_B(BUF, HALF, K0)                                              \
    {                                                                       \
        _Pragma("unroll")                                                   \
        for (int rr = 0; rr < 2; ++rr)                                      \
            __builtin_amdgcn_global_load_lds(                               \
                ASG(BT + (size_t)(n0 + (HALF) * 128 + s_row[rr]) * K2       \
                    + (K0) + s_col[rr]),                                    \
                ASL(LDS + HBASE(BUF, 1, HALF) + (rr * 512 + wave * 64) * 16), \
                16, 0, 0);                                                  \
    }

    f32x4 acc[8][4] = {};
    bf16x8 a[4][2], b[4][2];

#define MM(MIB, NIB)                                                        \
    {                                                                       \
        _Pragma("unroll")                                                   \
        for (int i = 0; i < 4; ++i)                                         \
            _Pragma("unroll")                                               \
            for (int j = 0; j < 2; ++j) {                                   \
                acc[(MIB) + i][(NIB) + j] =                                 \
                    __builtin_amdgcn_mfma_f32_16x16x32_bf16(                \
                        a[i][0], b[(NIB) + j][0], acc[(MIB) + i][(NIB) + j], 0, 0, 0); \
                acc[(MIB) + i][(NIB) + j] =                                 \
                    __builtin_amdgcn_mfma_f32_16x16x32_bf16(                \
                        a[i][1], b[(NIB) + j][1], acc[(MIB) + i][(NIB) + j], 0, 0, 0); \
            }                                                               \
    }

#define PH_SYNC()                                                           \
    __builtin_amdgcn_s_barrier();                                           \
    asm volatile("s_waitcnt lgkmcnt(0)" ::: "memory");                      \
    __builtin_amdgcn_sched_barrier(0);

#define KTILE(BUF, SK)                                                      \
    {                                                                       \
        _Pragma("unroll")                                                   \
        for (int i = 0; i < 4; ++i) {                                       \
            a[i][0] = *(const bf16x8*)(bA[BUF] + i * 2048);                 \
            a[i][1] = *(const bf16x8*)(bA[BUF] + i * 2048 + 1024);          \
        }                                                                   \
        _Pragma("unroll")                                                   \
        for (int j = 0; j < 2; ++j) {                                       \
            b[j][0] = *(const bf16x8*)(bB[BUF] + bOff + j * 2048);          \
            b[j][1] = *(const bf16x8*)(bB[BUF] + bOff + j * 2048 + 1024);   \
        }                                                                   \
        PH_SYNC();                                                          \
        __builtin_amdgcn_s_setprio(1);                                      \
        MM(0, 0);                                                           \
        __builtin_amdgcn_s_setprio(0);                                      \
        __builtin_amdgcn_s_barrier();                                       \
        _Pragma("unroll")                                                   \
        for (int j = 0; j < 2; ++j) {                                       \
            b[2 + j][0] = *(const bf16x8*)(bB[BUF] + bOff + (2 + j) * 2048); \
            b[2 + j][1] = *(const bf16x8*)(bB[BUF] + bOff + (2 + j) * 2048 + 1024); \
        }                                                                   \
        PH_SYNC();                                                          \
        __builtin_amdgcn_s_setprio(1);                                      \
        MM(0, 2);                                                           \
        __builtin_amdgcn_s_setprio(0);                                      \
        __builtin_amdgcn_s_barrier();                                       \
        _Pragma("unroll")                                                   \
        for (int i = 0; i < 4; ++i) {                                       \
            a[i][0] = *(const bf16x8*)(bA[BUF] + (4 + i) * 2048);           \
            a[i][1] = *(const bf16x8*)(bA[BUF] + (4 + i) * 2048 + 1024);    \
        }                                                                   \
        STAGE_B(BUF, 0, SK);                                                \
        STAGE_B(BUF, 1, SK);                                                \
        PH_SYNC();                                                          \
        __builtin_amdgcn_s_setprio(1);                                      \
        MM(4, 0);                                                           \
        __builtin_amdgcn_s_setprio(0);                                      \
        __builtin_amdgcn_s_barrier();                                       \
        STAGE_A(BUF, 0, SK);                                                \
        STAGE_A(BUF, 1, SK);                                                \
        PH_SYNC();                                                          \
        __builtin_amdgcn_s_setprio(1);                                      \
        MM(4, 2);                                                           \
        __builtin_amdgcn_s_setprio(0);                                      \
        asm volatile("s_waitcnt vmcnt(8)" ::: "memory");                    \
        __builtin_amdgcn_sched_barrier(0);                                  \
        __builtin_amdgcn_s_barrier();                                       \
    }

    STAGE_A(0, 0, 0);  STAGE_A(0, 1, 0);  STAGE_B(0, 0, 0);  STAGE_B(0, 1, 0);
    STAGE_A(1, 0, 64); STAGE_A(1, 1, 64); STAGE_B(1, 0, 64); STAGE_B(1, 1, 64);
    asm volatile("s_waitcnt vmcnt(8)" ::: "memory");
    __builtin_amdgcn_sched_barrier(0);
    __builtin_amdgcn_s_barrier();

    for (int it = 0; it < 16; ++it) {
        const int k0  = it * 128;
        const int ksA = (k0 + 128) & (K2 - 1);
        const int ksB = (k0 + 192) & (K2 - 1);
        KTILE(0, ksA);
        KTILE(1, ksB);
    }
    asm volatile("s_waitcnt vmcnt(0)" ::: "memory");
    __builtin_amdgcn_sched_barrier(0);

#pragma unroll
    for (int mi = 0; mi < 8; ++mi)
#pragma unroll
        for (int ni = 0; ni < 4; ++ni)
#pragma unroll
            for (int rr = 0; rr < 4; ++rr) {
                int row = m0 + wm + mi * 16 + kg * 4 + rr;
                int col = n0 + wn + ni * 16 + r16l;
                C[(size_t)row * 1024 + col] = acc[mi][ni][rr];
            }
#undef KTILE
#undef PH_SYNC
#undef MM
#undef STAGE_A
#undef STAGE_B
#undef HBASE
}

// ---------------- LIF scan kernels (fp32 membranes) ----------------

// L0 fused scan via MFMA + mask software-pipeline. 256 blocks x 64 threads.
__global__ __launch_bounds__(64) void k_scan_l0(
    const u64* __restrict__ mask,          // [Tc][NB] for this chunk
    const float* __restrict__ W0,          // [64][1024] row-major
    const float* __restrict__ bias,
    float* __restrict__ mstate, bf16* __restrict__ S, int Tc, float beta) {
    __shared__ float Ilds[2][16][68];
    const int lane = threadIdx.x;
    const int gid  = blockIdx.x * 64 + lane;   // = b*1024 + q*64 + lane
    const int b  = blockIdx.x >> 4;
    const int q  = blockIdx.x & 15;
    const int j0 = q * 64;
    const int r16 = lane & 15;
    const int kg  = lane >> 4;
    bf16x8 bh[4][2], bl[4][2];
#pragma unroll
    for (int jt = 0; jt < 4; ++jt)
#pragma unroll
        for (int kk = 0; kk < 2; ++kk)
#pragma unroll
            for (int e = 0; e < 8; ++e) {
                int k = kk * 32 + kg * 8 + e;
                float w = fmaxf(W0[(size_t)k * 1024 + j0 + jt * 16 + r16], 0.f);
                bf16 h = __float2bfloat16(w);
                float hf = __bfloat162float(h);
                bf16 l = __float2bfloat16(w - hf);
                bh[jt][kk][e] = *(short*)&h;
                bl[jt][kk][e] = *(short*)&l;
            }
    float m = mstate[gid];
    const float bj = bias[j0 + lane];
    const size_t stride = (size_t)NB * NH;
    const int ntile = Tc / 16;
    const int tmax = ntile - 1;

#define LOADM(TT) mask[(size_t)(((TT) <= tmax ? (TT) : tmax) * 16 + r16) * NB + b]

#define L0_COMPUTE(MSK, P)                                                  \
    {                                                                       \
        f32x4 acc[4] = {};                                                  \
        _Pragma("unroll")                                                   \
        for (int kk = 0; kk < 2; ++kk) {                                    \
            unsigned byte8 = (unsigned)(((MSK) >> (kk * 32 + kg * 8)) & 0xFF); \
            bf16x8 af;                                                      \
            _Pragma("unroll")                                               \
            for (int e = 0; e < 8; ++e)                                     \
                af[e] = ((byte8 >> e) & 1) ? (short)0x3F80 : (short)0;      \
            _Pragma("unroll")                                               \
            for (int jt = 0; jt < 4; ++jt) {                                \
                acc[jt] = __builtin_amdgcn_mfma_f32_16x16x32_bf16(          \
                    af, bh[jt][kk], acc[jt], 0, 0, 0);                      \
                acc[jt] = __builtin_amdgcn_mfma_f32_16x16x32_bf16(          \
                    af, bl[jt][kk], acc[jt], 0, 0, 0);                      \
            }                                                               \
        }                                                                   \
        _Pragma("unroll")                                                   \
        for (int jt = 0; jt < 4; ++jt)                                      \
            _Pragma("unroll")                                               \
            for (int rr = 0; rr < 4; ++rr)                                  \
                Ilds[P][kg * 4 + rr][jt * 16 + r16] = acc[jt][rr];          \
    }

    u64 mc = LOADM(0);
    L0_COMPUTE(mc, 0);
    u64 mn = LOADM(1);
    for (int tt = 0; tt < ntile; ++tt) {
        __builtin_amdgcn_s_barrier();            // tile tt resident
        float v[16];
#pragma unroll
        for (int u = 0; u < 16; ++u)
            v[u] = Ilds[tt & 1][u][lane];
        u64 m2 = LOADM(tt + 2);
        if (tt + 1 < ntile) L0_COMPUTE(mn, (tt + 1) & 1);
        unsigned short o[16];
#pragma unroll
        for (int u = 0; u < 16; ++u) {
            m = fmaf(beta, m, v[u] + bj);
            bool sp = (m >= 1.0f);
            o[u] = sp ? (unsigned short)0x3F80 : (unsigned short)0;
            m = sp ? 0.f : m;
        }
#pragma unroll
        for (int u = 0; u < 16; ++u)
            ((unsigned short*)S)[(size_t)(tt * 16 + u) * stride + gid] = o[u];
        mn = m2;
    }
    mstate[gid] = m;
#undef L0_COMPUTE
#undef LOADM
}

// hidden layer 1 scan: LDS double buffer, 16B/lane staging, store-aware
// counted vmcnt (R17): steady wait = 40 stores + 10 loads newer = vmcnt(50).
__global__ __launch_bounds__(64) void k_scan_hidden(
    const float* __restrict__ I, const float* __restrict__ bias,
    float* __restrict__ mstate, bf16* __restrict__ S, int Tc, float beta) {
    __shared__ __align__(16) float segA[SEGH * 64];
    __shared__ __align__(16) float segB[SEGH * 64];
    const int lane = threadIdx.x;
    const int gid  = blockIdx.x * 64 + lane;
    const int j = gid & (NH - 1);
    float m = mstate[gid];
    const float bj = bias[j];
    const size_t stride = (size_t)NB * NH;
    const int nseg = Tc / SEGH;                  // even
    const int lrow = lane >> 4;
    const int lcol = (lane & 15) << 2;

#define H_PREFETCH(SEGBUF, SIDX)                                            \
    {                                                                       \
        const float* src = I + (size_t)(SIDX) * SEGH * stride               \
                             + (size_t)lrow * stride + blockIdx.x * 64 + lcol; \
        _Pragma("unroll")                                                   \
        for (int g = 0; g < SEGH / 4; ++g)                                  \
            __builtin_amdgcn_global_load_lds(                               \
                ASG(src + (size_t)(g * 4) * stride),                        \
                ASL(&SEGBUF[g * 256]), 16, 0, 0);                           \
    }

#define H_PROC(SEGBUF, SIDX)                                                \
    {                                                                       \
        const int btt = (SIDX) * SEGH;                                      \
        _Pragma("unroll")                                                   \
        for (int sb = 0; sb < SEGH / 8; ++sb) {                             \
            float v[8];                                                     \
            _Pragma("unroll")                                               \
            for (int u = 0; u < 8; ++u)                                     \
                v[u] = SEGBUF[(sb * 8 + u) * 64 + lane];                    \
            unsigned short o[8];                                            \
            _Pragma("unroll")                                               \
            for (int u = 0; u < 8; ++u) {                                   \
                m = fmaf(beta, m, v[u] + bj);                               \
                bool sp = (m >= 1.0f);                                      \
                o[u] = sp ? (unsigned short)0x3F80 : (unsigned short)0;     \
                m = sp ? 0.f : m;                                           \
            }                                                               \
            _Pragma("unroll")                                               \
            for (int u = 0; u < 8; ++u)                                     \
                ((unsigned short*)S)[(size_t)(btt + sb * 8 + u) * stride + gid] = o[u]; \
        }                                                                   \
    }

    H_PREFETCH(segA, 0);
    H_PREFETCH(segB, 1);
    asm volatile("s_waitcnt vmcnt(10)" ::: "memory");  // segA resident
    __builtin_amdgcn_sched_barrier(0);
    for (int s = 0; s < nseg; s += 2) {
        H_PROC(segA, s);                               // 40 stores
        if (s + 2 < nseg) {
            H_PREFETCH(segA, s + 2);                   // 10 loads
            asm volatile("s_waitcnt vmcnt(50)" ::: "memory");  // segB resident
        } else {
            asm volatile("s_waitcnt vmcnt(40)" ::: "memory");  // segB resident
        }
        __builtin_amdgcn_sched_barrier(0);
        H_PROC(segB, s + 1);                           // 40 stores
        if (s + 3 < nseg) {
            H_PREFETCH(segB, s + 3);
            asm volatile("s_waitcnt vmcnt(50)" ::: "memory");  // segA(s+2) resident
            __builtin_amdgcn_sched_barrier(0);
        } else if (s + 2 < nseg) {
            asm volatile("s_waitcnt vmcnt(40)" ::: "memory");
            __builtin_amdgcn_sched_barrier(0);
        }
    }
    mstate[gid] = m;
#undef H_PREFETCH
#undef H_PROC
}

// output layer scan (once over full T): wave w stages rows {w+4g}, 16B/lane.
// Store-aware counted vmcnt (R17), barriers for cross-wave row visibility.
__global__ __launch_bounds__(256) void k_scan_out(
    const float* __restrict__ I2, const float* __restrict__ bias,
    float* __restrict__ mstate, float* __restrict__ out,
    int Tc, int t0, float beta) {
    __shared__ __align__(16) float segA[SEGO * 256];
    __shared__ __align__(16) float segB[SEGO * 256];
    const int tid  = threadIdx.x;
    const int lane = tid & 63;
    const int wave = tid >> 6;
    const int k = tid & 15;
    const int b = tid >> 4;
    float m = mstate[tid];
    float bj = (k < N_OUT) ? bias[k] : 0.f;
    const int nseg = Tc / SEGO;                  // even (T=4000 -> 100)

#define O_PREFETCH(SEGBUF, SIDX)                                            \
    {                                                                       \
        const float* src = I2 + (size_t)(SIDX) * SEGO * 256                 \
                              + (size_t)wave * 256 + lane * 4;              \
        _Pragma("unroll")                                                   \
        for (int g = 0; g < SEGO / 4; ++g)                                  \
            __builtin_amdgcn_global_load_lds(                               \
                ASG(src + (size_t)(g * 4) * 256),                           \
                ASL(&SEGBUF[(g * 4 + wave) * 256]), 16, 0, 0);              \
    }

#define O_PROC(SEGBUF, SIDX)                                                \
    {                                                                       \
        const int btt = (SIDX) * SEGO;                                      \
        _Pragma("unroll")                                                   \
        for (int sb = 0; sb < SEGO / 8; ++sb) {                             \
            float v[8];                                                     \
            _Pragma("unroll")                                               \
            for (int u = 0; u < 8; ++u)                                     \
                v[u] = SEGBUF[(sb * 8 + u) * 256 + tid];                    \
            float o[8];                                                     \
            _Pragma("unroll")                                               \
            for (int u = 0; u < 8; ++u) {                                   \
                m = fmaf(beta, m, v[u] + bj);                               \
                bool sp = (m >= 1.0f);                                      \
                o[u] = sp ? 1.f : 0.f;                                      \
                m = sp ? 0.f : m;                                           \
            }                                                               \
            if (k < N_OUT) {                                                \
                _Pragma("unroll")                                           \
                for (int u = 0; u < 8; ++u)                                 \
                    out[((size_t)(t0 + btt + sb * 8 + u) * NB + b) * N_OUT + k] = o[u]; \
            }                                                               \
        }                                                                   \
    }

    O_PREFETCH(segA, 0);
    O_PREFETCH(segB, 1);
    asm volatile("s_waitcnt vmcnt(10)" ::: "memory");  // segA resident
    __builtin_amdgcn_sched_barrier(0);
    __builtin_amdgcn_s_barrier();
    for (int s = 0; s < nseg; s += 2) {
        O_PROC(segA, s);                               // 40 stores
        if (s + 2 < nseg) {
            O_PREFETCH(segA, s + 2);
            asm volatile("s_waitcnt vmcnt(50)" ::: "memory");  // segB resident
        } else {
            asm volatile("s_waitcnt vmcnt(40)" ::: "memory");
        }
        __builtin_amdgcn_sched_barrier(0);
        __builtin_amdgcn_s_barrier();
        O_PROC(segB, s + 1);
        if (s + 3 < nseg) {
            O_PREFETCH(segB, s + 3);
            asm volatile("s_waitcnt vmcnt(50)" ::: "memory");  // segA(s+2) resident
            __builtin_amdgcn_sched_barrier(0);
            __builtin_amdgcn_s_barrier();
        } else if (s + 2 < nseg) {
            asm volatile("s_waitcnt vmcnt(40)" ::: "memory");
            __builtin_amdgcn_sched_barrier(0);
            __builtin_amdgcn_s_barrier();
        }
    }
    mstate[tid] = m;
#undef O_PREFETCH
#undef O_PROC
}

// ---------------- host ----------------

extern "C" void kernel_launch(void* const* d_in, const int* in_sizes, int n_in,
                              void* d_out, int out_size, void* d_ws, size_t ws_size,
                              hipStream_t stream) {
    const float* in_sp = (const float*)d_in[0];
    const float* W0 = (const float*)d_in[1];
    const float* b0 = (const float*)d_in[2];
    const float* W1 = (const float*)d_in[3];
    const float* b1 = (const float*)d_in[4];
    const float* W2 = (const float*)d_in[5];
    const float* b2 = (const float*)d_in[6];
    float* out = (float*)d_out;

    char* p = (char*)d_ws;
    auto carve = [&](size_t bytes) -> void* {
        char* r = p; p += (bytes + 255) & ~(size_t)255; return (void*)r;
    };
    u64*  MASK  = (u64*)carve((size_t)T_STEPS * NB * 8);
    bf16* BT1   = (bf16*)carve((size_t)NH * 2 * NH * 2);
    bf16* BT2   = (bf16*)carve((size_t)128 * 2 * NH * 2);
    float* m0s  = (float*)carve((size_t)NB * NH * 4);
    float* m1s  = (float*)carve((size_t)NB * NH * 4);
    float* m2s  = (float*)carve((size_t)NB * 16 * 4);
    float* I2BUF = (float*)carve((size_t)T_STEPS * NB * 16 * 4);  // full T
    size_t fixed = (size_t)(p - (char*)d_ws);

    // Tc | 4000, Tc % 400 == 0 (scan segs even; L0 tiles of 16; Mc % 256 == 0)
    const int tc_opts[3] = {2000, 800, 400};
    int Tc = 400;
    for (int i = 0; i < 3; ++i) {
        size_t Mc_ = (size_t)tc_opts[i] * NB;
        size_t need = fixed
            + ((Mc_ * NH * 4 + 255) & ~(size_t)255)
            + ((Mc_ * NH * 2 + 255) & ~(size_t)255);
        if (need <= ws_size) { Tc = tc_opts[i]; break; }
    }
    size_t Mc = (size_t)Tc * NB;
    float* IBUF = (float*)carve(Mc * NH * 4);
    bf16*  S    = (bf16*)carve(Mc * NH * 2);

    const float beta = (float)exp(-0.25 / 10.0);

    // m0s/m1s/m2s contiguous: one zero kernel.
    int nM = NB * NH * 2 + NB * 16;
    k_zero<<<(nM + 255) / 256, 256, 0, stream>>>(m0s, nM);

    // input spike masks (one wave per (t,b))
    k_mask<<<(T_STEPS * NB * 64) / 256, 256, 0, stream>>>(in_sp, MASK, T_STEPS * NB);

    k_limbs_t<<<256, 256, 0, stream>>>(W1, BT1);
    k_limbs<<<(128 * 2 * NH + 255) / 256, 256, 0, stream>>>(W2, BT2, NH, N_OUT, 128);

    const int C = T_STEPS / Tc;
    const int gx8 = (int)(Mc / 256);
    const int gthin = (int)(Mc / 64);
    for (int c = 0; c < C; ++c) {
        int t0 = c * Tc;
        // layer 0: fused MFMA scan (exact fp32 via limbs)
        k_scan_l0<<<256, 64, 0, stream>>>(MASK + (size_t)t0 * NB, W0, b0,
                                          m0s, S, Tc, beta);
        // layer 1: 256^2 8-phase GEMM
        k_gemm8<<<gx8 * 4, 512, 0, stream>>>(S, BT1, IBUF, gx8);
        k_scan_hidden<<<(NB * NH) / 64, 64, 0, stream>>>(IBUF, b1, m1s, S, Tc, beta);
        // layer 2: thin GEMM v2 into the full-T I2 buffer
        k_gemm_thin<<<gthin, 256, 0, stream>>>(S, BT2,
                                               I2BUF + (size_t)t0 * NB * 16);
    }
    // output scan once over full T
    k_scan_out<<<1, 256, 0, stream>>>(I2BUF, b2, m2s, out, T_STEPS, 0, beta);
}

// Round 18
// 729.284 us; speedup vs baseline: 2.4521x; 1.1191x over previous
//
#include <hip/hip_runtime.h>
#include <hip/hip_bf16.h>
#include <math.h>

// SNN forward: 64 -> 1024 -> 1024 -> 10, T=4000, B=16, LIF beta=exp(-0.025),
// thr=1, hard reset to 0, Dale clamp W>=0.
// R18: scan_out store-path fix done RIGHT. R17 postmortem: FIFO vmcnt means
// waiting for segment loads necessarily drains the previous PROC's 40
// scattered out-stores (~4600cy/segment). Fix: spikes are binary -> pack 40
// steps into a u64 register, ONE store per segment (BITS[100][256]); steady
// wait = vmcnt(11) (1 store + 10 loads newer), tail vmcnt(1). k_unpack
// (coalesced, ~8us) expands bits -> out floats.
// L0: fused MFMA scan + mask pipeline. L1: 256^2 8-phase GEMM (T2/T3/T4/T5).
// L2: thin N=16 GEMM. scan_out once over full T.

#define T_STEPS 4000
#define NB 16
#define N_IN 64
#define NH 1024
#define N_OUT 10
#define SEGO 40           // scan_out segment rows; 10 glds + 1 bit-store
#define SEGH 40           // scan_hidden segment rows; 10 glds/segment

typedef __attribute__((ext_vector_type(8))) short bf16x8;
typedef __attribute__((ext_vector_type(4))) float f32x4;
typedef __hip_bfloat16 bf16;
typedef unsigned long long u64;

#define ASG(p) (const __attribute__((address_space(1))) void*)(p)
#define ASL(p) (__attribute__((address_space(3))) void*)(p)

// ---------------- small utility kernels ----------------

__global__ void k_zero(float* p, int n) {
    int i = blockIdx.x * 256 + threadIdx.x;
    if (i < n) p[i] = 0.f;
}

// Build per-(t,b) 64-bit input spike masks. One wave per (t,b).
__global__ void k_mask(const float* __restrict__ in, u64* __restrict__ mask, int total) {
    int w = (blockIdx.x * 256 + threadIdx.x) >> 6;
    int lane = threadIdx.x & 63;
    if (w >= total) return;
    float v = in[(size_t)w * 64 + lane];
    u64 bal = __ballot(v > 0.5f);
    if (lane == 0) mask[w] = bal;
}

// Unpack scan_out bit-spikes: out[t][b][k] = bit (t%40) of BITS[t/40][b*16+k].
__global__ void k_unpack(const u64* __restrict__ BITS, float* __restrict__ out,
                         int total) {
    int idx = blockIdx.x * 256 + threadIdx.x;
    if (idx >= total) return;
    int t   = idx / (NB * N_OUT);
    int rem = idx - t * (NB * N_OUT);
    int b = rem / N_OUT;
    int k = rem - b * N_OUT;
    u64 w = BITS[(size_t)(t / SEGO) * 256 + b * 16 + k];
    out[idx] = ((w >> (t % SEGO)) & 1ULL) ? 1.f : 0.f;
}

// Transposing limb builder for BT1: W [1024 x 1024] -> BT [1024][2048],
// plain [hi | lo]. Coalesced reads, LDS transpose ([64][65] pad), coalesced
// writes.
__global__ __launch_bounds__(256) void k_limbs_t(
    const float* __restrict__ W, bf16* __restrict__ BT) {
    __shared__ float Wlds[64][65];
    const int tid  = threadIdx.x;
    const int lane = tid & 63;
    const int wr   = tid >> 6;            // 0..3
    const int k0 = (blockIdx.x & 15) * 64;
    const int n0 = (blockIdx.x >> 4) * 64;
#pragma unroll
    for (int rr = 0; rr < 16; ++rr) {
        int kl = wr * 16 + rr;
        Wlds[kl][lane] = W[(size_t)(k0 + kl) * 1024 + n0 + lane];
    }
    __syncthreads();
#pragma unroll
    for (int rr = 0; rr < 16; ++rr) {
        int nl = wr * 16 + rr;
        float w = fmaxf(Wlds[lane][nl], 0.f);      // Dale's law clamp
        bf16 h = __float2bfloat16(w);
        float hf = __bfloat162float(h);
        bf16 l = __float2bfloat16(w - hf);
        size_t base = (size_t)(n0 + nl) * 2048 + k0 + lane;
        BT[base] = h;
        BT[base + 1024] = l;
    }
}

// Small limb builder (BT2): W [K x N] -> BT [Npad x 2K] plain [hi|lo].
__global__ void k_limbs(const float* __restrict__ W, bf16* __restrict__ BT,
                        int K, int N, int Npad) {
    int idx = blockIdx.x * 256 + threadIdx.x;
    int total = Npad * 2 * K;
    if (idx >= total) return;
    int n  = idx / (2 * K);
    int k2 = idx - n * (2 * K);
    int lo = (k2 >= K);
    int k = lo ? (k2 - K) : k2;
    float v = 0.f;
    if (n < N) {
        float w = fmaxf(W[(size_t)k * N + n], 0.f);
        float hi = __bfloat162float(__float2bfloat16(w));
        v = lo ? (w - hi) : w;
    }
    BT[idx] = __float2bfloat16(v);
}

// ---------------- thin GEMM v2 (layer 2): C[M x 16] = A[M x 1024] @ BT^T ---
// A read ONCE per row (hi and lo B both consumed per A-frag). 64 rows/block.

__global__ __launch_bounds__(256) void k_gemm_thin(
    const bf16* __restrict__ A, const bf16* __restrict__ BT,
    float* __restrict__ C) {
    const int tid  = threadIdx.x;
    const int lane = tid & 63;
    const int wave = tid >> 6;
    const int r16 = lane & 15;
    const int kg  = lane >> 4;
    const int m0 = blockIdx.x * 64 + wave * 16;
    f32x4 acc = {};
    const bf16* ap = A + (size_t)(m0 + r16) * 1024 + kg * 8;
    const bf16* bh = BT + (size_t)r16 * 2048 + kg * 8;   // hi limb cols
    const bf16* bl = bh + 1024;                          // lo limb cols
#pragma unroll 8
    for (int kt = 0; kt < 32; ++kt) {
        const int ka = kt * 32;
        bf16x8 af  = *(const bf16x8*)(ap + ka);
        bf16x8 bfh = *(const bf16x8*)(bh + ka);
        bf16x8 bfl = *(const bf16x8*)(bl + ka);
        acc = __builtin_amdgcn_mfma_f32_16x16x32_bf16(af, bfh, acc, 0, 0, 0);
        acc = __builtin_amdgcn_mfma_f32_16x16x32_bf16(af, bfl, acc, 0, 0, 0);
    }
#pragma unroll
    for (int rr = 0; rr < 4; ++rr)
        C[(size_t)(m0 + kg * 4 + rr) * 16 + r16] = acc[rr];
}

// ---------------- 256^2 8-phase GEMM (layer 1) ----------------
// Stage ordering invariant (R8): a region is staged only in a phase after all
// ds_reads of it have drained past a barrier (A at P3, B at P2).

__global__ __launch_bounds__(512) void k_gemm8(
    const bf16* __restrict__ A, const bf16* __restrict__ BT,
    float* __restrict__ C, int gx) {
    const int KA = 1024, K2 = 2048;
    const int kmask = KA - 1;
    const int nwg = gridDim.x;
    const int wg  = blockIdx.x;
    const int q = nwg >> 3, r = nwg & 7;
    const int xcd = wg & 7, idx0 = wg >> 3;
    const int swz = (xcd < r ? xcd * (q + 1) : r * (q + 1) + (xcd - r) * q) + idx0;
    const int gy = nwg / gx;              // 4
    const int n0 = (swz % gy) * 256;
    const int m0 = (swz / gy) * 256;

    __shared__ __align__(16) char LDS[131072];
    const int tid  = threadIdx.x;
    const int lane = tid & 63;
    const int wave = tid >> 6;
    const int wm = (wave >> 2) * 128;
    const int wn = (wave & 3) * 64;
    const int r16l = lane & 15;
    const int kg   = lane >> 4;
    const int hA   = wave >> 2;
    const int hB   = (wave & 3) >> 1;
    const int wn64 = wave & 1;

    const int po = (r16l * 64 + kg * 16) ^ (((r16l >> 3) & 1) << 5);
    const char* bA[2] = { LDS + hA * 16384 + po,
                          LDS + 65536 + hA * 16384 + po };
    const char* bB[2] = { LDS + 32768 + hB * 16384 + po,
                          LDS + 98304 + hB * 16384 + po };
    const int bOff = wn64 * 8192;

    int s_row[2], s_col[2];
#pragma unroll
    for (int rr = 0; rr < 2; ++rr) {
        int d = (rr * 512 + tid) * 16;
        int l = d ^ (((d >> 9) & 1) << 5);
        int sub = l >> 10;
        int w = l & 1023;
        s_row[rr] = (sub >> 1) * 16 + (w >> 6);
        s_col[rr] = ((sub & 1) * 64 + (w & 63)) >> 1;
    }

#define HBASE(BUF, OP, HALF) ((((BUF) * 2 + (OP)) * 2 + (HALF)) * 16384)
#define STAGE_A(BUF, HALF, K0)                                              \
    {                                                                       \
        _Pragma("unroll")                                                   \
        for (int rr = 0; rr < 2; ++rr)                                      \
            __builtin_amdgcn_global_load_lds(                               \
                ASG(A + (size_t)(m0 + (HALF) * 128 + s_row[rr]) * KA        \
                    + (((K0) + s_col[rr]) & kmask)),                        \
                ASL(LDS + HBASE(BUF, 0, HALF) + (rr * 512 + wave * 64) * 16), \
                16, 0, 0);                                                  \
    }
#define STAGE_B(BUF, HALF, K0)                                              \
    {                                                                       \
        _Pragma("unroll")                                                   \
        for (int rr = 0; rr < 2; ++rr)                                      \
            __builtin_amdgcn_global_load_lds(                               \
                ASG(BT + (size_t)(n0 + (HALF) * 128 + s_row[rr]) * K2       \
                    + (K0) + s_col[rr]),                                    \
                ASL(LDS + HBASE(BUF, 1, HALF) + (rr * 512 + wave * 64) * 16), \
                16, 0, 0);                                                  \
    }

    f32x4 acc[8][4] = {};
    bf16x8 a[4][2], b[4][2];

#define MM(MIB, NIB)                                                        \
    {                                                                       \
        _Pragma("unroll")                                                   \
        for (int i = 0; i < 4; ++i)                                         \
            _Pragma("unroll")                                               \
            for (int j = 0; j < 2; ++j) {                                   \
                acc[(MIB) + i][(NIB) + j] =                                 \
                    __builtin_amdgcn_mfma_f32_16x16x32_bf16(                \
                        a[i][0], b[(NIB) + j][0], acc[(MIB) + i][(NIB) + j], 0, 0, 0); \
                acc[(MIB) + i][(NIB) + j] =                                 \
                    __builtin_amdgcn_mfma_f32_16x16x32_bf16(                \
                        a[i][1], b[(NIB) + j][1], acc[(MIB) + i][(NIB) + j], 0, 0, 0); \
            }                                                               \
    }

#define PH_SYNC()                                                           \
    __builtin_amdgcn_s_barrier();                                           \
    asm volatile("s_waitcnt lgkmcnt(0)" ::: "memory");                      \
    __builtin_amdgcn_sched_barrier(0);

#define KTILE(BUF, SK)                                                      \
    {                                                                       \
        _Pragma("unroll")                                                   \
        for (int i = 0; i < 4; ++i) {                                       \
            a[i][0] = *(const bf16x8*)(bA[BUF] + i * 2048);                 \
            a[i][1] = *(const bf16x8*)(bA[BUF] + i * 2048 + 1024);          \
        }                                                                   \
        _Pragma("unroll")                                                   \
        for (int j = 0; j < 2; ++j) {                                       \
            b[j][0] = *(const bf16x8*)(bB[BUF] + bOff + j * 2048);          \
            b[j][1] = *(const bf16x8*)(bB[BUF] + bOff + j * 2048 + 1024);   \
        }                                                                   \
        PH_SYNC();                                                          \
        __builtin_amdgcn_s_setprio(1);                                      \
        MM(0, 0);                                                           \
        __builtin_amdgcn_s_setprio(0);                                      \
        __builtin_amdgcn_s_barrier();                                       \
        _Pragma("unroll")                                                   \
        for (int j = 0; j < 2; ++j) {                                       \
            b[2 + j][0] = *(const bf16x8*)(bB[BUF] + bOff + (2 + j) * 2048); \
            b[2 + j][1] = *(const bf16x8*)(bB[BUF] + bOff + (2 + j) * 2048 + 1024); \
        }                                                                   \
        PH_SYNC();                                                          \
        __builtin_amdgcn_s_setprio(1);                                      \
        MM(0, 2);                                                           \
        __builtin_amdgcn_s_setprio(0);                                      \
        __builtin_amdgcn_s_barrier();                                       \
        _Pragma("unroll")                                                   \
        for (int i = 0; i < 4; ++i) {                                       \
            a[i][0] = *(const bf16x8*)(bA[BUF] + (4 + i) * 2048);           \
            a[i][1] = *(const bf16x8*)(bA[BUF] + (4 + i) * 2048 + 1024);    \
        }                                                                   \
        STAGE_B(BUF, 0, SK);                                                \
        STAGE_B(BUF, 1, SK);                                                \
        PH_SYNC();                                                          \
        __builtin_amdgcn_s_setprio(1);                                      \
        MM(4, 0);                                                           \
        __builtin_amdgcn_s_setprio(0);                                      \
        __builtin_amdgcn_s_barrier();                                       \
        STAGE_A(BUF, 0, SK);                                                \
        STAGE_A(BUF, 1, SK);                                                \
        PH_SYNC();                                                          \
        __builtin_amdgcn_s_setprio(1);                                      \
        MM(4, 2);                                                           \
        __builtin_amdgcn_s_setprio(0);                                      \
        asm volatile("s_waitcnt vmcnt(8)" ::: "memory");                    \
        __builtin_amdgcn_sched_barrier(0);                                  \
        __builtin_amdgcn_s_barrier();                                       \
    }

    STAGE_A(0, 0, 0);  STAGE_A(0, 1, 0);  STAGE_B(0, 0, 0);  STAGE_B(0, 1, 0);
    STAGE_A(1, 0, 64); STAGE_A(1, 1, 64); STAGE_B(1, 0, 64); STAGE_B(1, 1, 64);
    asm volatile("s_waitcnt vmcnt(8)" ::: "memory");
    __builtin_amdgcn_sched_barrier(0);
    __builtin_amdgcn_s_barrier();

    for (int it = 0; it < 16; ++it) {
        const int k0  = it * 128;
        const int ksA = (k0 + 128) & (K2 - 1);
        const int ksB = (k0 + 192) & (K2 - 1);
        KTILE(0, ksA);
        KTILE(1, ksB);
    }
    asm volatile("s_waitcnt vmcnt(0)" ::: "memory");
    __builtin_amdgcn_sched_barrier(0);

#pragma unroll
    for (int mi = 0; mi < 8; ++mi)
#pragma unroll
        for (int ni = 0; ni < 4; ++ni)
#pragma unroll
            for (int rr = 0; rr < 4; ++rr) {
                int row = m0 + wm + mi * 16 + kg * 4 + rr;
                int col = n0 + wn + ni * 16 + r16l;
                C[(size_t)row * 1024 + col] = acc[mi][ni][rr];
            }
#undef KTILE
#undef PH_SYNC
#undef MM
#undef STAGE_A
#undef STAGE_B
#undef HBASE
}

// ---------------- LIF scan kernels (fp32 membranes) ----------------

// L0 fused scan via MFMA + mask software-pipeline. 256 blocks x 64 threads.
__global__ __launch_bounds__(64) void k_scan_l0(
    const u64* __restrict__ mask,          // [Tc][NB] for this chunk
    const float* __restrict__ W0,          // [64][1024] row-major
    const float* __restrict__ bias,
    float* __restrict__ mstate, bf16* __restrict__ S, int Tc, float beta) {
    __shared__ float Ilds[2][16][68];
    const int lane = threadIdx.x;
    const int gid  = blockIdx.x * 64 + lane;   // = b*1024 + q*64 + lane
    const int b  = blockIdx.x >> 4;
    const int q  = blockIdx.x & 15;
    const int j0 = q * 64;
    const int r16 = lane & 15;
    const int kg  = lane >> 4;
    bf16x8 bh[4][2], bl[4][2];
#pragma unroll
    for (int jt = 0; jt < 4; ++jt)
#pragma unroll
        for (int kk = 0; kk < 2; ++kk)
#pragma unroll
            for (int e = 0; e < 8; ++e) {
                int k = kk * 32 + kg * 8 + e;
                float w = fmaxf(W0[(size_t)k * 1024 + j0 + jt * 16 + r16], 0.f);
                bf16 h = __float2bfloat16(w);
                float hf = __bfloat162float(h);
                bf16 l = __float2bfloat16(w - hf);
                bh[jt][kk][e] = *(short*)&h;
                bl[jt][kk][e] = *(short*)&l;
            }
    float m = mstate[gid];
    const float bj = bias[j0 + lane];
    const size_t stride = (size_t)NB * NH;
    const int ntile = Tc / 16;
    const int tmax = ntile - 1;

#define LOADM(TT) mask[(size_t)(((TT) <= tmax ? (TT) : tmax) * 16 + r16) * NB + b]

#define L0_COMPUTE(MSK, P)                                                  \
    {                                                                       \
        f32x4 acc[4] = {};                                                  \
        _Pragma("unroll")                                                   \
        for (int kk = 0; kk < 2; ++kk) {                                    \
            unsigned byte8 = (unsigned)(((MSK) >> (kk * 32 + kg * 8)) & 0xFF); \
            bf16x8 af;                                                      \
            _Pragma("unroll")                                               \
            for (int e = 0; e < 8; ++e)                                     \
                af[e] = ((byte8 >> e) & 1) ? (short)0x3F80 : (short)0;      \
            _Pragma("unroll")                                               \
            for (int jt = 0; jt < 4; ++jt) {                                \
                acc[jt] = __builtin_amdgcn_mfma_f32_16x16x32_bf16(          \
                    af, bh[jt][kk], acc[jt], 0, 0, 0);                      \
                acc[jt] = __builtin_amdgcn_mfma_f32_16x16x32_bf16(          \
                    af, bl[jt][kk], acc[jt], 0, 0, 0);                      \
            }                                                               \
        }                                                                   \
        _Pragma("unroll")                                                   \
        for (int jt = 0; jt < 4; ++jt)                                      \
            _Pragma("unroll")                                               \
            for (int rr = 0; rr < 4; ++rr)                                  \
                Ilds[P][kg * 4 + rr][jt * 16 + r16] = acc[jt][rr];          \
    }

    u64 mc = LOADM(0);
    L0_COMPUTE(mc, 0);
    u64 mn = LOADM(1);
    for (int tt = 0; tt < ntile; ++tt) {
        __builtin_amdgcn_s_barrier();            // tile tt resident
        float v[16];
#pragma unroll
        for (int u = 0; u < 16; ++u)
            v[u] = Ilds[tt & 1][u][lane];
        u64 m2 = LOADM(tt + 2);
        if (tt + 1 < ntile) L0_COMPUTE(mn, (tt + 1) & 1);
        unsigned short o[16];
#pragma unroll
        for (int u = 0; u < 16; ++u) {
            m = fmaf(beta, m, v[u] + bj);
            bool sp = (m >= 1.0f);
            o[u] = sp ? (unsigned short)0x3F80 : (unsigned short)0;
            m = sp ? 0.f : m;
        }
#pragma unroll
        for (int u = 0; u < 16; ++u)
            ((unsigned short*)S)[(size_t)(tt * 16 + u) * stride + gid] = o[u];
        mn = m2;
    }
    mstate[gid] = m;
#undef L0_COMPUTE
#undef LOADM
}

// hidden layer 1 scan: LDS double buffer, 16B/lane staging, store-aware
// counted vmcnt. S stores are 128B-coalesced per wave-instr (fast retire).
__global__ __launch_bounds__(64) void k_scan_hidden(
    const float* __restrict__ I, const float* __restrict__ bias,
    float* __restrict__ mstate, bf16* __restrict__ S, int Tc, float beta) {
    __shared__ __align__(16) float segA[SEGH * 64];
    __shared__ __align__(16) float segB[SEGH * 64];
    const int lane = threadIdx.x;
    const int gid  = blockIdx.x * 64 + lane;
    const int j = gid & (NH - 1);
    float m = mstate[gid];
    const float bj = bias[j];
    const size_t stride = (size_t)NB * NH;
    const int nseg = Tc / SEGH;                  // even
    const int lrow = lane >> 4;
    const int lcol = (lane & 15) << 2;

#define H_PREFETCH(SEGBUF, SIDX)                                            \
    {                                                                       \
        const float* src = I + (size_t)(SIDX) * SEGH * stride               \
                             + (size_t)lrow * stride + blockIdx.x * 64 + lcol; \
        _Pragma("unroll")                                                   \
        for (int g = 0; g < SEGH / 4; ++g)                                  \
            __builtin_amdgcn_global_load_lds(                               \
                ASG(src + (size_t)(g * 4) * stride),                        \
                ASL(&SEGBUF[g * 256]), 16, 0, 0);                           \
    }

#define H_PROC(SEGBUF, SIDX)                                                \
    {                                                                       \
        const int btt = (SIDX) * SEGH;                                      \
        _Pragma("unroll")                                                   \
        for (int sb = 0; sb < SEGH / 8; ++sb) {                             \
            float v[8];                                                     \
            _Pragma("unroll")                                               \
            for (int u = 0; u < 8; ++u)                                     \
                v[u] = SEGBUF[(sb * 8 + u) * 64 + lane];                    \
            unsigned short o[8];                                            \
            _Pragma("unroll")                                               \
            for (int u = 0; u < 8; ++u) {                                   \
                m = fmaf(beta, m, v[u] + bj);                               \
                bool sp = (m >= 1.0f);                                      \
                o[u] = sp ? (unsigned short)0x3F80 : (unsigned short)0;     \
                m = sp ? 0.f : m;                                           \
            }                                                               \
            _Pragma("unroll")                                               \
            for (int u = 0; u < 8; ++u)                                     \
                ((unsigned short*)S)[(size_t)(btt + sb * 8 + u) * stride + gid] = o[u]; \
        }                                                                   \
    }

    H_PREFETCH(segA, 0);
    H_PREFETCH(segB, 1);
    asm volatile("s_waitcnt vmcnt(10)" ::: "memory");  // segA resident
    __builtin_amdgcn_sched_barrier(0);
    for (int s = 0; s < nseg; s += 2) {
        H_PROC(segA, s);                               // 40 stores
        if (s + 2 < nseg) {
            H_PREFETCH(segA, s + 2);                   // 10 loads
            asm volatile("s_waitcnt vmcnt(50)" ::: "memory");  // segB resident
        } else {
            asm volatile("s_waitcnt vmcnt(40)" ::: "memory");  // segB resident
        }
        __builtin_amdgcn_sched_barrier(0);
        H_PROC(segB, s + 1);                           // 40 stores
        if (s + 3 < nseg) {
            H_PREFETCH(segB, s + 3);
            asm volatile("s_waitcnt vmcnt(50)" ::: "memory");  // segA(s+2) resident
            __builtin_amdgcn_sched_barrier(0);
        } else if (s + 2 < nseg) {
            asm volatile("s_waitcnt vmcnt(40)" ::: "memory");
            __builtin_amdgcn_sched_barrier(0);
        }
    }
    mstate[gid] = m;
#undef H_PREFETCH
#undef H_PROC
}

// output layer scan (once over full T): wave w stages rows {w+4g}, 16B/lane.
// Spikes bit-packed per segment: ONE u64 store per 40 steps -> stores leave
// the vmcnt wait path (steady vmcnt(11) = 1 store + 10 loads newer).
__global__ __launch_bounds__(256) void k_scan_out(
    const float* __restrict__ I2, const float* __restrict__ bias,
    float* __restrict__ mstate, u64* __restrict__ BITS,
    int Tc, float beta) {
    __shared__ __align__(16) float segA[SEGO * 256];
    __shared__ __align__(16) float segB[SEGO * 256];
    const int tid  = threadIdx.x;
    const int lane = tid & 63;
    const int wave = tid >> 6;
    const int k = tid & 15;
    float m = mstate[tid];
    float bj = (k < N_OUT) ? bias[k] : 0.f;
    const int nseg = Tc / SEGO;                  // even (T=4000 -> 100)

#define O_PREFETCH(SEGBUF, SIDX)                                            \
    {                                                                       \
        const float* src = I2 + (size_t)(SIDX) * SEGO * 256                 \
                              + (size_t)wave * 256 + lane * 4;              \
        _Pragma("unroll")                                                   \
        for (int g = 0; g < SEGO / 4; ++g)                                  \
            __builtin_amdgcn_global_load_lds(                               \
                ASG(src + (size_t)(g * 4) * 256),                           \
                ASL(&SEGBUF[(g * 4 + wave) * 256]), 16, 0, 0);              \
    }

#define O_PROC(SEGBUF, SIDX)                                                \
    {                                                                       \
        u64 obits = 0;                                                      \
        _Pragma("unroll")                                                   \
        for (int sb = 0; sb < SEGO / 8; ++sb) {                             \
            float v[8];                                                     \
            _Pragma("unroll")                                               \
            for (int u = 0; u < 8; ++u)                                     \
                v[u] = SEGBUF[(sb * 8 + u) * 256 + tid];                    \
            _Pragma("unroll")                                               \
            for (int u = 0; u < 8; ++u) {                                   \
                m = fmaf(beta, m, v[u] + bj);                               \
                bool sp = (m >= 1.0f);                                      \
                obits |= ((u64)(sp ? 1 : 0)) << (sb * 8 + u);               \
                m = sp ? 0.f : m;                                           \
            }                                                               \
        }                                                                   \
        BITS[(size_t)(SIDX) * 256 + tid] = obits;                           \
    }

    O_PREFETCH(segA, 0);
    O_PREFETCH(segB, 1);
    asm volatile("s_waitcnt vmcnt(10)" ::: "memory");  // segA resident
    __builtin_amdgcn_sched_barrier(0);
    __builtin_amdgcn_s_barrier();
    for (int s = 0; s < nseg; s += 2) {
        O_PROC(segA, s);                               // 1 store
        if (s + 2 < nseg) {
            O_PREFETCH(segA, s + 2);
            asm volatile("s_waitcnt vmcnt(11)" ::: "memory");  // segB resident
        } else {
            asm volatile("s_waitcnt vmcnt(1)" ::: "memory");
        }
        __builtin_amdgcn_sched_barrier(0);
        __builtin_amdgcn_s_barrier();
        O_PROC(segB, s + 1);
        if (s + 3 < nseg) {
            O_PREFETCH(segB, s + 3);
            asm volatile("s_waitcnt vmcnt(11)" ::: "memory");  // segA(s+2) resident
            __builtin_amdgcn_sched_barrier(0);
            __builtin_amdgcn_s_barrier();
        } else if (s + 2 < nseg) {
            asm volatile("s_waitcnt vmcnt(1)" ::: "memory");
            __builtin_amdgcn_sched_barrier(0);
            __builtin_amdgcn_s_barrier();
        }
    }
    mstate[tid] = m;
#undef O_PREFETCH
#undef O_PROC
}

// ---------------- host ----------------

extern "C" void kernel_launch(void* const* d_in, const int* in_sizes, int n_in,
                              void* d_out, int out_size, void* d_ws, size_t ws_size,
                              hipStream_t stream) {
    const float* in_sp = (const float*)d_in[0];
    const float* W0 = (const float*)d_in[1];
    const float* b0 = (const float*)d_in[2];
    const float* W1 = (const float*)d_in[3];
    const float* b1 = (const float*)d_in[4];
    const float* W2 = (const float*)d_in[5];
    const float* b2 = (const float*)d_in[6];
    float* out = (float*)d_out;

    char* p = (char*)d_ws;
    auto carve = [&](size_t bytes) -> void* {
        char* r = p; p += (bytes + 255) & ~(size_t)255; return (void*)r;
    };
    u64*  MASK  = (u64*)carve((size_t)T_STEPS * NB * 8);
    bf16* BT1   = (bf16*)carve((size_t)NH * 2 * NH * 2);
    bf16* BT2   = (bf16*)carve((size_t)128 * 2 * NH * 2);
    float* m0s  = (float*)carve((size_t)NB * NH * 4);
    float* m1s  = (float*)carve((size_t)NB * NH * 4);
    float* m2s  = (float*)carve((size_t)NB * 16 * 4);
    float* I2BUF = (float*)carve((size_t)T_STEPS * NB * 16 * 4);  // full T
    u64*  BITS  = (u64*)carve((size_t)(T_STEPS / SEGO) * 256 * 8);
    size_t fixed = (size_t)(p - (char*)d_ws);

    // Tc | 4000, Tc % 400 == 0 (scan segs even; L0 tiles of 16; Mc % 256 == 0)
    const int tc_opts[3] = {2000, 800, 400};
    int Tc = 400;
    for (int i = 0; i < 3; ++i) {
        size_t Mc_ = (size_t)tc_opts[i] * NB;
        size_t need = fixed
            + ((Mc_ * NH * 4 + 255) & ~(size_t)255)
            + ((Mc_ * NH * 2 + 255) & ~(size_t)255);
        if (need <= ws_size) { Tc = tc_opts[i]; break; }
    }
    size_t Mc = (size_t)Tc * NB;
    float* IBUF = (float*)carve(Mc * NH * 4);
    bf16*  S    = (bf16*)carve(Mc * NH * 2);

    const float beta = (float)exp(-0.25 / 10.0);

    // m0s/m1s/m2s contiguous: one zero kernel.
    int nM = NB * NH * 2 + NB * 16;
    k_zero<<<(nM + 255) / 256, 256, 0, stream>>>(m0s, nM);

    // input spike masks (one wave per (t,b))
    k_mask<<<(T_STEPS * NB * 64) / 256, 256, 0, stream>>>(in_sp, MASK, T_STEPS * NB);

    k_limbs_t<<<256, 256, 0, stream>>>(W1, BT1);
    k_limbs<<<(128 * 2 * NH + 255) / 256, 256, 0, stream>>>(W2, BT2, NH, N_OUT, 128);

    const int C = T_STEPS / Tc;
    const int gx8 = (int)(Mc / 256);
    const int gthin = (int)(Mc / 64);
    for (int c = 0; c < C; ++c) {
        int t0 = c * Tc;
        // layer 0: fused MFMA scan (exact fp32 via limbs)
        k_scan_l0<<<256, 64, 0, stream>>>(MASK + (size_t)t0 * NB, W0, b0,
                                          m0s, S, Tc, beta);
        // layer 1: 256^2 8-phase GEMM
        k_gemm8<<<gx8 * 4, 512, 0, stream>>>(S, BT1, IBUF, gx8);
        k_scan_hidden<<<(NB * NH) / 64, 64, 0, stream>>>(IBUF, b1, m1s, S, Tc, beta);
        // layer 2: thin GEMM v2 into the full-T I2 buffer
        k_gemm_thin<<<gthin, 256, 0, stream>>>(S, BT2,
                                               I2BUF + (size_t)t0 * NB * 16);
    }
    // output scan once over full T (bit-packed), then unpack to floats
    k_scan_out<<<1, 256, 0, stream>>>(I2BUF, b2, m2s, BITS, T_STEPS, beta);
    int nOut = T_STEPS * NB * N_OUT;
    k_unpack<<<(nOut + 255) / 256, 256, 0, stream>>>(BITS, out, nOut);
}